// Round 1
// baseline (1389.224 us; speedup 1.0000x reference)
//
#include <hip/hip_runtime.h>

#define N_NODES 50000
#define N_EDGES 800000
#define IN_DIM 64
#define HID 128
#define NUM_LAYERS 4
#define NUM_GRAPHS 128
#define BN_EPS 1e-5f

// ---------------- small utility kernels ----------------

__global__ void zero_kernel(int* __restrict__ p, int n) {
    int i = blockIdx.x * blockDim.x + threadIdx.x;
    if (i < n) p[i] = 0;
}

__global__ void hist_kernel(const int* __restrict__ dst, int* __restrict__ cnt) {
    int e = blockIdx.x * blockDim.x + threadIdx.x;
    if (e < N_EDGES) atomicAdd(&cnt[dst[e]], 1);
}

__global__ void counts_kernel(const int* __restrict__ batch, int* __restrict__ counts) {
    int n = blockIdx.x * blockDim.x + threadIdx.x;
    if (n < N_NODES) atomicAdd(&counts[batch[n]], 1);
}

// single-block exclusive scan over 50000 counters
__global__ __launch_bounds__(1024) void scan_kernel(const int* __restrict__ cnt,
                                                    int* __restrict__ row_start,
                                                    int* __restrict__ fillp) {
    __shared__ int ls[1024];
    int t = threadIdx.x;
    const int per = (N_NODES + 1023) / 1024;   // 49
    int beg = t * per;
    int end = min(beg + per, N_NODES);
    int s = 0;
    for (int i = beg; i < end; ++i) s += cnt[i];
    ls[t] = s;
    __syncthreads();
    for (int off = 1; off < 1024; off <<= 1) {
        int v = (t >= off) ? ls[t - off] : 0;
        __syncthreads();
        ls[t] += v;
        __syncthreads();
    }
    int excl = ls[t] - s;
    int run = excl;
    for (int i = beg; i < end; ++i) {
        row_start[i] = run;
        fillp[i] = run;
        run += cnt[i];
    }
    if (t == 1023) row_start[N_NODES] = ls[1023];
}

__global__ void fill_kernel(const int* __restrict__ src, const int* __restrict__ dst,
                            const float* __restrict__ ea, int* __restrict__ fillp,
                            int* __restrict__ srcs, float2* __restrict__ eas) {
    int e = blockIdx.x * blockDim.x + threadIdx.x;
    if (e >= N_EDGES) return;
    int p = atomicAdd(&fillp[dst[e]], 1);
    srcs[p] = src[e];
    eas[p] = make_float2(ea[2 * e], ea[2 * e + 1]);
}

// h[n][c] += vn[batch[n]][c]
__global__ void addvn_kernel(float* __restrict__ h, const float* __restrict__ vn,
                             const int* __restrict__ batch) {
    int idx = blockIdx.x * 256 + threadIdx.x;
    int n = idx >> 7;
    int c = idx & 127;
    if (n < N_NODES) h[idx] += vn[batch[n] * HID + c];
}

// ---------------- edge aggregation (CSR gather) ----------------
// z[n] = h[n] + sum_{edges into n} relu(h[src] + edge_attr @ W_e + b_e)
__global__ void aggr_kernel(const float* __restrict__ h, const int* __restrict__ srcs,
                            const float2* __restrict__ eas, const int* __restrict__ row_start,
                            const float* __restrict__ We, const float* __restrict__ be,
                            float* __restrict__ z, float* __restrict__ S1, float* __restrict__ S2) {
    if (blockIdx.x == 0 && threadIdx.x < HID) {   // zero BN stat accumulators for this layer
        S1[threadIdx.x] = 0.f;
        S2[threadIdx.x] = 0.f;
    }
    int c = threadIdx.x & 127;
    int n = blockIdx.x * 2 + (threadIdx.x >> 7);
    if (n >= N_NODES) return;
    float w0 = We[c], w1 = We[HID + c], bb = be[c];
    int jb = row_start[n], je = row_start[n + 1];
    float acc = 0.f;
    for (int j = jb; j < je; ++j) {
        int s = srcs[j];
        float2 ea = eas[j];
        float m = h[s * HID + c] + fmaf(ea.x, w0, fmaf(ea.y, w1, bb));
        acc += fmaxf(m, 0.f);
    }
    z[n * HID + c] = h[n * HID + c] + acc;
}

// ---------------- f32 register-tiled GEMM: out[M,128] = A[M,K] @ W[K,128] + b ----------------
// block = 256 threads, tile 128 rows x 128 cols, 8x8 per thread. Whole W in LDS.
template <int RELU, int STATS>
__global__ __launch_bounds__(256) void gemm_kernel(const float* __restrict__ A,
                                                   const float* __restrict__ W,
                                                   const float* __restrict__ bias,
                                                   float* __restrict__ out, int K,
                                                   float* __restrict__ S1, float* __restrict__ S2,
                                                   float* __restrict__ zinit, int zinit_n) {
    __shared__ float wS[HID * HID];   // up to 64 KB
    __shared__ float zS[16 * 128];    // 8 KB, [k][row]
    int tid = threadIdx.x;
    if (zinit && blockIdx.x == 0) {
        for (int i = tid; i < zinit_n; i += 256) zinit[i] = 0.f;
    }
    for (int i = tid; i < K * HID; i += 256) wS[i] = W[i];

    int row0 = blockIdx.x * 128;
    int tr = tid >> 4;            // 0..15
    int tc = tid & 15;            // 0..15
    int r0 = tr * 8, c0 = tc * 8;
    int lrow = tid >> 1;          // 0..127
    int kg = (tid & 1) * 8;       // 0 or 8

    float acc[8][8];
#pragma unroll
    for (int j = 0; j < 8; ++j)
#pragma unroll
        for (int i = 0; i < 8; ++i) acc[j][i] = 0.f;

    __syncthreads();   // wS ready
    for (int kk0 = 0; kk0 < K; kk0 += 16) {
        float4 v0, v1;
        int grow = row0 + lrow;
        if (grow < N_NODES) {
            const float* ap = A + (size_t)grow * K + kk0 + kg;
            v0 = *(const float4*)ap;
            v1 = *(const float4*)(ap + 4);
        } else {
            v0 = make_float4(0.f, 0.f, 0.f, 0.f);
            v1 = v0;
        }
        zS[(kg + 0) * 128 + lrow] = v0.x;
        zS[(kg + 1) * 128 + lrow] = v0.y;
        zS[(kg + 2) * 128 + lrow] = v0.z;
        zS[(kg + 3) * 128 + lrow] = v0.w;
        zS[(kg + 4) * 128 + lrow] = v1.x;
        zS[(kg + 5) * 128 + lrow] = v1.y;
        zS[(kg + 6) * 128 + lrow] = v1.z;
        zS[(kg + 7) * 128 + lrow] = v1.w;
        __syncthreads();
#pragma unroll
        for (int kk = 0; kk < 16; ++kk) {
            float4 a0 = *(const float4*)&zS[kk * 128 + r0];
            float4 a1 = *(const float4*)&zS[kk * 128 + r0 + 4];
            float4 b0 = *(const float4*)&wS[(kk0 + kk) * HID + c0];
            float4 b1 = *(const float4*)&wS[(kk0 + kk) * HID + c0 + 4];
            float a[8] = {a0.x, a0.y, a0.z, a0.w, a1.x, a1.y, a1.z, a1.w};
            float b[8] = {b0.x, b0.y, b0.z, b0.w, b1.x, b1.y, b1.z, b1.w};
#pragma unroll
            for (int j = 0; j < 8; ++j)
#pragma unroll
                for (int i = 0; i < 8; ++i) acc[j][i] = fmaf(a[j], b[i], acc[j][i]);
        }
        __syncthreads();
    }

    float bcol[8];
#pragma unroll
    for (int i = 0; i < 8; ++i) bcol[i] = bias[c0 + i];
    float s1l[8], s2l[8];
#pragma unroll
    for (int i = 0; i < 8; ++i) { s1l[i] = 0.f; s2l[i] = 0.f; }

#pragma unroll
    for (int j = 0; j < 8; ++j) {
        int row = row0 + r0 + j;
        if (row < N_NODES) {
            float v[8];
#pragma unroll
            for (int i = 0; i < 8; ++i) {
                float t = acc[j][i] + bcol[i];
                if (RELU) t = fmaxf(t, 0.f);
                v[i] = t;
                if (STATS) {
                    s1l[i] += t;
                    s2l[i] += t * t;
                }
            }
            float4 o0 = make_float4(v[0], v[1], v[2], v[3]);
            float4 o1 = make_float4(v[4], v[5], v[6], v[7]);
            *(float4*)&out[(size_t)row * HID + c0] = o0;
            *(float4*)&out[(size_t)row * HID + c0 + 4] = o1;
        }
    }

    if (STATS) {
        float* s1L = zS;
        float* s2L = zS + 128;
        if (tid < 128) { s1L[tid] = 0.f; s2L[tid] = 0.f; }
        __syncthreads();
#pragma unroll
        for (int i = 0; i < 8; ++i) {
            atomicAdd(&s1L[c0 + i], s1l[i]);
            atomicAdd(&s2L[c0 + i], s2l[i]);
        }
        __syncthreads();
        if (tid < 128) {
            atomicAdd(&S1[tid], s1L[tid]);
            atomicAdd(&S2[tid], s2L[tid]);
        }
    }
}

// ---------------- BN apply + relu + segment-sum into vn_up/pool ----------------
__global__ void bn_kernel(const float* __restrict__ z2, const float* __restrict__ S1,
                          const float* __restrict__ S2, const float* __restrict__ gma,
                          const float* __restrict__ bta, const int* __restrict__ batch,
                          float* __restrict__ h, float* __restrict__ up) {
    int c = threadIdx.x & 127;
    int grp = threadIdx.x >> 7;
    int n0 = (blockIdx.x * 2 + grp) * 16;
    float mu = S1[c] * (1.f / N_NODES);
    float var = S2[c] * (1.f / N_NODES) - mu * mu;
    float rs = rsqrtf(var + BN_EPS);
    float gm = gma[c] * rs;
    float bt = bta[c];
    float acc = 0.f;
    int gcur = -1;
    for (int i = 0; i < 16; ++i) {
        int n = n0 + i;
        if (n >= N_NODES) break;
        float v = z2[n * HID + c];
        float hn = fmaxf((v - mu) * gm + bt, 0.f);
        h[n * HID + c] = hn;
        int gb = batch[n];
        if (gb != gcur) {
            if (gcur >= 0) atomicAdd(&up[gcur * HID + c], acc);
            acc = 0.f;
            gcur = gb;
        }
        acc += hn;
    }
    if (gcur >= 0) atomicAdd(&up[gcur * HID + c], acc);
}

// ---------------- virtual-node MLP: vn[g] += relu(up[g]@W1+b1)@W2+b2 ----------------
__global__ __launch_bounds__(128) void vnmlp_kernel(const float* __restrict__ up,
                                                    const float* __restrict__ W1,
                                                    const float* __restrict__ b1,
                                                    const float* __restrict__ W2,
                                                    const float* __restrict__ b2,
                                                    float* __restrict__ vn) {
    __shared__ float t[HID];
    int g = blockIdx.x, c = threadIdx.x;
    float s = b1[c];
    for (int k = 0; k < HID; ++k) s = fmaf(up[g * HID + k], W1[k * HID + c], s);
    t[c] = fmaxf(s, 0.f);
    __syncthreads();
    float s2 = b2[c];
    for (int k = 0; k < HID; ++k) s2 = fmaf(t[k], W2[k * HID + c], s2);
    vn[g * HID + c] += s2;
}

// ---------------- classifier: logits[g] ----------------
__global__ __launch_bounds__(128) void cls_kernel(const float* __restrict__ pool,
                                                  const int* __restrict__ counts,
                                                  const float* __restrict__ W1,
                                                  const float* __restrict__ b1,
                                                  const float* __restrict__ W2,
                                                  const float* __restrict__ b2,
                                                  float* __restrict__ out) {
    __shared__ float t[HID];
    __shared__ float red[HID];
    int g = blockIdx.x, c = threadIdx.x;
    float cntf = fmaxf((float)counts[g], 1.f);
    t[c] = pool[g * HID + c] / cntf;
    __syncthreads();
    float s = b1[c];
    for (int k = 0; k < HID; ++k) s = fmaf(t[k], W1[k * HID + c], s);
    float y = fmaxf(s, 0.f);
    red[c] = y * W2[c];
    __syncthreads();
    for (int off = 64; off > 0; off >>= 1) {
        if (c < off) red[c] += red[c + off];
        __syncthreads();
    }
    if (c == 0) out[g] = red[0] + b2[0];
}

// ---------------- host-side orchestration ----------------
extern "C" void kernel_launch(void* const* d_in, const int* in_sizes, int n_in,
                              void* d_out, int out_size, void* d_ws, size_t ws_size,
                              hipStream_t stream) {
    const float* x        = (const float*)d_in[0];
    const float* edge_attr= (const float*)d_in[1];
    const int*   edge_idx = (const int*)d_in[2];
    const int*   batch    = (const int*)d_in[3];
    const float* W_in     = (const float*)d_in[4];
    const float* b_in     = (const float*)d_in[5];
    const float* W_e      = (const float*)d_in[6];
    const float* b_e      = (const float*)d_in[7];
    const float* conv_W1  = (const float*)d_in[8];
    const float* conv_b1  = (const float*)d_in[9];
    const float* conv_W2  = (const float*)d_in[10];
    const float* conv_b2  = (const float*)d_in[11];
    const float* bn_g     = (const float*)d_in[12];
    const float* bn_b     = (const float*)d_in[13];
    const float* vn_W1    = (const float*)d_in[14];
    const float* vn_b1    = (const float*)d_in[15];
    const float* vn_W2    = (const float*)d_in[16];
    const float* vn_b2    = (const float*)d_in[17];
    const float* cls_W1   = (const float*)d_in[18];
    const float* cls_b1   = (const float*)d_in[19];
    const float* cls_W2   = (const float*)d_in[20];
    const float* cls_b2   = (const float*)d_in[21];

    char* ws = (char*)d_ws;
    size_t off = 0;
    auto alloc = [&](size_t bytes) -> void* {
        void* p = ws + off;
        off = (off + bytes + 255) & ~(size_t)255;
        return p;
    };
    float* A = (float*)alloc((size_t)N_NODES * HID * 4);   // h / y
    float* B = (float*)alloc((size_t)N_NODES * HID * 4);   // z / z2
    size_t zero_begin = off;
    int*   cnt    = (int*)alloc((size_t)N_NODES * 4);
    int*   counts = (int*)alloc((size_t)NUM_GRAPHS * 4);
    float* vn     = (float*)alloc((size_t)NUM_GRAPHS * HID * 4);
    float* pool   = (float*)alloc((size_t)NUM_GRAPHS * HID * 4);
    size_t zero_end = off;
    int*    row_start = (int*)alloc((size_t)(N_NODES + 1) * 4);
    int*    fillp     = (int*)alloc((size_t)N_NODES * 4);
    int*    srcs      = (int*)alloc((size_t)N_EDGES * 4);
    float2* eas       = (float2*)alloc((size_t)N_EDGES * 8);
    float*  vn_up     = (float*)alloc((size_t)NUM_GRAPHS * HID * 4);
    float*  S1        = (float*)alloc((size_t)HID * 4);
    float*  S2        = (float*)alloc((size_t)HID * 4);
    (void)ws_size; (void)in_sizes; (void)n_in; (void)out_size;

    const int* srcp = edge_idx;
    const int* dstp = edge_idx + N_EDGES;

    int zero_n = (int)((zero_end - zero_begin) / 4);
    zero_kernel<<<(zero_n + 255) / 256, 256, 0, stream>>>((int*)(ws + zero_begin), zero_n);
    hist_kernel<<<(N_EDGES + 255) / 256, 256, 0, stream>>>(dstp, cnt);
    counts_kernel<<<(N_NODES + 255) / 256, 256, 0, stream>>>(batch, counts);
    scan_kernel<<<1, 1024, 0, stream>>>(cnt, row_start, fillp);
    fill_kernel<<<(N_EDGES + 255) / 256, 256, 0, stream>>>(srcp, dstp, edge_attr, fillp, srcs, eas);

    const int gemm_grid = (N_NODES + 127) / 128;
    // h0 = x @ W_in + b_in
    gemm_kernel<0, 0><<<gemm_grid, 256, 0, stream>>>(x, W_in, b_in, A, IN_DIM,
                                                     nullptr, nullptr, nullptr, 0);

    for (int i = 0; i < NUM_LAYERS; ++i) {
        if (i > 0)
            addvn_kernel<<<(N_NODES * HID) / 256, 256, 0, stream>>>(A, vn, batch);
        aggr_kernel<<<N_NODES / 2, 256, 0, stream>>>(A, srcs, eas, row_start, W_e, b_e, B, S1, S2);
        gemm_kernel<1, 0><<<gemm_grid, 256, 0, stream>>>(B, conv_W1 + (size_t)i * HID * HID,
                                                         conv_b1 + (size_t)i * HID, A, HID,
                                                         nullptr, nullptr,
                                                         (i < NUM_LAYERS - 1) ? vn_up : nullptr,
                                                         NUM_GRAPHS * HID);
        gemm_kernel<0, 1><<<gemm_grid, 256, 0, stream>>>(A, conv_W2 + (size_t)i * HID * HID,
                                                         conv_b2 + (size_t)i * HID, B, HID,
                                                         S1, S2, nullptr, 0);
        bn_kernel<<<(N_NODES + 31) / 32, 256, 0, stream>>>(B, S1, S2, bn_g + (size_t)i * HID,
                                                           bn_b + (size_t)i * HID, batch, A,
                                                           (i < NUM_LAYERS - 1) ? vn_up : pool);
        if (i < NUM_LAYERS - 1)
            vnmlp_kernel<<<NUM_GRAPHS, 128, 0, stream>>>(vn_up, vn_W1, vn_b1, vn_W2, vn_b2, vn);
    }

    cls_kernel<<<NUM_GRAPHS, 128, 0, stream>>>(pool, counts, cls_W1, cls_b1, cls_W2, cls_b2,
                                               (float*)d_out);
}

// Round 2
// 1019.105 us; speedup vs baseline: 1.3632x; 1.3632x over previous
//
#include <hip/hip_runtime.h>

#define N_NODES 50000
#define N_EDGES 800000
#define IN_DIM 64
#define HID 128
#define NUM_LAYERS 4
#define NUM_GRAPHS 128
#define BN_EPS 1e-5f

// ---------------- small utility kernels ----------------

__global__ void zero_kernel(int* __restrict__ p, int n) {
    int i = blockIdx.x * blockDim.x + threadIdx.x;
    if (i < n) p[i] = 0;
}

__global__ void hist_kernel(const int* __restrict__ dst, int* __restrict__ cnt) {
    int e = blockIdx.x * blockDim.x + threadIdx.x;
    if (e < N_EDGES) atomicAdd(&cnt[dst[e]], 1);
}

__global__ void counts_kernel(const int* __restrict__ batch, int* __restrict__ counts) {
    int n = blockIdx.x * blockDim.x + threadIdx.x;
    if (n < N_NODES) atomicAdd(&counts[batch[n]], 1);
}

// single-block exclusive scan over 50000 counters
__global__ __launch_bounds__(1024) void scan_kernel(const int* __restrict__ cnt,
                                                    int* __restrict__ row_start,
                                                    int* __restrict__ fillp) {
    __shared__ int ls[1024];
    int t = threadIdx.x;
    const int per = (N_NODES + 1023) / 1024;   // 49
    int beg = t * per;
    int end = min(beg + per, N_NODES);
    int s = 0;
    for (int i = beg; i < end; ++i) s += cnt[i];
    ls[t] = s;
    __syncthreads();
    for (int off = 1; off < 1024; off <<= 1) {
        int v = (t >= off) ? ls[t - off] : 0;
        __syncthreads();
        ls[t] += v;
        __syncthreads();
    }
    int excl = ls[t] - s;
    int run = excl;
    for (int i = beg; i < end; ++i) {
        row_start[i] = run;
        fillp[i] = run;
        run += cnt[i];
    }
    if (t == 1023) row_start[N_NODES] = ls[1023];
}

__global__ void fill_kernel(const int* __restrict__ src, const int* __restrict__ dst,
                            const float* __restrict__ ea, int* __restrict__ fillp,
                            int* __restrict__ srcs, float2* __restrict__ eas) {
    int e = blockIdx.x * blockDim.x + threadIdx.x;
    if (e >= N_EDGES) return;
    int p = atomicAdd(&fillp[dst[e]], 1);
    srcs[p] = src[e];
    eas[p] = make_float2(ea[2 * e], ea[2 * e + 1]);
}

// h[n][c] += vn[batch[n]][c]
__global__ void addvn_kernel(float* __restrict__ h, const float* __restrict__ vn,
                             const int* __restrict__ batch) {
    int idx = blockIdx.x * 256 + threadIdx.x;
    int n = idx >> 7;
    int c = idx & 127;
    if (n < N_NODES) h[idx] += vn[batch[n] * HID + c];
}

// ---------------- edge aggregation (CSR gather) ----------------
// z[n] = h[n] + sum_{edges into n} relu(h[src] + edge_attr @ W_e + b_e)
// 4 channels per thread (float4 gather), edge loop unrolled x4 for MLP-level ILP.
__global__ __launch_bounds__(256) void aggr_kernel(const float* __restrict__ h,
                                                   const int* __restrict__ srcs,
                                                   const float2* __restrict__ eas,
                                                   const int* __restrict__ row_start,
                                                   const float* __restrict__ We,
                                                   const float* __restrict__ be,
                                                   float* __restrict__ z,
                                                   float* __restrict__ S1,
                                                   float* __restrict__ S2) {
    int tid = threadIdx.x;
    if (blockIdx.x == 0 && tid < HID) {   // zero BN stat accumulators for this layer
        S1[tid] = 0.f;
        S2[tid] = 0.f;
    }
    int cg = (tid & 31) * 4;              // this thread's 4-channel group
    int n = blockIdx.x * 8 + (tid >> 5);  // 8 nodes per 256-thread block (grid exact)

    float4 w0 = *(const float4*)&We[cg];
    float4 w1 = *(const float4*)&We[HID + cg];
    float4 bb = *(const float4*)&be[cg];

    int jb = row_start[n], je = row_start[n + 1];
    float4 acc = make_float4(0.f, 0.f, 0.f, 0.f);

    int j = jb;
    for (; j + 4 <= je; j += 4) {
        int s0 = srcs[j + 0], s1 = srcs[j + 1], s2 = srcs[j + 2], s3 = srcs[j + 3];
        float2 e0 = eas[j + 0], e1 = eas[j + 1], e2 = eas[j + 2], e3 = eas[j + 3];
        float4 h0 = *(const float4*)&h[(size_t)s0 * HID + cg];
        float4 h1 = *(const float4*)&h[(size_t)s1 * HID + cg];
        float4 h2 = *(const float4*)&h[(size_t)s2 * HID + cg];
        float4 h3 = *(const float4*)&h[(size_t)s3 * HID + cg];
        acc.x += fmaxf(h0.x + fmaf(e0.x, w0.x, fmaf(e0.y, w1.x, bb.x)), 0.f);
        acc.y += fmaxf(h0.y + fmaf(e0.x, w0.y, fmaf(e0.y, w1.y, bb.y)), 0.f);
        acc.z += fmaxf(h0.z + fmaf(e0.x, w0.z, fmaf(e0.y, w1.z, bb.z)), 0.f);
        acc.w += fmaxf(h0.w + fmaf(e0.x, w0.w, fmaf(e0.y, w1.w, bb.w)), 0.f);
        acc.x += fmaxf(h1.x + fmaf(e1.x, w0.x, fmaf(e1.y, w1.x, bb.x)), 0.f);
        acc.y += fmaxf(h1.y + fmaf(e1.x, w0.y, fmaf(e1.y, w1.y, bb.y)), 0.f);
        acc.z += fmaxf(h1.z + fmaf(e1.x, w0.z, fmaf(e1.y, w1.z, bb.z)), 0.f);
        acc.w += fmaxf(h1.w + fmaf(e1.x, w0.w, fmaf(e1.y, w1.w, bb.w)), 0.f);
        acc.x += fmaxf(h2.x + fmaf(e2.x, w0.x, fmaf(e2.y, w1.x, bb.x)), 0.f);
        acc.y += fmaxf(h2.y + fmaf(e2.x, w0.y, fmaf(e2.y, w1.y, bb.y)), 0.f);
        acc.z += fmaxf(h2.z + fmaf(e2.x, w0.z, fmaf(e2.y, w1.z, bb.z)), 0.f);
        acc.w += fmaxf(h2.w + fmaf(e2.x, w0.w, fmaf(e2.y, w1.w, bb.w)), 0.f);
        acc.x += fmaxf(h3.x + fmaf(e3.x, w0.x, fmaf(e3.y, w1.x, bb.x)), 0.f);
        acc.y += fmaxf(h3.y + fmaf(e3.x, w0.y, fmaf(e3.y, w1.y, bb.y)), 0.f);
        acc.z += fmaxf(h3.z + fmaf(e3.x, w0.z, fmaf(e3.y, w1.z, bb.z)), 0.f);
        acc.w += fmaxf(h3.w + fmaf(e3.x, w0.w, fmaf(e3.y, w1.w, bb.w)), 0.f);
    }
    for (; j < je; ++j) {
        int s = srcs[j];
        float2 e = eas[j];
        float4 hv = *(const float4*)&h[(size_t)s * HID + cg];
        acc.x += fmaxf(hv.x + fmaf(e.x, w0.x, fmaf(e.y, w1.x, bb.x)), 0.f);
        acc.y += fmaxf(hv.y + fmaf(e.x, w0.y, fmaf(e.y, w1.y, bb.y)), 0.f);
        acc.z += fmaxf(hv.z + fmaf(e.x, w0.z, fmaf(e.y, w1.z, bb.z)), 0.f);
        acc.w += fmaxf(hv.w + fmaf(e.x, w0.w, fmaf(e.y, w1.w, bb.w)), 0.f);
    }

    float4 hn = *(const float4*)&h[(size_t)n * HID + cg];
    float4 o = make_float4(hn.x + acc.x, hn.y + acc.y, hn.z + acc.z, hn.w + acc.w);
    *(float4*)&z[(size_t)n * HID + cg] = o;
}

// ---------------- f32 register-tiled GEMM: out[M,128] = A[M,K] @ W[K,128] + b ----------------
// block = 256 threads, tile 128 rows x 128 cols, 8x8 per thread. Whole W in LDS.
template <int RELU, int STATS>
__global__ __launch_bounds__(256) void gemm_kernel(const float* __restrict__ A,
                                                   const float* __restrict__ W,
                                                   const float* __restrict__ bias,
                                                   float* __restrict__ out, int K,
                                                   float* __restrict__ S1, float* __restrict__ S2,
                                                   float* __restrict__ zinit, int zinit_n) {
    __shared__ float wS[HID * HID];   // up to 64 KB
    __shared__ float zS[16 * 128];    // 8 KB, [k][row]
    int tid = threadIdx.x;
    if (zinit && blockIdx.x == 0) {
        for (int i = tid; i < zinit_n; i += 256) zinit[i] = 0.f;
    }
    for (int i = tid; i < K * HID; i += 256) wS[i] = W[i];

    int row0 = blockIdx.x * 128;
    int tr = tid >> 4;            // 0..15
    int tc = tid & 15;            // 0..15
    int r0 = tr * 8, c0 = tc * 8;
    int lrow = tid >> 1;          // 0..127
    int kg = (tid & 1) * 8;       // 0 or 8

    float acc[8][8];
#pragma unroll
    for (int j = 0; j < 8; ++j)
#pragma unroll
        for (int i = 0; i < 8; ++i) acc[j][i] = 0.f;

    __syncthreads();   // wS ready
    for (int kk0 = 0; kk0 < K; kk0 += 16) {
        float4 v0, v1;
        int grow = row0 + lrow;
        if (grow < N_NODES) {
            const float* ap = A + (size_t)grow * K + kk0 + kg;
            v0 = *(const float4*)ap;
            v1 = *(const float4*)(ap + 4);
        } else {
            v0 = make_float4(0.f, 0.f, 0.f, 0.f);
            v1 = v0;
        }
        zS[(kg + 0) * 128 + lrow] = v0.x;
        zS[(kg + 1) * 128 + lrow] = v0.y;
        zS[(kg + 2) * 128 + lrow] = v0.z;
        zS[(kg + 3) * 128 + lrow] = v0.w;
        zS[(kg + 4) * 128 + lrow] = v1.x;
        zS[(kg + 5) * 128 + lrow] = v1.y;
        zS[(kg + 6) * 128 + lrow] = v1.z;
        zS[(kg + 7) * 128 + lrow] = v1.w;
        __syncthreads();
#pragma unroll
        for (int kk = 0; kk < 16; ++kk) {
            float4 a0 = *(const float4*)&zS[kk * 128 + r0];
            float4 a1 = *(const float4*)&zS[kk * 128 + r0 + 4];
            float4 b0 = *(const float4*)&wS[(kk0 + kk) * HID + c0];
            float4 b1 = *(const float4*)&wS[(kk0 + kk) * HID + c0 + 4];
            float a[8] = {a0.x, a0.y, a0.z, a0.w, a1.x, a1.y, a1.z, a1.w};
            float b[8] = {b0.x, b0.y, b0.z, b0.w, b1.x, b1.y, b1.z, b1.w};
#pragma unroll
            for (int j = 0; j < 8; ++j)
#pragma unroll
                for (int i = 0; i < 8; ++i) acc[j][i] = fmaf(a[j], b[i], acc[j][i]);
        }
        __syncthreads();
    }

    float bcol[8];
#pragma unroll
    for (int i = 0; i < 8; ++i) bcol[i] = bias[c0 + i];
    float s1l[8], s2l[8];
#pragma unroll
    for (int i = 0; i < 8; ++i) { s1l[i] = 0.f; s2l[i] = 0.f; }

#pragma unroll
    for (int j = 0; j < 8; ++j) {
        int row = row0 + r0 + j;
        if (row < N_NODES) {
            float v[8];
#pragma unroll
            for (int i = 0; i < 8; ++i) {
                float t = acc[j][i] + bcol[i];
                if (RELU) t = fmaxf(t, 0.f);
                v[i] = t;
                if (STATS) {
                    s1l[i] += t;
                    s2l[i] += t * t;
                }
            }
            float4 o0 = make_float4(v[0], v[1], v[2], v[3]);
            float4 o1 = make_float4(v[4], v[5], v[6], v[7]);
            *(float4*)&out[(size_t)row * HID + c0] = o0;
            *(float4*)&out[(size_t)row * HID + c0 + 4] = o1;
        }
    }

    if (STATS) {
        float* s1L = zS;
        float* s2L = zS + 128;
        if (tid < 128) { s1L[tid] = 0.f; s2L[tid] = 0.f; }
        __syncthreads();
#pragma unroll
        for (int i = 0; i < 8; ++i) {
            atomicAdd(&s1L[c0 + i], s1l[i]);
            atomicAdd(&s2L[c0 + i], s2l[i]);
        }
        __syncthreads();
        if (tid < 128) {
            atomicAdd(&S1[tid], s1L[tid]);
            atomicAdd(&S2[tid], s2L[tid]);
        }
    }
}

// ---------------- BN apply + relu + segment-sum into vn_up/pool ----------------
__global__ void bn_kernel(const float* __restrict__ z2, const float* __restrict__ S1,
                          const float* __restrict__ S2, const float* __restrict__ gma,
                          const float* __restrict__ bta, const int* __restrict__ batch,
                          float* __restrict__ h, float* __restrict__ up) {
    int c = threadIdx.x & 127;
    int grp = threadIdx.x >> 7;
    int n0 = (blockIdx.x * 2 + grp) * 16;
    float mu = S1[c] * (1.f / N_NODES);
    float var = S2[c] * (1.f / N_NODES) - mu * mu;
    float rs = rsqrtf(var + BN_EPS);
    float gm = gma[c] * rs;
    float bt = bta[c];
    float acc = 0.f;
    int gcur = -1;
    for (int i = 0; i < 16; ++i) {
        int n = n0 + i;
        if (n >= N_NODES) break;
        float v = z2[n * HID + c];
        float hn = fmaxf((v - mu) * gm + bt, 0.f);
        h[n * HID + c] = hn;
        int gb = batch[n];
        if (gb != gcur) {
            if (gcur >= 0) atomicAdd(&up[gcur * HID + c], acc);
            acc = 0.f;
            gcur = gb;
        }
        acc += hn;
    }
    if (gcur >= 0) atomicAdd(&up[gcur * HID + c], acc);
}

// ---------------- virtual-node MLP: vn[g] += relu(up[g]@W1+b1)@W2+b2 ----------------
__global__ __launch_bounds__(128) void vnmlp_kernel(const float* __restrict__ up,
                                                    const float* __restrict__ W1,
                                                    const float* __restrict__ b1,
                                                    const float* __restrict__ W2,
                                                    const float* __restrict__ b2,
                                                    float* __restrict__ vn) {
    __shared__ float t[HID];
    int g = blockIdx.x, c = threadIdx.x;
    float s = b1[c];
    for (int k = 0; k < HID; ++k) s = fmaf(up[g * HID + k], W1[k * HID + c], s);
    t[c] = fmaxf(s, 0.f);
    __syncthreads();
    float s2 = b2[c];
    for (int k = 0; k < HID; ++k) s2 = fmaf(t[k], W2[k * HID + c], s2);
    vn[g * HID + c] += s2;
}

// ---------------- classifier: logits[g] ----------------
__global__ __launch_bounds__(128) void cls_kernel(const float* __restrict__ pool,
                                                  const int* __restrict__ counts,
                                                  const float* __restrict__ W1,
                                                  const float* __restrict__ b1,
                                                  const float* __restrict__ W2,
                                                  const float* __restrict__ b2,
                                                  float* __restrict__ out) {
    __shared__ float t[HID];
    __shared__ float red[HID];
    int g = blockIdx.x, c = threadIdx.x;
    float cntf = fmaxf((float)counts[g], 1.f);
    t[c] = pool[g * HID + c] / cntf;
    __syncthreads();
    float s = b1[c];
    for (int k = 0; k < HID; ++k) s = fmaf(t[k], W1[k * HID + c], s);
    float y = fmaxf(s, 0.f);
    red[c] = y * W2[c];
    __syncthreads();
    for (int off = 64; off > 0; off >>= 1) {
        if (c < off) red[c] += red[c + off];
        __syncthreads();
    }
    if (c == 0) out[g] = red[0] + b2[0];
}

// ---------------- host-side orchestration ----------------
extern "C" void kernel_launch(void* const* d_in, const int* in_sizes, int n_in,
                              void* d_out, int out_size, void* d_ws, size_t ws_size,
                              hipStream_t stream) {
    const float* x        = (const float*)d_in[0];
    const float* edge_attr= (const float*)d_in[1];
    const int*   edge_idx = (const int*)d_in[2];
    const int*   batch    = (const int*)d_in[3];
    const float* W_in     = (const float*)d_in[4];
    const float* b_in     = (const float*)d_in[5];
    const float* W_e      = (const float*)d_in[6];
    const float* b_e      = (const float*)d_in[7];
    const float* conv_W1  = (const float*)d_in[8];
    const float* conv_b1  = (const float*)d_in[9];
    const float* conv_W2  = (const float*)d_in[10];
    const float* conv_b2  = (const float*)d_in[11];
    const float* bn_g     = (const float*)d_in[12];
    const float* bn_b     = (const float*)d_in[13];
    const float* vn_W1    = (const float*)d_in[14];
    const float* vn_b1    = (const float*)d_in[15];
    const float* vn_W2    = (const float*)d_in[16];
    const float* vn_b2    = (const float*)d_in[17];
    const float* cls_W1   = (const float*)d_in[18];
    const float* cls_b1   = (const float*)d_in[19];
    const float* cls_W2   = (const float*)d_in[20];
    const float* cls_b2   = (const float*)d_in[21];

    char* ws = (char*)d_ws;
    size_t off = 0;
    auto alloc = [&](size_t bytes) -> void* {
        void* p = ws + off;
        off = (off + bytes + 255) & ~(size_t)255;
        return p;
    };
    float* A = (float*)alloc((size_t)N_NODES * HID * 4);   // h / y
    float* B = (float*)alloc((size_t)N_NODES * HID * 4);   // z / z2
    size_t zero_begin = off;
    int*   cnt    = (int*)alloc((size_t)N_NODES * 4);
    int*   counts = (int*)alloc((size_t)NUM_GRAPHS * 4);
    float* vn     = (float*)alloc((size_t)NUM_GRAPHS * HID * 4);
    float* pool   = (float*)alloc((size_t)NUM_GRAPHS * HID * 4);
    size_t zero_end = off;
    int*    row_start = (int*)alloc((size_t)(N_NODES + 1) * 4);
    int*    fillp     = (int*)alloc((size_t)N_NODES * 4);
    int*    srcs      = (int*)alloc((size_t)N_EDGES * 4);
    float2* eas       = (float2*)alloc((size_t)N_EDGES * 8);
    float*  vn_up     = (float*)alloc((size_t)NUM_GRAPHS * HID * 4);
    float*  S1        = (float*)alloc((size_t)HID * 4);
    float*  S2        = (float*)alloc((size_t)HID * 4);
    (void)ws_size; (void)in_sizes; (void)n_in; (void)out_size;

    const int* srcp = edge_idx;
    const int* dstp = edge_idx + N_EDGES;

    int zero_n = (int)((zero_end - zero_begin) / 4);
    zero_kernel<<<(zero_n + 255) / 256, 256, 0, stream>>>((int*)(ws + zero_begin), zero_n);
    hist_kernel<<<(N_EDGES + 255) / 256, 256, 0, stream>>>(dstp, cnt);
    counts_kernel<<<(N_NODES + 255) / 256, 256, 0, stream>>>(batch, counts);
    scan_kernel<<<1, 1024, 0, stream>>>(cnt, row_start, fillp);
    fill_kernel<<<(N_EDGES + 255) / 256, 256, 0, stream>>>(srcp, dstp, edge_attr, fillp, srcs, eas);

    const int gemm_grid = (N_NODES + 127) / 128;
    // h0 = x @ W_in + b_in
    gemm_kernel<0, 0><<<gemm_grid, 256, 0, stream>>>(x, W_in, b_in, A, IN_DIM,
                                                     nullptr, nullptr, nullptr, 0);

    for (int i = 0; i < NUM_LAYERS; ++i) {
        if (i > 0)
            addvn_kernel<<<(N_NODES * HID) / 256, 256, 0, stream>>>(A, vn, batch);
        aggr_kernel<<<N_NODES / 8, 256, 0, stream>>>(A, srcs, eas, row_start, W_e, b_e, B, S1, S2);
        gemm_kernel<1, 0><<<gemm_grid, 256, 0, stream>>>(B, conv_W1 + (size_t)i * HID * HID,
                                                         conv_b1 + (size_t)i * HID, A, HID,
                                                         nullptr, nullptr,
                                                         (i < NUM_LAYERS - 1) ? vn_up : nullptr,
                                                         NUM_GRAPHS * HID);
        gemm_kernel<0, 1><<<gemm_grid, 256, 0, stream>>>(A, conv_W2 + (size_t)i * HID * HID,
                                                         conv_b2 + (size_t)i * HID, B, HID,
                                                         S1, S2, nullptr, 0);
        bn_kernel<<<(N_NODES + 31) / 32, 256, 0, stream>>>(B, S1, S2, bn_g + (size_t)i * HID,
                                                           bn_b + (size_t)i * HID, batch, A,
                                                           (i < NUM_LAYERS - 1) ? vn_up : pool);
        if (i < NUM_LAYERS - 1)
            vnmlp_kernel<<<NUM_GRAPHS, 128, 0, stream>>>(vn_up, vn_W1, vn_b1, vn_W2, vn_b2, vn);
    }

    cls_kernel<<<NUM_GRAPHS, 128, 0, stream>>>(pool, counts, cls_W1, cls_b1, cls_W2, cls_b2,
                                               (float*)d_out);
}

// Round 3
// 814.269 us; speedup vs baseline: 1.7061x; 1.2516x over previous
//
#include <hip/hip_runtime.h>

#define N_NODES 50000
#define N_EDGES 800000
#define IN_DIM 64
#define HID 128
#define NUM_LAYERS 4
#define NUM_GRAPHS 128
#define BN_EPS 1e-5f

// ---------------- small utility kernels ----------------

__global__ void zero_kernel(int* __restrict__ p, int n) {
    int i = blockIdx.x * blockDim.x + threadIdx.x;
    if (i < n) p[i] = 0;
}

__global__ void hist_kernel(const int* __restrict__ dst, int* __restrict__ cnt) {
    int e = blockIdx.x * blockDim.x + threadIdx.x;
    if (e < N_EDGES) atomicAdd(&cnt[dst[e]], 1);
}

// batch is sorted: endpos[g] = #nodes with batch <= g, written only at run boundaries.
__global__ void endpos_kernel(const int* __restrict__ batch, int* __restrict__ endpos) {
    int n = blockIdx.x * 256 + threadIdx.x;
    if (n >= N_NODES) return;
    int b = batch[n];
    int b1 = (n + 1 < N_NODES) ? batch[n + 1] : NUM_GRAPHS;
    for (int g = b; g < b1; ++g) endpos[g] = n + 1;
    if (n == 0)
        for (int g = 0; g < b; ++g) endpos[g] = 0;
}

// ---------------- 3-stage coalesced exclusive scan over 50000 counters ----------------
#define SCAN_BLOCKS ((N_NODES + 1023) / 1024)   // 49

__global__ __launch_bounds__(1024) void scan1_kernel(const int* __restrict__ cnt,
                                                     int* __restrict__ bsum) {
    __shared__ int ls[1024];
    int t = threadIdx.x;
    int g = blockIdx.x * 1024 + t;
    int v = (g < N_NODES) ? cnt[g] : 0;
    ls[t] = v;
    __syncthreads();
    for (int off = 512; off > 0; off >>= 1) {
        if (t < off) ls[t] += ls[t + off];
        __syncthreads();
    }
    if (t == 0) bsum[blockIdx.x] = ls[0];
}

__global__ void scan2_kernel(const int* __restrict__ bsum, int* __restrict__ boff) {
    if (threadIdx.x == 0) {
        int r = 0;
        for (int i = 0; i < SCAN_BLOCKS; ++i) {
            boff[i] = r;
            r += bsum[i];
        }
    }
}

__global__ __launch_bounds__(1024) void scan3_kernel(const int* __restrict__ cnt,
                                                     const int* __restrict__ boff,
                                                     int* __restrict__ row_start,
                                                     int* __restrict__ fillp) {
    __shared__ int ls[1024];
    int t = threadIdx.x;
    int g = blockIdx.x * 1024 + t;
    int v = (g < N_NODES) ? cnt[g] : 0;
    ls[t] = v;
    __syncthreads();
    for (int off = 1; off < 1024; off <<= 1) {
        int x = (t >= off) ? ls[t - off] : 0;
        __syncthreads();
        ls[t] += x;
        __syncthreads();
    }
    int excl = ls[t] - v + boff[blockIdx.x];
    if (g < N_NODES) {
        row_start[g] = excl;
        fillp[g] = excl;
        if (g == N_NODES - 1) row_start[N_NODES] = excl + v;
    }
}

__global__ void fill_kernel(const int* __restrict__ src, const int* __restrict__ dst,
                            const float* __restrict__ ea, int* __restrict__ fillp,
                            int* __restrict__ srcs, float2* __restrict__ eas) {
    int e = blockIdx.x * blockDim.x + threadIdx.x;
    if (e >= N_EDGES) return;
    int p = atomicAdd(&fillp[dst[e]], 1);
    srcs[p] = src[e];
    eas[p] = make_float2(ea[2 * e], ea[2 * e + 1]);
}

// h[n][cg..cg+3] += vn[batch[n]][cg..cg+3]
__global__ void addvn_kernel(float* __restrict__ h, const float* __restrict__ vn,
                             const int* __restrict__ batch) {
    int idx = blockIdx.x * 256 + threadIdx.x;   // over N_NODES*32
    int n = idx >> 5;
    if (n >= N_NODES) return;
    int cg = (idx & 31) * 4;
    float4 hv = *(const float4*)&h[(size_t)n * HID + cg];
    float4 vv = *(const float4*)&vn[(size_t)batch[n] * HID + cg];
    hv.x += vv.x; hv.y += vv.y; hv.z += vv.z; hv.w += vv.w;
    *(float4*)&h[(size_t)n * HID + cg] = hv;
}

// ---------------- edge aggregation (CSR gather) ----------------
// z[n] = h[n] + sum_{edges into n} relu(h[src] + edge_attr @ W_e + b_e)
__global__ __launch_bounds__(256) void aggr_kernel(const float* __restrict__ h,
                                                   const int* __restrict__ srcs,
                                                   const float2* __restrict__ eas,
                                                   const int* __restrict__ row_start,
                                                   const float* __restrict__ We,
                                                   const float* __restrict__ be,
                                                   float* __restrict__ z,
                                                   float* __restrict__ S1,
                                                   float* __restrict__ S2) {
    int tid = threadIdx.x;
    if (blockIdx.x == 0 && tid < HID) {   // zero BN stat accumulators for this layer
        S1[tid] = 0.f;
        S2[tid] = 0.f;
    }
    int cg = (tid & 31) * 4;              // this thread's 4-channel group
    int n = blockIdx.x * 8 + (tid >> 5);  // 8 nodes per 256-thread block (grid exact)

    float4 w0 = *(const float4*)&We[cg];
    float4 w1 = *(const float4*)&We[HID + cg];
    float4 bb = *(const float4*)&be[cg];

    int jb = row_start[n], je = row_start[n + 1];
    float4 acc = make_float4(0.f, 0.f, 0.f, 0.f);

    int j = jb;
    for (; j + 4 <= je; j += 4) {
        int s0 = srcs[j + 0], s1 = srcs[j + 1], s2 = srcs[j + 2], s3 = srcs[j + 3];
        float2 e0 = eas[j + 0], e1 = eas[j + 1], e2 = eas[j + 2], e3 = eas[j + 3];
        float4 h0 = *(const float4*)&h[(size_t)s0 * HID + cg];
        float4 h1 = *(const float4*)&h[(size_t)s1 * HID + cg];
        float4 h2 = *(const float4*)&h[(size_t)s2 * HID + cg];
        float4 h3 = *(const float4*)&h[(size_t)s3 * HID + cg];
        acc.x += fmaxf(h0.x + fmaf(e0.x, w0.x, fmaf(e0.y, w1.x, bb.x)), 0.f);
        acc.y += fmaxf(h0.y + fmaf(e0.x, w0.y, fmaf(e0.y, w1.y, bb.y)), 0.f);
        acc.z += fmaxf(h0.z + fmaf(e0.x, w0.z, fmaf(e0.y, w1.z, bb.z)), 0.f);
        acc.w += fmaxf(h0.w + fmaf(e0.x, w0.w, fmaf(e0.y, w1.w, bb.w)), 0.f);
        acc.x += fmaxf(h1.x + fmaf(e1.x, w0.x, fmaf(e1.y, w1.x, bb.x)), 0.f);
        acc.y += fmaxf(h1.y + fmaf(e1.x, w0.y, fmaf(e1.y, w1.y, bb.y)), 0.f);
        acc.z += fmaxf(h1.z + fmaf(e1.x, w0.z, fmaf(e1.y, w1.z, bb.z)), 0.f);
        acc.w += fmaxf(h1.w + fmaf(e1.x, w0.w, fmaf(e1.y, w1.w, bb.w)), 0.f);
        acc.x += fmaxf(h2.x + fmaf(e2.x, w0.x, fmaf(e2.y, w1.x, bb.x)), 0.f);
        acc.y += fmaxf(h2.y + fmaf(e2.x, w0.y, fmaf(e2.y, w1.y, bb.y)), 0.f);
        acc.z += fmaxf(h2.z + fmaf(e2.x, w0.z, fmaf(e2.y, w1.z, bb.z)), 0.f);
        acc.w += fmaxf(h2.w + fmaf(e2.x, w0.w, fmaf(e2.y, w1.w, bb.w)), 0.f);
        acc.x += fmaxf(h3.x + fmaf(e3.x, w0.x, fmaf(e3.y, w1.x, bb.x)), 0.f);
        acc.y += fmaxf(h3.y + fmaf(e3.x, w0.y, fmaf(e3.y, w1.y, bb.y)), 0.f);
        acc.z += fmaxf(h3.z + fmaf(e3.x, w0.z, fmaf(e3.y, w1.z, bb.z)), 0.f);
        acc.w += fmaxf(h3.w + fmaf(e3.x, w0.w, fmaf(e3.y, w1.w, bb.w)), 0.f);
    }
    for (; j < je; ++j) {
        int s = srcs[j];
        float2 e = eas[j];
        float4 hv = *(const float4*)&h[(size_t)s * HID + cg];
        acc.x += fmaxf(hv.x + fmaf(e.x, w0.x, fmaf(e.y, w1.x, bb.x)), 0.f);
        acc.y += fmaxf(hv.y + fmaf(e.x, w0.y, fmaf(e.y, w1.y, bb.y)), 0.f);
        acc.z += fmaxf(hv.z + fmaf(e.x, w0.z, fmaf(e.y, w1.z, bb.z)), 0.f);
        acc.w += fmaxf(hv.w + fmaf(e.x, w0.w, fmaf(e.y, w1.w, bb.w)), 0.f);
    }

    float4 hn = *(const float4*)&h[(size_t)n * HID + cg];
    float4 o = make_float4(hn.x + acc.x, hn.y + acc.y, hn.z + acc.z, hn.w + acc.w);
    *(float4*)&z[(size_t)n * HID + cg] = o;
}

// ---------------- f32 register-tiled GEMM: out[M,128] = A[M,K] @ W[K,128] + b ----------------
template <int RELU, int STATS>
__global__ __launch_bounds__(256) void gemm_kernel(const float* __restrict__ A,
                                                   const float* __restrict__ W,
                                                   const float* __restrict__ bias,
                                                   float* __restrict__ out, int K,
                                                   float* __restrict__ S1, float* __restrict__ S2,
                                                   float* __restrict__ zinit, int zinit_n) {
    __shared__ float wS[HID * HID];   // up to 64 KB
    __shared__ float zS[16 * 128];    // 8 KB, [k][row]
    int tid = threadIdx.x;
    if (zinit && blockIdx.x == 0) {
        for (int i = tid; i < zinit_n; i += 256) zinit[i] = 0.f;
    }
    for (int i = tid; i < K * HID; i += 256) wS[i] = W[i];

    int row0 = blockIdx.x * 128;
    int tr = tid >> 4;            // 0..15
    int tc = tid & 15;            // 0..15
    int r0 = tr * 8, c0 = tc * 8;
    int lrow = tid >> 1;          // 0..127
    int kg = (tid & 1) * 8;       // 0 or 8

    float acc[8][8];
#pragma unroll
    for (int j = 0; j < 8; ++j)
#pragma unroll
        for (int i = 0; i < 8; ++i) acc[j][i] = 0.f;

    __syncthreads();   // wS ready
    for (int kk0 = 0; kk0 < K; kk0 += 16) {
        float4 v0, v1;
        int grow = row0 + lrow;
        if (grow < N_NODES) {
            const float* ap = A + (size_t)grow * K + kk0 + kg;
            v0 = *(const float4*)ap;
            v1 = *(const float4*)(ap + 4);
        } else {
            v0 = make_float4(0.f, 0.f, 0.f, 0.f);
            v1 = v0;
        }
        zS[(kg + 0) * 128 + lrow] = v0.x;
        zS[(kg + 1) * 128 + lrow] = v0.y;
        zS[(kg + 2) * 128 + lrow] = v0.z;
        zS[(kg + 3) * 128 + lrow] = v0.w;
        zS[(kg + 4) * 128 + lrow] = v1.x;
        zS[(kg + 5) * 128 + lrow] = v1.y;
        zS[(kg + 6) * 128 + lrow] = v1.z;
        zS[(kg + 7) * 128 + lrow] = v1.w;
        __syncthreads();
#pragma unroll
        for (int kk = 0; kk < 16; ++kk) {
            float4 a0 = *(const float4*)&zS[kk * 128 + r0];
            float4 a1 = *(const float4*)&zS[kk * 128 + r0 + 4];
            float4 b0 = *(const float4*)&wS[(kk0 + kk) * HID + c0];
            float4 b1 = *(const float4*)&wS[(kk0 + kk) * HID + c0 + 4];
            float a[8] = {a0.x, a0.y, a0.z, a0.w, a1.x, a1.y, a1.z, a1.w};
            float b[8] = {b0.x, b0.y, b0.z, b0.w, b1.x, b1.y, b1.z, b1.w};
#pragma unroll
            for (int j = 0; j < 8; ++j)
#pragma unroll
                for (int i = 0; i < 8; ++i) acc[j][i] = fmaf(a[j], b[i], acc[j][i]);
        }
        __syncthreads();
    }

    float bcol[8];
#pragma unroll
    for (int i = 0; i < 8; ++i) bcol[i] = bias[c0 + i];
    float s1l[8], s2l[8];
#pragma unroll
    for (int i = 0; i < 8; ++i) { s1l[i] = 0.f; s2l[i] = 0.f; }

#pragma unroll
    for (int j = 0; j < 8; ++j) {
        int row = row0 + r0 + j;
        if (row < N_NODES) {
            float v[8];
#pragma unroll
            for (int i = 0; i < 8; ++i) {
                float t = acc[j][i] + bcol[i];
                if (RELU) t = fmaxf(t, 0.f);
                v[i] = t;
                if (STATS) {
                    s1l[i] += t;
                    s2l[i] += t * t;
                }
            }
            float4 o0 = make_float4(v[0], v[1], v[2], v[3]);
            float4 o1 = make_float4(v[4], v[5], v[6], v[7]);
            *(float4*)&out[(size_t)row * HID + c0] = o0;
            *(float4*)&out[(size_t)row * HID + c0 + 4] = o1;
        }
    }

    if (STATS) {
        float* s1L = zS;
        float* s2L = zS + 128;
        if (tid < 128) { s1L[tid] = 0.f; s2L[tid] = 0.f; }
        __syncthreads();
#pragma unroll
        for (int i = 0; i < 8; ++i) {
            atomicAdd(&s1L[c0 + i], s1l[i]);
            atomicAdd(&s2L[c0 + i], s2l[i]);
        }
        __syncthreads();
        if (tid < 128) {
            atomicAdd(&S1[tid], s1L[tid]);
            atomicAdd(&S2[tid], s2L[tid]);
        }
    }
}

// ---------------- BN apply + relu + segment-sum into vn_up/pool (float4) ----------------
__global__ __launch_bounds__(256) void bn_kernel(const float* __restrict__ z2,
                                                 const float* __restrict__ S1,
                                                 const float* __restrict__ S2,
                                                 const float* __restrict__ gma,
                                                 const float* __restrict__ bta,
                                                 const int* __restrict__ batch,
                                                 float* __restrict__ h, float* __restrict__ up) {
    int tid = threadIdx.x;
    int cg = (tid & 31) * 4;
    int n0 = (blockIdx.x * 8 + (tid >> 5)) * 16;
    const float inv = 1.f / (float)N_NODES;
    float4 s1 = *(const float4*)&S1[cg];
    float4 s2 = *(const float4*)&S2[cg];
    float4 g4 = *(const float4*)&gma[cg];
    float4 b4 = *(const float4*)&bta[cg];
    float mux = s1.x * inv, muy = s1.y * inv, muz = s1.z * inv, muw = s1.w * inv;
    float gmx = g4.x * rsqrtf(s2.x * inv - mux * mux + BN_EPS);
    float gmy = g4.y * rsqrtf(s2.y * inv - muy * muy + BN_EPS);
    float gmz = g4.z * rsqrtf(s2.z * inv - muz * muz + BN_EPS);
    float gmw = g4.w * rsqrtf(s2.w * inv - muw * muw + BN_EPS);

    float4 acc = make_float4(0.f, 0.f, 0.f, 0.f);
    int gcur = -1;
    for (int i = 0; i < 16; ++i) {
        int n = n0 + i;
        if (n >= N_NODES) break;
        float4 v = *(const float4*)&z2[(size_t)n * HID + cg];
        float4 hn;
        hn.x = fmaxf(fmaf(v.x - mux, gmx, b4.x), 0.f);
        hn.y = fmaxf(fmaf(v.y - muy, gmy, b4.y), 0.f);
        hn.z = fmaxf(fmaf(v.z - muz, gmz, b4.z), 0.f);
        hn.w = fmaxf(fmaf(v.w - muw, gmw, b4.w), 0.f);
        *(float4*)&h[(size_t)n * HID + cg] = hn;
        int gb = batch[n];
        if (gb != gcur) {
            if (gcur >= 0) {
                atomicAdd(&up[gcur * HID + cg + 0], acc.x);
                atomicAdd(&up[gcur * HID + cg + 1], acc.y);
                atomicAdd(&up[gcur * HID + cg + 2], acc.z);
                atomicAdd(&up[gcur * HID + cg + 3], acc.w);
            }
            acc = make_float4(0.f, 0.f, 0.f, 0.f);
            gcur = gb;
        }
        acc.x += hn.x; acc.y += hn.y; acc.z += hn.z; acc.w += hn.w;
    }
    if (gcur >= 0) {
        atomicAdd(&up[gcur * HID + cg + 0], acc.x);
        atomicAdd(&up[gcur * HID + cg + 1], acc.y);
        atomicAdd(&up[gcur * HID + cg + 2], acc.z);
        atomicAdd(&up[gcur * HID + cg + 3], acc.w);
    }
}

// ---------------- virtual-node MLP: vn[g] += relu(up[g]@W1+b1)@W2+b2 ----------------
__global__ __launch_bounds__(128) void vnmlp_kernel(const float* __restrict__ up,
                                                    const float* __restrict__ W1,
                                                    const float* __restrict__ b1,
                                                    const float* __restrict__ W2,
                                                    const float* __restrict__ b2,
                                                    float* __restrict__ vn) {
    __shared__ float t[HID];
    int g = blockIdx.x, c = threadIdx.x;
    float s = b1[c];
#pragma unroll 8
    for (int k = 0; k < HID; ++k) s = fmaf(up[g * HID + k], W1[k * HID + c], s);
    t[c] = fmaxf(s, 0.f);
    __syncthreads();
    float s2 = b2[c];
#pragma unroll 8
    for (int k = 0; k < HID; ++k) s2 = fmaf(t[k], W2[k * HID + c], s2);
    vn[g * HID + c] += s2;
}

// ---------------- classifier: logits[g] ----------------
__global__ __launch_bounds__(128) void cls_kernel(const float* __restrict__ pool,
                                                  const int* __restrict__ endpos,
                                                  const float* __restrict__ W1,
                                                  const float* __restrict__ b1,
                                                  const float* __restrict__ W2,
                                                  const float* __restrict__ b2,
                                                  float* __restrict__ out) {
    __shared__ float t[HID];
    __shared__ float red[HID];
    int g = blockIdx.x, c = threadIdx.x;
    int cnt = endpos[g] - (g > 0 ? endpos[g - 1] : 0);
    float cntf = fmaxf((float)cnt, 1.f);
    t[c] = pool[g * HID + c] / cntf;
    __syncthreads();
    float s = b1[c];
#pragma unroll 8
    for (int k = 0; k < HID; ++k) s = fmaf(t[k], W1[k * HID + c], s);
    float y = fmaxf(s, 0.f);
    red[c] = y * W2[c];
    __syncthreads();
    for (int off = 64; off > 0; off >>= 1) {
        if (c < off) red[c] += red[c + off];
        __syncthreads();
    }
    if (c == 0) out[g] = red[0] + b2[0];
}

// ---------------- host-side orchestration ----------------
extern "C" void kernel_launch(void* const* d_in, const int* in_sizes, int n_in,
                              void* d_out, int out_size, void* d_ws, size_t ws_size,
                              hipStream_t stream) {
    const float* x        = (const float*)d_in[0];
    const float* edge_attr= (const float*)d_in[1];
    const int*   edge_idx = (const int*)d_in[2];
    const int*   batch    = (const int*)d_in[3];
    const float* W_in     = (const float*)d_in[4];
    const float* b_in     = (const float*)d_in[5];
    const float* W_e      = (const float*)d_in[6];
    const float* b_e      = (const float*)d_in[7];
    const float* conv_W1  = (const float*)d_in[8];
    const float* conv_b1  = (const float*)d_in[9];
    const float* conv_W2  = (const float*)d_in[10];
    const float* conv_b2  = (const float*)d_in[11];
    const float* bn_g     = (const float*)d_in[12];
    const float* bn_b     = (const float*)d_in[13];
    const float* vn_W1    = (const float*)d_in[14];
    const float* vn_b1    = (const float*)d_in[15];
    const float* vn_W2    = (const float*)d_in[16];
    const float* vn_b2    = (const float*)d_in[17];
    const float* cls_W1   = (const float*)d_in[18];
    const float* cls_b1   = (const float*)d_in[19];
    const float* cls_W2   = (const float*)d_in[20];
    const float* cls_b2   = (const float*)d_in[21];

    char* ws = (char*)d_ws;
    size_t off = 0;
    auto alloc = [&](size_t bytes) -> void* {
        void* p = ws + off;
        off = (off + bytes + 255) & ~(size_t)255;
        return p;
    };
    float* A = (float*)alloc((size_t)N_NODES * HID * 4);   // h / y
    float* B = (float*)alloc((size_t)N_NODES * HID * 4);   // z / z2
    size_t zero_begin = off;
    int*   cnt    = (int*)alloc((size_t)N_NODES * 4);
    float* vn     = (float*)alloc((size_t)NUM_GRAPHS * HID * 4);
    float* pool   = (float*)alloc((size_t)NUM_GRAPHS * HID * 4);
    size_t zero_end = off;
    int*    endpos    = (int*)alloc((size_t)NUM_GRAPHS * 4);
    int*    row_start = (int*)alloc((size_t)(N_NODES + 1) * 4);
    int*    fillp     = (int*)alloc((size_t)N_NODES * 4);
    int*    srcs      = (int*)alloc((size_t)N_EDGES * 4);
    float2* eas       = (float2*)alloc((size_t)N_EDGES * 8);
    float*  vn_up     = (float*)alloc((size_t)NUM_GRAPHS * HID * 4);
    float*  S1        = (float*)alloc((size_t)HID * 4);
    float*  S2        = (float*)alloc((size_t)HID * 4);
    int*    bsum      = (int*)alloc((size_t)SCAN_BLOCKS * 4);
    int*    boff      = (int*)alloc((size_t)SCAN_BLOCKS * 4);
    (void)ws_size; (void)in_sizes; (void)n_in; (void)out_size;

    const int* srcp = edge_idx;
    const int* dstp = edge_idx + N_EDGES;

    int zero_n = (int)((zero_end - zero_begin) / 4);
    zero_kernel<<<(zero_n + 255) / 256, 256, 0, stream>>>((int*)(ws + zero_begin), zero_n);
    hist_kernel<<<(N_EDGES + 255) / 256, 256, 0, stream>>>(dstp, cnt);
    endpos_kernel<<<(N_NODES + 255) / 256, 256, 0, stream>>>(batch, endpos);
    scan1_kernel<<<SCAN_BLOCKS, 1024, 0, stream>>>(cnt, bsum);
    scan2_kernel<<<1, 64, 0, stream>>>(bsum, boff);
    scan3_kernel<<<SCAN_BLOCKS, 1024, 0, stream>>>(cnt, boff, row_start, fillp);
    fill_kernel<<<(N_EDGES + 255) / 256, 256, 0, stream>>>(srcp, dstp, edge_attr, fillp, srcs, eas);

    const int gemm_grid = (N_NODES + 127) / 128;
    // h0 = x @ W_in + b_in
    gemm_kernel<0, 0><<<gemm_grid, 256, 0, stream>>>(x, W_in, b_in, A, IN_DIM,
                                                     nullptr, nullptr, nullptr, 0);

    for (int i = 0; i < NUM_LAYERS; ++i) {
        if (i > 0)
            addvn_kernel<<<(N_NODES * 32 + 255) / 256, 256, 0, stream>>>(A, vn, batch);
        aggr_kernel<<<N_NODES / 8, 256, 0, stream>>>(A, srcs, eas, row_start, W_e, b_e, B, S1, S2);
        gemm_kernel<1, 0><<<gemm_grid, 256, 0, stream>>>(B, conv_W1 + (size_t)i * HID * HID,
                                                         conv_b1 + (size_t)i * HID, A, HID,
                                                         nullptr, nullptr,
                                                         (i < NUM_LAYERS - 1) ? vn_up : nullptr,
                                                         NUM_GRAPHS * HID);
        gemm_kernel<0, 1><<<gemm_grid, 256, 0, stream>>>(A, conv_W2 + (size_t)i * HID * HID,
                                                         conv_b2 + (size_t)i * HID, B, HID,
                                                         S1, S2, nullptr, 0);
        bn_kernel<<<(N_NODES + 127) / 128, 256, 0, stream>>>(B, S1, S2, bn_g + (size_t)i * HID,
                                                             bn_b + (size_t)i * HID, batch, A,
                                                             (i < NUM_LAYERS - 1) ? vn_up : pool);
        if (i < NUM_LAYERS - 1)
            vnmlp_kernel<<<NUM_GRAPHS, 128, 0, stream>>>(vn_up, vn_W1, vn_b1, vn_W2, vn_b2, vn);
    }

    cls_kernel<<<NUM_GRAPHS, 128, 0, stream>>>(pool, endpos, cls_W1, cls_b1, cls_W2, cls_b2,
                                               (float*)d_out);
}

// Round 4
// 757.065 us; speedup vs baseline: 1.8350x; 1.0756x over previous
//
#include <hip/hip_runtime.h>

#define N_NODES 50000
#define N_EDGES 800000
#define IN_DIM 64
#define HID 128
#define NUM_LAYERS 4
#define NUM_GRAPHS 128
#define BN_EPS 1e-5f

typedef __attribute__((ext_vector_type(8))) short short8;
typedef __attribute__((ext_vector_type(4))) float f32x4;

__device__ inline unsigned short f2bf(float f) {
    unsigned int u = __float_as_uint(f);
    u += 0x7FFFu + ((u >> 16) & 1u);   // round-to-nearest-even
    return (unsigned short)(u >> 16);
}

// ---------------- small utility kernels ----------------

__global__ void zero_kernel(int* __restrict__ p, int n) {
    int i = blockIdx.x * blockDim.x + threadIdx.x;
    if (i < n) p[i] = 0;
}

__global__ void hist_kernel(const int* __restrict__ dst, int* __restrict__ cnt) {
    int e = blockIdx.x * blockDim.x + threadIdx.x;
    if (e < N_EDGES) atomicAdd(&cnt[dst[e]], 1);
}

// batch is sorted: endpos[g] = #nodes with batch <= g, written only at run boundaries.
__global__ void endpos_kernel(const int* __restrict__ batch, int* __restrict__ endpos) {
    int n = blockIdx.x * 256 + threadIdx.x;
    if (n >= N_NODES) return;
    int b = batch[n];
    int b1 = (n + 1 < N_NODES) ? batch[n + 1] : NUM_GRAPHS;
    for (int g = b; g < b1; ++g) endpos[g] = n + 1;
    if (n == 0)
        for (int g = 0; g < b; ++g) endpos[g] = 0;
}

// weight prep: transpose + cvt to bf16 once per call.
// wt_in[c][k] (128x64), wt1/wt2[layer][c][k] (4x128x128)
__global__ void wprep_kernel(const float* __restrict__ W_in,
                             const float* __restrict__ conv_W1,
                             const float* __restrict__ conv_W2,
                             unsigned short* __restrict__ wt_in,
                             unsigned short* __restrict__ wt1,
                             unsigned short* __restrict__ wt2) {
    int i = blockIdx.x * 256 + threadIdx.x;
    if (i < 128 * IN_DIM) {
        int c = i >> 6, k = i & 63;
        wt_in[i] = f2bf(W_in[k * HID + c]);
    }
    if (i < 4 * HID * HID) {
        int o = i & (HID * HID - 1);
        int layer = i >> 14;
        int c = o >> 7, k = o & 127;
        wt1[i] = f2bf(conv_W1[layer * HID * HID + k * HID + c]);
        wt2[i] = f2bf(conv_W2[layer * HID * HID + k * HID + c]);
    }
}

// ---------------- 3-stage coalesced exclusive scan over 50000 counters ----------------
#define SCAN_BLOCKS ((N_NODES + 1023) / 1024)   // 49

__global__ __launch_bounds__(1024) void scan1_kernel(const int* __restrict__ cnt,
                                                     int* __restrict__ bsum) {
    __shared__ int ls[1024];
    int t = threadIdx.x;
    int g = blockIdx.x * 1024 + t;
    int v = (g < N_NODES) ? cnt[g] : 0;
    ls[t] = v;
    __syncthreads();
    for (int off = 512; off > 0; off >>= 1) {
        if (t < off) ls[t] += ls[t + off];
        __syncthreads();
    }
    if (t == 0) bsum[blockIdx.x] = ls[0];
}

__global__ void scan2_kernel(const int* __restrict__ bsum, int* __restrict__ boff) {
    if (threadIdx.x == 0) {
        int r = 0;
        for (int i = 0; i < SCAN_BLOCKS; ++i) {
            boff[i] = r;
            r += bsum[i];
        }
    }
}

__global__ __launch_bounds__(1024) void scan3_kernel(const int* __restrict__ cnt,
                                                     const int* __restrict__ boff,
                                                     int* __restrict__ row_start,
                                                     int* __restrict__ fillp) {
    __shared__ int ls[1024];
    int t = threadIdx.x;
    int g = blockIdx.x * 1024 + t;
    int v = (g < N_NODES) ? cnt[g] : 0;
    ls[t] = v;
    __syncthreads();
    for (int off = 1; off < 1024; off <<= 1) {
        int x = (t >= off) ? ls[t - off] : 0;
        __syncthreads();
        ls[t] += x;
        __syncthreads();
    }
    int excl = ls[t] - v + boff[blockIdx.x];
    if (g < N_NODES) {
        row_start[g] = excl;
        fillp[g] = excl;
        if (g == N_NODES - 1) row_start[N_NODES] = excl + v;
    }
}

__global__ void fill_kernel(const int* __restrict__ src, const int* __restrict__ dst,
                            const float* __restrict__ ea, int* __restrict__ fillp,
                            int* __restrict__ srcs, float2* __restrict__ eas) {
    int e = blockIdx.x * blockDim.x + threadIdx.x;
    if (e >= N_EDGES) return;
    int p = atomicAdd(&fillp[dst[e]], 1);
    srcs[p] = src[e];
    eas[p] = make_float2(ea[2 * e], ea[2 * e + 1]);
}

// h[n][cg..cg+3] += vn[batch[n]][cg..cg+3]
__global__ void addvn_kernel(float* __restrict__ h, const float* __restrict__ vn,
                             const int* __restrict__ batch) {
    int idx = blockIdx.x * 256 + threadIdx.x;   // over N_NODES*32
    int n = idx >> 5;
    if (n >= N_NODES) return;
    int cg = (idx & 31) * 4;
    float4 hv = *(const float4*)&h[(size_t)n * HID + cg];
    float4 vv = *(const float4*)&vn[(size_t)batch[n] * HID + cg];
    hv.x += vv.x; hv.y += vv.y; hv.z += vv.z; hv.w += vv.w;
    *(float4*)&h[(size_t)n * HID + cg] = hv;
}

// ---------------- edge aggregation (CSR gather), 8-deep MLP ----------------
// z[n] = h[n] + sum_{edges into n} relu(h[src] + edge_attr @ W_e + b_e)
__global__ __launch_bounds__(256) void aggr_kernel(const float* __restrict__ h,
                                                   const int* __restrict__ srcs,
                                                   const float2* __restrict__ eas,
                                                   const int* __restrict__ row_start,
                                                   const float* __restrict__ We,
                                                   const float* __restrict__ be,
                                                   float* __restrict__ z,
                                                   float* __restrict__ S1,
                                                   float* __restrict__ S2) {
    int tid = threadIdx.x;
    if (blockIdx.x == 0 && tid < HID) {   // zero BN stat accumulators for this layer
        S1[tid] = 0.f;
        S2[tid] = 0.f;
    }
    int cg = (tid & 31) * 4;              // this thread's 4-channel group
    int n = blockIdx.x * 8 + (tid >> 5);  // 8 nodes per 256-thread block (grid exact)

    float4 w0 = *(const float4*)&We[cg];
    float4 w1 = *(const float4*)&We[HID + cg];
    float4 bb = *(const float4*)&be[cg];

    float4 hn = *(const float4*)&h[(size_t)n * HID + cg];   // self term, issued early
    int jb = row_start[n], je = row_start[n + 1];
    float4 acc = make_float4(0.f, 0.f, 0.f, 0.f);

    int j = jb;
    for (; j + 8 <= je; j += 8) {
        int s[8];
        float2 e[8];
        float4 hv[8];
#pragma unroll
        for (int u = 0; u < 8; ++u) s[u] = srcs[j + u];
#pragma unroll
        for (int u = 0; u < 8; ++u) e[u] = eas[j + u];
#pragma unroll
        for (int u = 0; u < 8; ++u) hv[u] = *(const float4*)&h[(size_t)s[u] * HID + cg];
#pragma unroll
        for (int u = 0; u < 8; ++u) {
            float ex = e[u].x, ey = e[u].y;
            acc.x += fmaxf(hv[u].x + fmaf(ex, w0.x, fmaf(ey, w1.x, bb.x)), 0.f);
            acc.y += fmaxf(hv[u].y + fmaf(ex, w0.y, fmaf(ey, w1.y, bb.y)), 0.f);
            acc.z += fmaxf(hv[u].z + fmaf(ex, w0.z, fmaf(ey, w1.z, bb.z)), 0.f);
            acc.w += fmaxf(hv[u].w + fmaf(ex, w0.w, fmaf(ey, w1.w, bb.w)), 0.f);
        }
    }
    if (j + 4 <= je) {
        int s[4];
        float2 e[4];
        float4 hv[4];
#pragma unroll
        for (int u = 0; u < 4; ++u) s[u] = srcs[j + u];
#pragma unroll
        for (int u = 0; u < 4; ++u) e[u] = eas[j + u];
#pragma unroll
        for (int u = 0; u < 4; ++u) hv[u] = *(const float4*)&h[(size_t)s[u] * HID + cg];
#pragma unroll
        for (int u = 0; u < 4; ++u) {
            float ex = e[u].x, ey = e[u].y;
            acc.x += fmaxf(hv[u].x + fmaf(ex, w0.x, fmaf(ey, w1.x, bb.x)), 0.f);
            acc.y += fmaxf(hv[u].y + fmaf(ex, w0.y, fmaf(ey, w1.y, bb.y)), 0.f);
            acc.z += fmaxf(hv[u].z + fmaf(ex, w0.z, fmaf(ey, w1.z, bb.z)), 0.f);
            acc.w += fmaxf(hv[u].w + fmaf(ex, w0.w, fmaf(ey, w1.w, bb.w)), 0.f);
        }
        j += 4;
    }
    for (; j < je; ++j) {
        int s = srcs[j];
        float2 e = eas[j];
        float4 hv = *(const float4*)&h[(size_t)s * HID + cg];
        acc.x += fmaxf(hv.x + fmaf(e.x, w0.x, fmaf(e.y, w1.x, bb.x)), 0.f);
        acc.y += fmaxf(hv.y + fmaf(e.x, w0.y, fmaf(e.y, w1.y, bb.y)), 0.f);
        acc.z += fmaxf(hv.z + fmaf(e.x, w0.z, fmaf(e.y, w1.z, bb.z)), 0.f);
        acc.w += fmaxf(hv.w + fmaf(e.x, w0.w, fmaf(e.y, w1.w, bb.w)), 0.f);
    }

    float4 o = make_float4(hn.x + acc.x, hn.y + acc.y, hn.z + acc.z, hn.w + acc.w);
    *(float4*)&z[(size_t)n * HID + cg] = o;
}

// ---------------- bf16 MFMA GEMM: out[M,128] = A[M,KD] @ W[KD,128] + b ----------------
// 64-row x 128-col block tile, 256 threads = 4 waves, wave w owns rows 16w..16w+15.
// A: f32 in HBM -> bf16 XOR-swizzled LDS. Wt: pre-transposed bf16 [col][k] in HBM.
template <int RELU, int STATS, int KD>
__global__ __launch_bounds__(256) void bgemm_kernel(const float* __restrict__ A,
                                                    const unsigned short* __restrict__ Wt,
                                                    const float* __restrict__ bias,
                                                    float* __restrict__ out,
                                                    float* __restrict__ S1,
                                                    float* __restrict__ S2,
                                                    float* __restrict__ zinit, int zinit_n) {
    __shared__ unsigned short aS[64 * KD];    // [row][k] bf16, byte ^= (row&7)<<4
    __shared__ unsigned short wS[128 * KD];   // [col][k] bf16, byte ^= (col&7)<<4
    __shared__ float sh1[HID], sh2[HID];
    int tid = threadIdx.x;
    if (zinit && blockIdx.x == 0)
        for (int i = tid; i < zinit_n; i += 256) zinit[i] = 0.f;
    if (STATS && tid < HID) { sh1[tid] = 0.f; sh2[tid] = 0.f; }

    int row0 = blockIdx.x * 64;

    // stage A (fully coalesced float4 loads, cvt to bf16, swizzled 8B LDS writes)
    constexpr int AITERS = (64 * KD) / (256 * 4);
#pragma unroll
    for (int it = 0; it < AITERS; ++it) {
        int idx = it * 1024 + tid * 4;     // f32 index in tile
        int r = idx / KD, k = idx % KD;    // compile-time shifts
        int grow = row0 + r;
        float4 v = (grow < N_NODES) ? *(const float4*)&A[(size_t)grow * KD + k]
                                    : make_float4(0.f, 0.f, 0.f, 0.f);
        unsigned int d0 = (unsigned int)f2bf(v.x) | ((unsigned int)f2bf(v.y) << 16);
        unsigned int d1 = (unsigned int)f2bf(v.z) | ((unsigned int)f2bf(v.w) << 16);
        unsigned int byte = (unsigned int)(idx * 2) ^ (unsigned int)((r & 7) << 4);
        *(uint2*)((char*)aS + byte) = make_uint2(d0, d1);
    }
    // stage Wt (bf16 in HBM, coalesced uint4, swizzled 16B LDS writes)
    constexpr int WITERS = (128 * KD) / (256 * 8);
#pragma unroll
    for (int it = 0; it < WITERS; ++it) {
        int idx = it * 2048 + tid * 8;     // bf16 index
        int c = idx / KD;
        uint4 v = *(const uint4*)&Wt[idx];
        unsigned int byte = (unsigned int)(idx * 2) ^ (unsigned int)((c & 7) << 4);
        *(uint4*)((char*)wS + byte) = v;
    }
    __syncthreads();

    int w = tid >> 6, l = tid & 63;
    int arow = 16 * w + (l & 15);
    int kq = (l >> 4) * 8;
    f32x4 acc[8];
#pragma unroll
    for (int t = 0; t < 8; ++t) acc[t] = (f32x4){0.f, 0.f, 0.f, 0.f};

#pragma unroll
    for (int s = 0; s < KD / 32; ++s) {
        int k0 = s * 32 + kq;
        short8 af = *(short8*)((char*)aS +
                               ((unsigned int)((arow * KD + k0) * 2) ^
                                (unsigned int)((arow & 7) << 4)));
#pragma unroll
        for (int t = 0; t < 8; ++t) {
            int col = 16 * t + (l & 15);
            short8 bf = *(short8*)((char*)wS +
                                   ((unsigned int)((col * KD + k0) * 2) ^
                                    (unsigned int)((col & 7) << 4)));
            acc[t] = __builtin_amdgcn_mfma_f32_16x16x32_bf16(af, bf, acc[t], 0, 0, 0);
        }
    }

    // epilogue: bias (+relu) (+stats), D layout: col=lane&15, row=(lane>>4)*4+r
    int rbase = row0 + 16 * w + (l >> 4) * 4;
#pragma unroll
    for (int t = 0; t < 8; ++t) {
        int col = 16 * t + (l & 15);
        float b = bias[col];
        float s1 = 0.f, s2 = 0.f;
#pragma unroll
        for (int r = 0; r < 4; ++r) {
            int grow = rbase + r;
            if (grow < N_NODES) {
                float v = acc[t][r] + b;
                if (RELU) v = fmaxf(v, 0.f);
                out[(size_t)grow * HID + col] = v;
                if (STATS) { s1 += v; s2 += v * v; }
            }
        }
        if (STATS) {
            atomicAdd(&sh1[col], s1);
            atomicAdd(&sh2[col], s2);
        }
    }
    if (STATS) {
        __syncthreads();
        if (tid < HID) {
            atomicAdd(&S1[tid], sh1[tid]);
            atomicAdd(&S2[tid], sh2[tid]);
        }
    }
}

// ---------------- BN apply + relu + segment-sum into vn_up/pool (float4) ----------------
__global__ __launch_bounds__(256) void bn_kernel(const float* __restrict__ z2,
                                                 const float* __restrict__ S1,
                                                 const float* __restrict__ S2,
                                                 const float* __restrict__ gma,
                                                 const float* __restrict__ bta,
                                                 const int* __restrict__ batch,
                                                 float* __restrict__ h, float* __restrict__ up) {
    int tid = threadIdx.x;
    int cg = (tid & 31) * 4;
    int n0 = (blockIdx.x * 8 + (tid >> 5)) * 16;
    const float inv = 1.f / (float)N_NODES;
    float4 s1 = *(const float4*)&S1[cg];
    float4 s2 = *(const float4*)&S2[cg];
    float4 g4 = *(const float4*)&gma[cg];
    float4 b4 = *(const float4*)&bta[cg];
    float mux = s1.x * inv, muy = s1.y * inv, muz = s1.z * inv, muw = s1.w * inv;
    float gmx = g4.x * rsqrtf(s2.x * inv - mux * mux + BN_EPS);
    float gmy = g4.y * rsqrtf(s2.y * inv - muy * muy + BN_EPS);
    float gmz = g4.z * rsqrtf(s2.z * inv - muz * muz + BN_EPS);
    float gmw = g4.w * rsqrtf(s2.w * inv - muw * muw + BN_EPS);

    float4 acc = make_float4(0.f, 0.f, 0.f, 0.f);
    int gcur = -1;
    for (int i = 0; i < 16; ++i) {
        int n = n0 + i;
        if (n >= N_NODES) break;
        float4 v = *(const float4*)&z2[(size_t)n * HID + cg];
        float4 hn;
        hn.x = fmaxf(fmaf(v.x - mux, gmx, b4.x), 0.f);
        hn.y = fmaxf(fmaf(v.y - muy, gmy, b4.y), 0.f);
        hn.z = fmaxf(fmaf(v.z - muz, gmz, b4.z), 0.f);
        hn.w = fmaxf(fmaf(v.w - muw, gmw, b4.w), 0.f);
        *(float4*)&h[(size_t)n * HID + cg] = hn;
        int gb = batch[n];
        if (gb != gcur) {
            if (gcur >= 0) {
                atomicAdd(&up[gcur * HID + cg + 0], acc.x);
                atomicAdd(&up[gcur * HID + cg + 1], acc.y);
                atomicAdd(&up[gcur * HID + cg + 2], acc.z);
                atomicAdd(&up[gcur * HID + cg + 3], acc.w);
            }
            acc = make_float4(0.f, 0.f, 0.f, 0.f);
            gcur = gb;
        }
        acc.x += hn.x; acc.y += hn.y; acc.z += hn.z; acc.w += hn.w;
    }
    if (gcur >= 0) {
        atomicAdd(&up[gcur * HID + cg + 0], acc.x);
        atomicAdd(&up[gcur * HID + cg + 1], acc.y);
        atomicAdd(&up[gcur * HID + cg + 2], acc.z);
        atomicAdd(&up[gcur * HID + cg + 3], acc.w);
    }
}

// ---------------- virtual-node MLP: vn[g] += relu(up[g]@W1+b1)@W2+b2 ----------------
__global__ __launch_bounds__(128) void vnmlp_kernel(const float* __restrict__ up,
                                                    const float* __restrict__ W1,
                                                    const float* __restrict__ b1,
                                                    const float* __restrict__ W2,
                                                    const float* __restrict__ b2,
                                                    float* __restrict__ vn) {
    __shared__ float t[HID];
    int g = blockIdx.x, c = threadIdx.x;
    float s = b1[c];
#pragma unroll 8
    for (int k = 0; k < HID; ++k) s = fmaf(up[g * HID + k], W1[k * HID + c], s);
    t[c] = fmaxf(s, 0.f);
    __syncthreads();
    float s2 = b2[c];
#pragma unroll 8
    for (int k = 0; k < HID; ++k) s2 = fmaf(t[k], W2[k * HID + c], s2);
    vn[g * HID + c] += s2;
}

// ---------------- classifier: logits[g] ----------------
__global__ __launch_bounds__(128) void cls_kernel(const float* __restrict__ pool,
                                                  const int* __restrict__ endpos,
                                                  const float* __restrict__ W1,
                                                  const float* __restrict__ b1,
                                                  const float* __restrict__ W2,
                                                  const float* __restrict__ b2,
                                                  float* __restrict__ out) {
    __shared__ float t[HID];
    __shared__ float red[HID];
    int g = blockIdx.x, c = threadIdx.x;
    int cnt = endpos[g] - (g > 0 ? endpos[g - 1] : 0);
    float cntf = fmaxf((float)cnt, 1.f);
    t[c] = pool[g * HID + c] / cntf;
    __syncthreads();
    float s = b1[c];
#pragma unroll 8
    for (int k = 0; k < HID; ++k) s = fmaf(t[k], W1[k * HID + c], s);
    float y = fmaxf(s, 0.f);
    red[c] = y * W2[c];
    __syncthreads();
    for (int off = 64; off > 0; off >>= 1) {
        if (c < off) red[c] += red[c + off];
        __syncthreads();
    }
    if (c == 0) out[g] = red[0] + b2[0];
}

// ---------------- host-side orchestration ----------------
extern "C" void kernel_launch(void* const* d_in, const int* in_sizes, int n_in,
                              void* d_out, int out_size, void* d_ws, size_t ws_size,
                              hipStream_t stream) {
    const float* x        = (const float*)d_in[0];
    const float* edge_attr= (const float*)d_in[1];
    const int*   edge_idx = (const int*)d_in[2];
    const int*   batch    = (const int*)d_in[3];
    const float* W_in     = (const float*)d_in[4];
    const float* b_in     = (const float*)d_in[5];
    const float* W_e      = (const float*)d_in[6];
    const float* b_e      = (const float*)d_in[7];
    const float* conv_W1  = (const float*)d_in[8];
    const float* conv_b1  = (const float*)d_in[9];
    const float* conv_W2  = (const float*)d_in[10];
    const float* conv_b2  = (const float*)d_in[11];
    const float* bn_g     = (const float*)d_in[12];
    const float* bn_b     = (const float*)d_in[13];
    const float* vn_W1    = (const float*)d_in[14];
    const float* vn_b1    = (const float*)d_in[15];
    const float* vn_W2    = (const float*)d_in[16];
    const float* vn_b2    = (const float*)d_in[17];
    const float* cls_W1   = (const float*)d_in[18];
    const float* cls_b1   = (const float*)d_in[19];
    const float* cls_W2   = (const float*)d_in[20];
    const float* cls_b2   = (const float*)d_in[21];

    char* ws = (char*)d_ws;
    size_t off = 0;
    auto alloc = [&](size_t bytes) -> void* {
        void* p = ws + off;
        off = (off + bytes + 255) & ~(size_t)255;
        return p;
    };
    float* A = (float*)alloc((size_t)N_NODES * HID * 4);   // h / y
    float* B = (float*)alloc((size_t)N_NODES * HID * 4);   // z / z2
    size_t zero_begin = off;
    int*   cnt    = (int*)alloc((size_t)N_NODES * 4);
    float* vn     = (float*)alloc((size_t)NUM_GRAPHS * HID * 4);
    float* pool   = (float*)alloc((size_t)NUM_GRAPHS * HID * 4);
    size_t zero_end = off;
    int*    endpos    = (int*)alloc((size_t)NUM_GRAPHS * 4);
    int*    row_start = (int*)alloc((size_t)(N_NODES + 1) * 4);
    int*    fillp     = (int*)alloc((size_t)N_NODES * 4);
    int*    srcs      = (int*)alloc((size_t)N_EDGES * 4);
    float2* eas       = (float2*)alloc((size_t)N_EDGES * 8);
    float*  vn_up     = (float*)alloc((size_t)NUM_GRAPHS * HID * 4);
    float*  S1        = (float*)alloc((size_t)HID * 4);
    float*  S2        = (float*)alloc((size_t)HID * 4);
    int*    bsum      = (int*)alloc((size_t)SCAN_BLOCKS * 4);
    int*    boff      = (int*)alloc((size_t)SCAN_BLOCKS * 4);
    unsigned short* wt_in = (unsigned short*)alloc((size_t)HID * IN_DIM * 2);
    unsigned short* wt1   = (unsigned short*)alloc((size_t)NUM_LAYERS * HID * HID * 2);
    unsigned short* wt2   = (unsigned short*)alloc((size_t)NUM_LAYERS * HID * HID * 2);
    (void)ws_size; (void)in_sizes; (void)n_in; (void)out_size;

    const int* srcp = edge_idx;
    const int* dstp = edge_idx + N_EDGES;

    int zero_n = (int)((zero_end - zero_begin) / 4);
    zero_kernel<<<(zero_n + 255) / 256, 256, 0, stream>>>((int*)(ws + zero_begin), zero_n);
    hist_kernel<<<(N_EDGES + 255) / 256, 256, 0, stream>>>(dstp, cnt);
    endpos_kernel<<<(N_NODES + 255) / 256, 256, 0, stream>>>(batch, endpos);
    wprep_kernel<<<(4 * HID * HID + 255) / 256, 256, 0, stream>>>(W_in, conv_W1, conv_W2,
                                                                  wt_in, wt1, wt2);
    scan1_kernel<<<SCAN_BLOCKS, 1024, 0, stream>>>(cnt, bsum);
    scan2_kernel<<<1, 64, 0, stream>>>(bsum, boff);
    scan3_kernel<<<SCAN_BLOCKS, 1024, 0, stream>>>(cnt, boff, row_start, fillp);
    fill_kernel<<<(N_EDGES + 255) / 256, 256, 0, stream>>>(srcp, dstp, edge_attr, fillp, srcs, eas);

    const int gemm_grid = (N_NODES + 63) / 64;   // 782
    // h0 = x @ W_in + b_in
    bgemm_kernel<0, 0, IN_DIM><<<gemm_grid, 256, 0, stream>>>(x, wt_in, b_in, A,
                                                              nullptr, nullptr, nullptr, 0);

    for (int i = 0; i < NUM_LAYERS; ++i) {
        if (i > 0)
            addvn_kernel<<<(N_NODES * 32 + 255) / 256, 256, 0, stream>>>(A, vn, batch);
        aggr_kernel<<<N_NODES / 8, 256, 0, stream>>>(A, srcs, eas, row_start, W_e, b_e, B, S1, S2);
        bgemm_kernel<1, 0, HID><<<gemm_grid, 256, 0, stream>>>(
            B, wt1 + (size_t)i * HID * HID, conv_b1 + (size_t)i * HID, A,
            nullptr, nullptr, (i < NUM_LAYERS - 1) ? vn_up : nullptr, NUM_GRAPHS * HID);
        bgemm_kernel<0, 1, HID><<<gemm_grid, 256, 0, stream>>>(
            A, wt2 + (size_t)i * HID * HID, conv_b2 + (size_t)i * HID, B,
            S1, S2, nullptr, 0);
        bn_kernel<<<(N_NODES + 127) / 128, 256, 0, stream>>>(B, S1, S2, bn_g + (size_t)i * HID,
                                                             bn_b + (size_t)i * HID, batch, A,
                                                             (i < NUM_LAYERS - 1) ? vn_up : pool);
        if (i < NUM_LAYERS - 1)
            vnmlp_kernel<<<NUM_GRAPHS, 128, 0, stream>>>(vn_up, vn_W1, vn_b1, vn_W2, vn_b2, vn);
    }

    cls_kernel<<<NUM_GRAPHS, 128, 0, stream>>>(pool, endpos, cls_W1, cls_b1, cls_W2, cls_b2,
                                               (float*)d_out);
}

// Round 5
// 680.316 us; speedup vs baseline: 2.0420x; 1.1128x over previous
//
#include <hip/hip_runtime.h>

#define N_NODES 50000
#define N_EDGES 800000
#define IN_DIM 64
#define HID 128
#define NUM_LAYERS 4
#define NUM_GRAPHS 128
#define BN_EPS 1e-5f

typedef __attribute__((ext_vector_type(8))) short short8;
typedef __attribute__((ext_vector_type(4))) float f32x4;

__device__ inline unsigned short f2bf(float f) {
    unsigned int u = __float_as_uint(f);
    u += 0x7FFFu + ((u >> 16) & 1u);   // round-to-nearest-even
    return (unsigned short)(u >> 16);
}
__device__ inline float bflo(unsigned int p) { return __uint_as_float(p << 16); }
__device__ inline float bfhi(unsigned int p) { return __uint_as_float(p & 0xFFFF0000u); }

// ---------------- small utility kernels ----------------

__global__ void zero_kernel(int* __restrict__ p, int n) {
    int i = blockIdx.x * blockDim.x + threadIdx.x;
    if (i < n) p[i] = 0;
}

// 4 independent atomic chains per thread
__global__ void hist_kernel(const int* __restrict__ dst, int* __restrict__ cnt) {
    int base = blockIdx.x * 1024 + threadIdx.x;
#pragma unroll
    for (int u = 0; u < 4; ++u) {
        int e = base + u * 256;
        if (e < N_EDGES) atomicAdd(&cnt[dst[e]], 1);
    }
}

// batch is sorted: endpos[g] = #nodes with batch <= g, written only at run boundaries.
__global__ void endpos_kernel(const int* __restrict__ batch, int* __restrict__ endpos) {
    int n = blockIdx.x * 256 + threadIdx.x;
    if (n >= N_NODES) return;
    int b = batch[n];
    int b1 = (n + 1 < N_NODES) ? batch[n + 1] : NUM_GRAPHS;
    for (int g = b; g < b1; ++g) endpos[g] = n + 1;
    if (n == 0)
        for (int g = 0; g < b; ++g) endpos[g] = 0;
}

// weight prep: transpose + cvt to bf16 once per call.
__global__ void wprep_kernel(const float* __restrict__ W_in,
                             const float* __restrict__ conv_W1,
                             const float* __restrict__ conv_W2,
                             unsigned short* __restrict__ wt_in,
                             unsigned short* __restrict__ wt1,
                             unsigned short* __restrict__ wt2) {
    int i = blockIdx.x * 256 + threadIdx.x;
    if (i < 128 * IN_DIM) {
        int c = i >> 6, k = i & 63;
        wt_in[i] = f2bf(W_in[k * HID + c]);
    }
    if (i < 4 * HID * HID) {
        int o = i & (HID * HID - 1);
        int layer = i >> 14;
        int c = o >> 7, k = o & 127;
        wt1[i] = f2bf(conv_W1[layer * HID * HID + k * HID + c]);
        wt2[i] = f2bf(conv_W2[layer * HID * HID + k * HID + c]);
    }
}

// ---------------- 3-stage coalesced exclusive scan over 50000 counters ----------------
#define SCAN_BLOCKS ((N_NODES + 1023) / 1024)   // 49

__global__ __launch_bounds__(1024) void scan1_kernel(const int* __restrict__ cnt,
                                                     int* __restrict__ bsum) {
    __shared__ int ls[1024];
    int t = threadIdx.x;
    int g = blockIdx.x * 1024 + t;
    int v = (g < N_NODES) ? cnt[g] : 0;
    ls[t] = v;
    __syncthreads();
    for (int off = 512; off > 0; off >>= 1) {
        if (t < off) ls[t] += ls[t + off];
        __syncthreads();
    }
    if (t == 0) bsum[blockIdx.x] = ls[0];
}

__global__ void scan2_kernel(const int* __restrict__ bsum, int* __restrict__ boff) {
    if (threadIdx.x == 0) {
        int r = 0;
        for (int i = 0; i < SCAN_BLOCKS; ++i) {
            boff[i] = r;
            r += bsum[i];
        }
    }
}

__global__ __launch_bounds__(1024) void scan3_kernel(const int* __restrict__ cnt,
                                                     const int* __restrict__ boff,
                                                     int* __restrict__ row_start,
                                                     int* __restrict__ fillp) {
    __shared__ int ls[1024];
    int t = threadIdx.x;
    int g = blockIdx.x * 1024 + t;
    int v = (g < N_NODES) ? cnt[g] : 0;
    ls[t] = v;
    __syncthreads();
    for (int off = 1; off < 1024; off <<= 1) {
        int x = (t >= off) ? ls[t - off] : 0;
        __syncthreads();
        ls[t] += x;
        __syncthreads();
    }
    int excl = ls[t] - v + boff[blockIdx.x];
    if (g < N_NODES) {
        row_start[g] = excl;
        fillp[g] = excl;
        if (g == N_NODES - 1) row_start[N_NODES] = excl + v;
    }
}

// 4 independent chains per thread
__global__ void fill_kernel(const int* __restrict__ src, const int* __restrict__ dst,
                            const float* __restrict__ ea, int* __restrict__ fillp,
                            int* __restrict__ srcs, float2* __restrict__ eas) {
    int base = blockIdx.x * 1024 + threadIdx.x;
#pragma unroll
    for (int u = 0; u < 4; ++u) {
        int e = base + u * 256;
        if (e < N_EDGES) {
            int p = atomicAdd(&fillp[dst[e]], 1);
            srcs[p] = src[e];
            eas[p] = make_float2(ea[2 * e], ea[2 * e + 1]);
        }
    }
}

// h[n][cg..] += vn[batch[n]][cg..]; also refresh bf16 shadow
__global__ void addvn_kernel(float* __restrict__ h, unsigned short* __restrict__ hbf,
                             const float* __restrict__ vn, const int* __restrict__ batch) {
    int idx = blockIdx.x * 256 + threadIdx.x;   // over N_NODES*32
    int n = idx >> 5;
    if (n >= N_NODES) return;
    int cg = (idx & 31) * 4;
    float4 hv = *(const float4*)&h[(size_t)n * HID + cg];
    float4 vv = *(const float4*)&vn[(size_t)batch[n] * HID + cg];
    hv.x += vv.x; hv.y += vv.y; hv.z += vv.z; hv.w += vv.w;
    *(float4*)&h[(size_t)n * HID + cg] = hv;
    uint2 pk;
    pk.x = (unsigned int)f2bf(hv.x) | ((unsigned int)f2bf(hv.y) << 16);
    pk.y = (unsigned int)f2bf(hv.z) | ((unsigned int)f2bf(hv.w) << 16);
    *(uint2*)&hbf[(size_t)n * HID + cg] = pk;
}

// ---------------- edge aggregation (CSR gather from bf16 shadow) ----------------
// z[n] = h[n] + sum_{edges into n} relu(hbf[src] + edge_attr @ W_e + b_e); z stored bf16
__global__ __launch_bounds__(256) void aggr_kernel(const float* __restrict__ h,
                                                   const unsigned short* __restrict__ hbf,
                                                   const int* __restrict__ srcs,
                                                   const float2* __restrict__ eas,
                                                   const int* __restrict__ row_start,
                                                   const float* __restrict__ We,
                                                   const float* __restrict__ be,
                                                   unsigned short* __restrict__ zbf,
                                                   float* __restrict__ S1,
                                                   float* __restrict__ S2) {
    int tid = threadIdx.x;
    if (blockIdx.x == 0 && tid < HID) {   // zero BN stat accumulators for this layer
        S1[tid] = 0.f;
        S2[tid] = 0.f;
    }
    int cg = (tid & 31) * 4;              // this thread's 4-channel group
    int n = blockIdx.x * 8 + (tid >> 5);  // 8 nodes per 256-thread block (grid exact)

    float4 w0 = *(const float4*)&We[cg];
    float4 w1 = *(const float4*)&We[HID + cg];
    float4 bb = *(const float4*)&be[cg];

    float4 hn = *(const float4*)&h[(size_t)n * HID + cg];   // self term, f32
    int jb = row_start[n], je = row_start[n + 1];
    float4 acc = make_float4(0.f, 0.f, 0.f, 0.f);

    int j = jb;
    for (; j + 8 <= je; j += 8) {
        int s[8];
        float2 e[8];
        uint2 q[8];
#pragma unroll
        for (int u = 0; u < 8; ++u) s[u] = srcs[j + u];
#pragma unroll
        for (int u = 0; u < 8; ++u) e[u] = eas[j + u];
#pragma unroll
        for (int u = 0; u < 8; ++u) q[u] = *(const uint2*)&hbf[(size_t)s[u] * HID + cg];
#pragma unroll
        for (int u = 0; u < 8; ++u) {
            float ex = e[u].x, ey = e[u].y;
            acc.x += fmaxf(bflo(q[u].x) + fmaf(ex, w0.x, fmaf(ey, w1.x, bb.x)), 0.f);
            acc.y += fmaxf(bfhi(q[u].x) + fmaf(ex, w0.y, fmaf(ey, w1.y, bb.y)), 0.f);
            acc.z += fmaxf(bflo(q[u].y) + fmaf(ex, w0.z, fmaf(ey, w1.z, bb.z)), 0.f);
            acc.w += fmaxf(bfhi(q[u].y) + fmaf(ex, w0.w, fmaf(ey, w1.w, bb.w)), 0.f);
        }
    }
    if (j + 4 <= je) {
        int s[4];
        float2 e[4];
        uint2 q[4];
#pragma unroll
        for (int u = 0; u < 4; ++u) s[u] = srcs[j + u];
#pragma unroll
        for (int u = 0; u < 4; ++u) e[u] = eas[j + u];
#pragma unroll
        for (int u = 0; u < 4; ++u) q[u] = *(const uint2*)&hbf[(size_t)s[u] * HID + cg];
#pragma unroll
        for (int u = 0; u < 4; ++u) {
            float ex = e[u].x, ey = e[u].y;
            acc.x += fmaxf(bflo(q[u].x) + fmaf(ex, w0.x, fmaf(ey, w1.x, bb.x)), 0.f);
            acc.y += fmaxf(bfhi(q[u].x) + fmaf(ex, w0.y, fmaf(ey, w1.y, bb.y)), 0.f);
            acc.z += fmaxf(bflo(q[u].y) + fmaf(ex, w0.z, fmaf(ey, w1.z, bb.z)), 0.f);
            acc.w += fmaxf(bfhi(q[u].y) + fmaf(ex, w0.w, fmaf(ey, w1.w, bb.w)), 0.f);
        }
        j += 4;
    }
    for (; j < je; ++j) {
        int s = srcs[j];
        float2 e = eas[j];
        uint2 q = *(const uint2*)&hbf[(size_t)s * HID + cg];
        acc.x += fmaxf(bflo(q.x) + fmaf(e.x, w0.x, fmaf(e.y, w1.x, bb.x)), 0.f);
        acc.y += fmaxf(bfhi(q.x) + fmaf(e.x, w0.y, fmaf(e.y, w1.y, bb.y)), 0.f);
        acc.z += fmaxf(bflo(q.y) + fmaf(e.x, w0.z, fmaf(e.y, w1.z, bb.z)), 0.f);
        acc.w += fmaxf(bfhi(q.y) + fmaf(e.x, w0.w, fmaf(e.y, w1.w, bb.w)), 0.f);
    }

    uint2 pk;
    pk.x = (unsigned int)f2bf(hn.x + acc.x) | ((unsigned int)f2bf(hn.y + acc.y) << 16);
    pk.y = (unsigned int)f2bf(hn.z + acc.z) | ((unsigned int)f2bf(hn.w + acc.w) << 16);
    *(uint2*)&zbf[(size_t)n * HID + cg] = pk;
}

// ---------------- bf16 MFMA GEMM: out[M,128] = A[M,KD] @ W[KD,128] + b ----------------
// 64x128 tile, 256 threads = 4 waves. ABF: A is bf16. OMODE: 0=f32, 1=bf16, 2=both.
template <int RELU, int STATS, int KD, int ABF, int OMODE>
__global__ __launch_bounds__(256) void bgemm_kernel(const void* __restrict__ Av,
                                                    const unsigned short* __restrict__ Wt,
                                                    const float* __restrict__ bias,
                                                    float* __restrict__ out,
                                                    unsigned short* __restrict__ outbf,
                                                    float* __restrict__ S1,
                                                    float* __restrict__ S2,
                                                    float* __restrict__ zinit, int zinit_n) {
    __shared__ unsigned short aS[64 * KD];    // [row][k] bf16, byte ^= (row&7)<<4
    __shared__ unsigned short wS[128 * KD];   // [col][k] bf16, byte ^= (col&7)<<4
    __shared__ float sh1[HID], sh2[HID];
    int tid = threadIdx.x;
    if (zinit && blockIdx.x == 0)
        for (int i = tid; i < zinit_n; i += 256) zinit[i] = 0.f;
    if (STATS && tid < HID) { sh1[tid] = 0.f; sh2[tid] = 0.f; }

    int row0 = blockIdx.x * 64;

    if constexpr (!ABF) {
        const float* A = (const float*)Av;
        constexpr int AITERS = (64 * KD) / (256 * 4);
#pragma unroll
        for (int it = 0; it < AITERS; ++it) {
            int idx = it * 1024 + tid * 4;
            int r = idx / KD, k = idx % KD;
            int grow = row0 + r;
            float4 v = (grow < N_NODES) ? *(const float4*)&A[(size_t)grow * KD + k]
                                        : make_float4(0.f, 0.f, 0.f, 0.f);
            unsigned int d0 = (unsigned int)f2bf(v.x) | ((unsigned int)f2bf(v.y) << 16);
            unsigned int d1 = (unsigned int)f2bf(v.z) | ((unsigned int)f2bf(v.w) << 16);
            unsigned int byte = (unsigned int)(idx * 2) ^ (unsigned int)((r & 7) << 4);
            *(uint2*)((char*)aS + byte) = make_uint2(d0, d1);
        }
    } else {
        const unsigned short* A = (const unsigned short*)Av;
        constexpr int AITERS = (64 * KD) / (256 * 8);
#pragma unroll
        for (int it = 0; it < AITERS; ++it) {
            int idx = it * 2048 + tid * 8;
            int r = idx / KD, k = idx % KD;
            int grow = row0 + r;
            uint4 v = (grow < N_NODES) ? *(const uint4*)&A[(size_t)grow * KD + k]
                                       : make_uint4(0u, 0u, 0u, 0u);
            unsigned int byte = (unsigned int)(idx * 2) ^ (unsigned int)((r & 7) << 4);
            *(uint4*)((char*)wS + 0) = *(uint4*)((char*)wS + 0);  // no-op guard against elision
            *(uint4*)((char*)aS + byte) = v;
        }
    }
    constexpr int WITERS = (128 * KD) / (256 * 8);
#pragma unroll
    for (int it = 0; it < WITERS; ++it) {
        int idx = it * 2048 + tid * 8;
        int c = idx / KD;
        uint4 v = *(const uint4*)&Wt[idx];
        unsigned int byte = (unsigned int)(idx * 2) ^ (unsigned int)((c & 7) << 4);
        *(uint4*)((char*)wS + byte) = v;
    }
    __syncthreads();

    int w = tid >> 6, l = tid & 63;
    int arow = 16 * w + (l & 15);
    int kq = (l >> 4) * 8;
    f32x4 acc[8];
#pragma unroll
    for (int t = 0; t < 8; ++t) acc[t] = (f32x4){0.f, 0.f, 0.f, 0.f};

#pragma unroll
    for (int s = 0; s < KD / 32; ++s) {
        int k0 = s * 32 + kq;
        short8 af = *(short8*)((char*)aS +
                               ((unsigned int)((arow * KD + k0) * 2) ^
                                (unsigned int)((arow & 7) << 4)));
#pragma unroll
        for (int t = 0; t < 8; ++t) {
            int col = 16 * t + (l & 15);
            short8 bf = *(short8*)((char*)wS +
                                   ((unsigned int)((col * KD + k0) * 2) ^
                                    (unsigned int)((col & 7) << 4)));
            acc[t] = __builtin_amdgcn_mfma_f32_16x16x32_bf16(af, bf, acc[t], 0, 0, 0);
        }
    }

    // epilogue: bias (+relu) (+stats); D layout: col=lane&15, row=(lane>>4)*4+r
    int rbase = row0 + 16 * w + (l >> 4) * 4;
#pragma unroll
    for (int t = 0; t < 8; ++t) {
        int col = 16 * t + (l & 15);
        float b = bias[col];
        float s1 = 0.f, s2 = 0.f;
#pragma unroll
        for (int r = 0; r < 4; ++r) {
            int grow = rbase + r;
            if (grow < N_NODES) {
                float v = acc[t][r] + b;
                if (RELU) v = fmaxf(v, 0.f);
                if (OMODE == 0 || OMODE == 2) out[(size_t)grow * HID + col] = v;
                if (OMODE == 1 || OMODE == 2) outbf[(size_t)grow * HID + col] = f2bf(v);
                if (STATS) { s1 += v; s2 += v * v; }
            }
        }
        if (STATS) {
            atomicAdd(&sh1[col], s1);
            atomicAdd(&sh2[col], s2);
        }
    }
    if (STATS) {
        __syncthreads();
        if (tid < HID) {
            atomicAdd(&S1[tid], sh1[tid]);
            atomicAdd(&S2[tid], sh2[tid]);
        }
    }
}

// ---------------- BN apply + relu + segment-sum into vn_up/pool (float4) ----------------
__global__ __launch_bounds__(256) void bn_kernel(const float* __restrict__ z2,
                                                 const float* __restrict__ S1,
                                                 const float* __restrict__ S2,
                                                 const float* __restrict__ gma,
                                                 const float* __restrict__ bta,
                                                 const int* __restrict__ batch,
                                                 float* __restrict__ h,
                                                 unsigned short* __restrict__ hbf,
                                                 float* __restrict__ up) {
    int tid = threadIdx.x;
    int cg = (tid & 31) * 4;
    int n0 = (blockIdx.x * 8 + (tid >> 5)) * 16;
    const float inv = 1.f / (float)N_NODES;
    float4 s1 = *(const float4*)&S1[cg];
    float4 s2 = *(const float4*)&S2[cg];
    float4 g4 = *(const float4*)&gma[cg];
    float4 b4 = *(const float4*)&bta[cg];
    float mux = s1.x * inv, muy = s1.y * inv, muz = s1.z * inv, muw = s1.w * inv;
    float gmx = g4.x * rsqrtf(s2.x * inv - mux * mux + BN_EPS);
    float gmy = g4.y * rsqrtf(s2.y * inv - muy * muy + BN_EPS);
    float gmz = g4.z * rsqrtf(s2.z * inv - muz * muz + BN_EPS);
    float gmw = g4.w * rsqrtf(s2.w * inv - muw * muw + BN_EPS);

    float4 acc = make_float4(0.f, 0.f, 0.f, 0.f);
    int gcur = -1;
    for (int i = 0; i < 16; ++i) {
        int n = n0 + i;
        if (n >= N_NODES) break;
        float4 v = *(const float4*)&z2[(size_t)n * HID + cg];
        float4 hn;
        hn.x = fmaxf(fmaf(v.x - mux, gmx, b4.x), 0.f);
        hn.y = fmaxf(fmaf(v.y - muy, gmy, b4.y), 0.f);
        hn.z = fmaxf(fmaf(v.z - muz, gmz, b4.z), 0.f);
        hn.w = fmaxf(fmaf(v.w - muw, gmw, b4.w), 0.f);
        *(float4*)&h[(size_t)n * HID + cg] = hn;
        uint2 pk;
        pk.x = (unsigned int)f2bf(hn.x) | ((unsigned int)f2bf(hn.y) << 16);
        pk.y = (unsigned int)f2bf(hn.z) | ((unsigned int)f2bf(hn.w) << 16);
        *(uint2*)&hbf[(size_t)n * HID + cg] = pk;
        int gb = batch[n];
        if (gb != gcur) {
            if (gcur >= 0) {
                atomicAdd(&up[gcur * HID + cg + 0], acc.x);
                atomicAdd(&up[gcur * HID + cg + 1], acc.y);
                atomicAdd(&up[gcur * HID + cg + 2], acc.z);
                atomicAdd(&up[gcur * HID + cg + 3], acc.w);
            }
            acc = make_float4(0.f, 0.f, 0.f, 0.f);
            gcur = gb;
        }
        acc.x += hn.x; acc.y += hn.y; acc.z += hn.z; acc.w += hn.w;
    }
    if (gcur >= 0) {
        atomicAdd(&up[gcur * HID + cg + 0], acc.x);
        atomicAdd(&up[gcur * HID + cg + 1], acc.y);
        atomicAdd(&up[gcur * HID + cg + 2], acc.z);
        atomicAdd(&up[gcur * HID + cg + 3], acc.w);
    }
}

// ---------------- virtual-node MLP: vn[g] += relu(up[g]@W1+b1)@W2+b2 ----------------
__global__ __launch_bounds__(128) void vnmlp_kernel(const float* __restrict__ up,
                                                    const float* __restrict__ W1,
                                                    const float* __restrict__ b1,
                                                    const float* __restrict__ W2,
                                                    const float* __restrict__ b2,
                                                    float* __restrict__ vn) {
    __shared__ float t[HID];
    int g = blockIdx.x, c = threadIdx.x;
    float s = b1[c];
#pragma unroll 8
    for (int k = 0; k < HID; ++k) s = fmaf(up[g * HID + k], W1[k * HID + c], s);
    t[c] = fmaxf(s, 0.f);
    __syncthreads();
    float s2 = b2[c];
#pragma unroll 8
    for (int k = 0; k < HID; ++k) s2 = fmaf(t[k], W2[k * HID + c], s2);
    vn[g * HID + c] += s2;
}

// ---------------- classifier: logits[g] ----------------
__global__ __launch_bounds__(128) void cls_kernel(const float* __restrict__ pool,
                                                  const int* __restrict__ endpos,
                                                  const float* __restrict__ W1,
                                                  const float* __restrict__ b1,
                                                  const float* __restrict__ W2,
                                                  const float* __restrict__ b2,
                                                  float* __restrict__ out) {
    __shared__ float t[HID];
    __shared__ float red[HID];
    int g = blockIdx.x, c = threadIdx.x;
    int cnt = endpos[g] - (g > 0 ? endpos[g - 1] : 0);
    float cntf = fmaxf((float)cnt, 1.f);
    t[c] = pool[g * HID + c] / cntf;
    __syncthreads();
    float s = b1[c];
#pragma unroll 8
    for (int k = 0; k < HID; ++k) s = fmaf(t[k], W1[k * HID + c], s);
    float y = fmaxf(s, 0.f);
    red[c] = y * W2[c];
    __syncthreads();
    for (int off = 64; off > 0; off >>= 1) {
        if (c < off) red[c] += red[c + off];
        __syncthreads();
    }
    if (c == 0) out[g] = red[0] + b2[0];
}

// ---------------- host-side orchestration ----------------
extern "C" void kernel_launch(void* const* d_in, const int* in_sizes, int n_in,
                              void* d_out, int out_size, void* d_ws, size_t ws_size,
                              hipStream_t stream) {
    const float* x        = (const float*)d_in[0];
    const float* edge_attr= (const float*)d_in[1];
    const int*   edge_idx = (const int*)d_in[2];
    const int*   batch    = (const int*)d_in[3];
    const float* W_in     = (const float*)d_in[4];
    const float* b_in     = (const float*)d_in[5];
    const float* W_e      = (const float*)d_in[6];
    const float* b_e      = (const float*)d_in[7];
    const float* conv_W1  = (const float*)d_in[8];
    const float* conv_b1  = (const float*)d_in[9];
    const float* conv_W2  = (const float*)d_in[10];
    const float* conv_b2  = (const float*)d_in[11];
    const float* bn_g     = (const float*)d_in[12];
    const float* bn_b     = (const float*)d_in[13];
    const float* vn_W1    = (const float*)d_in[14];
    const float* vn_b1    = (const float*)d_in[15];
    const float* vn_W2    = (const float*)d_in[16];
    const float* vn_b2    = (const float*)d_in[17];
    const float* cls_W1   = (const float*)d_in[18];
    const float* cls_b1   = (const float*)d_in[19];
    const float* cls_W2   = (const float*)d_in[20];
    const float* cls_b2   = (const float*)d_in[21];

    char* ws = (char*)d_ws;
    size_t off = 0;
    auto alloc = [&](size_t bytes) -> void* {
        void* p = ws + off;
        off = (off + bytes + 255) & ~(size_t)255;
        return p;
    };
    float* A = (float*)alloc((size_t)N_NODES * HID * 4);   // h (f32)
    float* B = (float*)alloc((size_t)N_NODES * HID * 4);   // z2 (f32)
    unsigned short* hbf = (unsigned short*)alloc((size_t)N_NODES * HID * 2);
    unsigned short* zbf = (unsigned short*)alloc((size_t)N_NODES * HID * 2);
    unsigned short* ybf = (unsigned short*)alloc((size_t)N_NODES * HID * 2);
    size_t zero_begin = off;
    int*   cnt    = (int*)alloc((size_t)N_NODES * 4);
    float* vn     = (float*)alloc((size_t)NUM_GRAPHS * HID * 4);
    float* pool   = (float*)alloc((size_t)NUM_GRAPHS * HID * 4);
    size_t zero_end = off;
    int*    endpos    = (int*)alloc((size_t)NUM_GRAPHS * 4);
    int*    row_start = (int*)alloc((size_t)(N_NODES + 1) * 4);
    int*    fillp     = (int*)alloc((size_t)N_NODES * 4);
    int*    srcs      = (int*)alloc((size_t)N_EDGES * 4);
    float2* eas       = (float2*)alloc((size_t)N_EDGES * 8);
    float*  vn_up     = (float*)alloc((size_t)NUM_GRAPHS * HID * 4);
    float*  S1        = (float*)alloc((size_t)HID * 4);
    float*  S2        = (float*)alloc((size_t)HID * 4);
    int*    bsum      = (int*)alloc((size_t)SCAN_BLOCKS * 4);
    int*    boff      = (int*)alloc((size_t)SCAN_BLOCKS * 4);
    unsigned short* wt_in = (unsigned short*)alloc((size_t)HID * IN_DIM * 2);
    unsigned short* wt1   = (unsigned short*)alloc((size_t)NUM_LAYERS * HID * HID * 2);
    unsigned short* wt2   = (unsigned short*)alloc((size_t)NUM_LAYERS * HID * HID * 2);
    (void)ws_size; (void)in_sizes; (void)n_in; (void)out_size;

    const int* srcp = edge_idx;
    const int* dstp = edge_idx + N_EDGES;

    int zero_n = (int)((zero_end - zero_begin) / 4);
    zero_kernel<<<(zero_n + 255) / 256, 256, 0, stream>>>((int*)(ws + zero_begin), zero_n);
    hist_kernel<<<(N_EDGES + 1023) / 1024, 256, 0, stream>>>(dstp, cnt);
    endpos_kernel<<<(N_NODES + 255) / 256, 256, 0, stream>>>(batch, endpos);
    wprep_kernel<<<(4 * HID * HID + 255) / 256, 256, 0, stream>>>(W_in, conv_W1, conv_W2,
                                                                  wt_in, wt1, wt2);
    scan1_kernel<<<SCAN_BLOCKS, 1024, 0, stream>>>(cnt, bsum);
    scan2_kernel<<<1, 64, 0, stream>>>(bsum, boff);
    scan3_kernel<<<SCAN_BLOCKS, 1024, 0, stream>>>(cnt, boff, row_start, fillp);
    fill_kernel<<<(N_EDGES + 1023) / 1024, 256, 0, stream>>>(srcp, dstp, edge_attr, fillp,
                                                             srcs, eas);

    const int gemm_grid = (N_NODES + 63) / 64;   // 782
    // h0 = x @ W_in + b_in  (f32 h + bf16 shadow)
    bgemm_kernel<0, 0, IN_DIM, 0, 2><<<gemm_grid, 256, 0, stream>>>(
        x, wt_in, b_in, A, hbf, nullptr, nullptr, nullptr, 0);

    for (int i = 0; i < NUM_LAYERS; ++i) {
        if (i > 0)
            addvn_kernel<<<(N_NODES * 32 + 255) / 256, 256, 0, stream>>>(A, hbf, vn, batch);
        aggr_kernel<<<N_NODES / 8, 256, 0, stream>>>(A, hbf, srcs, eas, row_start, W_e, b_e,
                                                     zbf, S1, S2);
        bgemm_kernel<1, 0, HID, 1, 1><<<gemm_grid, 256, 0, stream>>>(
            zbf, wt1 + (size_t)i * HID * HID, conv_b1 + (size_t)i * HID, nullptr, ybf,
            nullptr, nullptr, (i < NUM_LAYERS - 1) ? vn_up : nullptr, NUM_GRAPHS * HID);
        bgemm_kernel<0, 1, HID, 1, 0><<<gemm_grid, 256, 0, stream>>>(
            ybf, wt2 + (size_t)i * HID * HID, conv_b2 + (size_t)i * HID, B, nullptr,
            S1, S2, nullptr, 0);
        bn_kernel<<<(N_NODES + 127) / 128, 256, 0, stream>>>(B, S1, S2, bn_g + (size_t)i * HID,
                                                             bn_b + (size_t)i * HID, batch,
                                                             A, hbf,
                                                             (i < NUM_LAYERS - 1) ? vn_up : pool);
        if (i < NUM_LAYERS - 1)
            vnmlp_kernel<<<NUM_GRAPHS, 128, 0, stream>>>(vn_up, vn_W1, vn_b1, vn_W2, vn_b2, vn);
    }

    cls_kernel<<<NUM_GRAPHS, 128, 0, stream>>>(pool, endpos, cls_W1, cls_b1, cls_W2, cls_b2,
                                               (float*)d_out);
}

// Round 6
// 663.713 us; speedup vs baseline: 2.0931x; 1.0250x over previous
//
#include <hip/hip_runtime.h>

#define N_NODES 50000
#define N_EDGES 800000
#define IN_DIM 64
#define HID 128
#define NUM_LAYERS 4
#define NUM_GRAPHS 128
#define BN_EPS 1e-5f

typedef __attribute__((ext_vector_type(8))) short short8;
typedef __attribute__((ext_vector_type(4))) float f32x4;

__device__ inline unsigned short f2bf(float f) {
    unsigned int u = __float_as_uint(f);
    u += 0x7FFFu + ((u >> 16) & 1u);   // round-to-nearest-even
    return (unsigned short)(u >> 16);
}
__device__ inline float bflo(unsigned int p) { return __uint_as_float(p << 16); }
__device__ inline float bfhi(unsigned int p) { return __uint_as_float(p & 0xFFFF0000u); }

// ---------------- small utility kernels ----------------

// 4 independent atomic chains per thread
__global__ void hist_kernel(const int* __restrict__ dst, int* __restrict__ cnt) {
    int base = blockIdx.x * 1024 + threadIdx.x;
#pragma unroll
    for (int u = 0; u < 4; ++u) {
        int e = base + u * 256;
        if (e < N_EDGES) atomicAdd(&cnt[dst[e]], 1);
    }
}

// batch is sorted: endpos[g] = #nodes with batch <= g, written only at run boundaries.
__global__ void endpos_kernel(const int* __restrict__ batch, int* __restrict__ endpos) {
    int n = blockIdx.x * 256 + threadIdx.x;
    if (n >= N_NODES) return;
    int b = batch[n];
    int b1 = (n + 1 < N_NODES) ? batch[n + 1] : NUM_GRAPHS;
    for (int g = b; g < b1; ++g) endpos[g] = n + 1;
    if (n == 0)
        for (int g = 0; g < b; ++g) endpos[g] = 0;
}

// weight prep: transpose + cvt to bf16 once per call.
__global__ void wprep_kernel(const float* __restrict__ W_in,
                             const float* __restrict__ conv_W1,
                             const float* __restrict__ conv_W2,
                             unsigned short* __restrict__ wt_in,
                             unsigned short* __restrict__ wt1,
                             unsigned short* __restrict__ wt2) {
    int i = blockIdx.x * 256 + threadIdx.x;
    if (i < 128 * IN_DIM) {
        int c = i >> 6, k = i & 63;
        wt_in[i] = f2bf(W_in[k * HID + c]);
    }
    if (i < 4 * HID * HID) {
        int o = i & (HID * HID - 1);
        int layer = i >> 14;
        int c = o >> 7, k = o & 127;
        wt1[i] = f2bf(conv_W1[layer * HID * HID + k * HID + c]);
        wt2[i] = f2bf(conv_W2[layer * HID * HID + k * HID + c]);
    }
}

// ---------------- 3-stage coalesced exclusive scan over 50000 counters ----------------
#define SCAN_BLOCKS ((N_NODES + 1023) / 1024)   // 49

__global__ __launch_bounds__(1024) void scan1_kernel(const int* __restrict__ cnt,
                                                     int* __restrict__ bsum) {
    __shared__ int ls[1024];
    int t = threadIdx.x;
    int g = blockIdx.x * 1024 + t;
    int v = (g < N_NODES) ? cnt[g] : 0;
    ls[t] = v;
    __syncthreads();
    for (int off = 512; off > 0; off >>= 1) {
        if (t < off) ls[t] += ls[t + off];
        __syncthreads();
    }
    if (t == 0) bsum[blockIdx.x] = ls[0];
}

__global__ void scan2_kernel(const int* __restrict__ bsum, int* __restrict__ boff) {
    if (threadIdx.x == 0) {
        int r = 0;
        for (int i = 0; i < SCAN_BLOCKS; ++i) {
            boff[i] = r;
            r += bsum[i];
        }
    }
}

__global__ __launch_bounds__(1024) void scan3_kernel(const int* __restrict__ cnt,
                                                     const int* __restrict__ boff,
                                                     int* __restrict__ row_start,
                                                     int* __restrict__ fillp) {
    __shared__ int ls[1024];
    int t = threadIdx.x;
    int g = blockIdx.x * 1024 + t;
    int v = (g < N_NODES) ? cnt[g] : 0;
    ls[t] = v;
    __syncthreads();
    for (int off = 1; off < 1024; off <<= 1) {
        int x = (t >= off) ? ls[t - off] : 0;
        __syncthreads();
        ls[t] += x;
        __syncthreads();
    }
    int excl = ls[t] - v + boff[blockIdx.x];
    if (g < N_NODES) {
        row_start[g] = excl;
        fillp[g] = excl;
        if (g == N_NODES - 1) row_start[N_NODES] = excl + v;
    }
}

// one 16B record per edge: {src, ea.x bits, ea.y bits, 0}; 4 independent chains/thread
__global__ void fill_kernel(const int* __restrict__ src, const int* __restrict__ dst,
                            const float* __restrict__ ea, int* __restrict__ fillp,
                            int4* __restrict__ edges) {
    int base = blockIdx.x * 1024 + threadIdx.x;
#pragma unroll
    for (int u = 0; u < 4; ++u) {
        int e = base + u * 256;
        if (e < N_EDGES) {
            float2 a = *(const float2*)&ea[2 * e];
            int p = atomicAdd(&fillp[dst[e]], 1);
            edges[p] = make_int4(src[e], __float_as_int(a.x), __float_as_int(a.y), 0);
        }
    }
}

// h[n][cg..] += vn[batch[n]][cg..]; also refresh bf16 shadow
__global__ void addvn_kernel(float* __restrict__ h, unsigned short* __restrict__ hbf,
                             const float* __restrict__ vn, const int* __restrict__ batch) {
    int idx = blockIdx.x * 256 + threadIdx.x;   // over N_NODES*32
    int n = idx >> 5;
    if (n >= N_NODES) return;
    int cg = (idx & 31) * 4;
    float4 hv = *(const float4*)&h[(size_t)n * HID + cg];
    float4 vv = *(const float4*)&vn[(size_t)batch[n] * HID + cg];
    hv.x += vv.x; hv.y += vv.y; hv.z += vv.z; hv.w += vv.w;
    *(float4*)&h[(size_t)n * HID + cg] = hv;
    uint2 pk;
    pk.x = (unsigned int)f2bf(hv.x) | ((unsigned int)f2bf(hv.y) << 16);
    pk.y = (unsigned int)f2bf(hv.z) | ((unsigned int)f2bf(hv.w) << 16);
    *(uint2*)&hbf[(size_t)n * HID + cg] = pk;
}

// ---------------- edge aggregation (CSR gather from bf16 shadow) ----------------
// z[n] = h[n] + sum_{edges into n} relu(hbf[src] + edge_attr @ W_e + b_e); z stored bf16
__global__ __launch_bounds__(256) void aggr_kernel(const float* __restrict__ h,
                                                   const unsigned short* __restrict__ hbf,
                                                   const int4* __restrict__ edges,
                                                   const int* __restrict__ row_start,
                                                   const float* __restrict__ We,
                                                   const float* __restrict__ be,
                                                   unsigned short* __restrict__ zbf,
                                                   float* __restrict__ S1,
                                                   float* __restrict__ S2) {
    int tid = threadIdx.x;
    if (blockIdx.x == 0 && tid < HID) {   // zero BN stat accumulators for this layer
        S1[tid] = 0.f;
        S2[tid] = 0.f;
    }
    int cg = (tid & 31) * 4;              // this thread's 4-channel group
    int n = blockIdx.x * 8 + (tid >> 5);  // 8 nodes per 256-thread block (grid exact)

    float4 w0 = *(const float4*)&We[cg];
    float4 w1 = *(const float4*)&We[HID + cg];
    float4 bb = *(const float4*)&be[cg];

    float4 hn = *(const float4*)&h[(size_t)n * HID + cg];   // self term, f32
    int jb = row_start[n], je = row_start[n + 1];
    float4 acc = make_float4(0.f, 0.f, 0.f, 0.f);

    int j = jb;
    for (; j + 8 <= je; j += 8) {
        int4 q[8];
        uint2 hq[8];
#pragma unroll
        for (int u = 0; u < 8; ++u) q[u] = edges[j + u];
#pragma unroll
        for (int u = 0; u < 8; ++u) hq[u] = *(const uint2*)&hbf[(size_t)q[u].x * HID + cg];
#pragma unroll
        for (int u = 0; u < 8; ++u) {
            float ex = __int_as_float(q[u].y), ey = __int_as_float(q[u].z);
            acc.x += fmaxf(bflo(hq[u].x) + fmaf(ex, w0.x, fmaf(ey, w1.x, bb.x)), 0.f);
            acc.y += fmaxf(bfhi(hq[u].x) + fmaf(ex, w0.y, fmaf(ey, w1.y, bb.y)), 0.f);
            acc.z += fmaxf(bflo(hq[u].y) + fmaf(ex, w0.z, fmaf(ey, w1.z, bb.z)), 0.f);
            acc.w += fmaxf(bfhi(hq[u].y) + fmaf(ex, w0.w, fmaf(ey, w1.w, bb.w)), 0.f);
        }
    }
    if (j + 4 <= je) {
        int4 q[4];
        uint2 hq[4];
#pragma unroll
        for (int u = 0; u < 4; ++u) q[u] = edges[j + u];
#pragma unroll
        for (int u = 0; u < 4; ++u) hq[u] = *(const uint2*)&hbf[(size_t)q[u].x * HID + cg];
#pragma unroll
        for (int u = 0; u < 4; ++u) {
            float ex = __int_as_float(q[u].y), ey = __int_as_float(q[u].z);
            acc.x += fmaxf(bflo(hq[u].x) + fmaf(ex, w0.x, fmaf(ey, w1.x, bb.x)), 0.f);
            acc.y += fmaxf(bfhi(hq[u].x) + fmaf(ex, w0.y, fmaf(ey, w1.y, bb.y)), 0.f);
            acc.z += fmaxf(bflo(hq[u].y) + fmaf(ex, w0.z, fmaf(ey, w1.z, bb.z)), 0.f);
            acc.w += fmaxf(bfhi(hq[u].y) + fmaf(ex, w0.w, fmaf(ey, w1.w, bb.w)), 0.f);
        }
        j += 4;
    }
    for (; j < je; ++j) {
        int4 q = edges[j];
        uint2 hq = *(const uint2*)&hbf[(size_t)q.x * HID + cg];
        float ex = __int_as_float(q.y), ey = __int_as_float(q.z);
        acc.x += fmaxf(bflo(hq.x) + fmaf(ex, w0.x, fmaf(ey, w1.x, bb.x)), 0.f);
        acc.y += fmaxf(bfhi(hq.x) + fmaf(ex, w0.y, fmaf(ey, w1.y, bb.y)), 0.f);
        acc.z += fmaxf(bflo(hq.y) + fmaf(ex, w0.z, fmaf(ey, w1.z, bb.z)), 0.f);
        acc.w += fmaxf(bfhi(hq.y) + fmaf(ex, w0.w, fmaf(ey, w1.w, bb.w)), 0.f);
    }

    uint2 pk;
    pk.x = (unsigned int)f2bf(hn.x + acc.x) | ((unsigned int)f2bf(hn.y + acc.y) << 16);
    pk.y = (unsigned int)f2bf(hn.z + acc.z) | ((unsigned int)f2bf(hn.w + acc.w) << 16);
    *(uint2*)&zbf[(size_t)n * HID + cg] = pk;
}

// ---------------- bf16 MFMA GEMM: out[M,128] = A[M,KD] @ W[KD,128] + b ----------------
// 64x128 tile, 256 threads = 4 waves in 2x2 grid: wave (wr,wc) owns 32 rows x 64 cols.
// ABF: A is bf16. OMODE: 0=f32, 1=bf16, 2=both.
template <int RELU, int STATS, int KD, int ABF, int OMODE>
__global__ __launch_bounds__(256) void bgemm_kernel(const void* __restrict__ Av,
                                                    const unsigned short* __restrict__ Wt,
                                                    const float* __restrict__ bias,
                                                    float* __restrict__ out,
                                                    unsigned short* __restrict__ outbf,
                                                    float* __restrict__ S1,
                                                    float* __restrict__ S2,
                                                    float* __restrict__ zinit, int zinit_n) {
    __shared__ unsigned short aS[64 * KD];    // [row][k] bf16, byte ^= (row&7)<<4
    __shared__ unsigned short wS[128 * KD];   // [col][k] bf16, byte ^= (col&7)<<4
    __shared__ float sh1[HID], sh2[HID];
    int tid = threadIdx.x;
    if (zinit && blockIdx.x == 0)
        for (int i = tid; i < zinit_n; i += 256) zinit[i] = 0.f;
    if (STATS && tid < HID) { sh1[tid] = 0.f; sh2[tid] = 0.f; }

    int row0 = blockIdx.x * 64;

    if constexpr (!ABF) {
        const float* A = (const float*)Av;
        constexpr int AITERS = (64 * KD) / (256 * 4);
#pragma unroll
        for (int it = 0; it < AITERS; ++it) {
            int idx = it * 1024 + tid * 4;
            int r = idx / KD, k = idx % KD;
            int grow = row0 + r;
            float4 v = (grow < N_NODES) ? *(const float4*)&A[(size_t)grow * KD + k]
                                        : make_float4(0.f, 0.f, 0.f, 0.f);
            unsigned int d0 = (unsigned int)f2bf(v.x) | ((unsigned int)f2bf(v.y) << 16);
            unsigned int d1 = (unsigned int)f2bf(v.z) | ((unsigned int)f2bf(v.w) << 16);
            unsigned int byte = (unsigned int)(idx * 2) ^ (unsigned int)((r & 7) << 4);
            *(uint2*)((char*)aS + byte) = make_uint2(d0, d1);
        }
    } else {
        const unsigned short* A = (const unsigned short*)Av;
        constexpr int AITERS = (64 * KD) / (256 * 8);
#pragma unroll
        for (int it = 0; it < AITERS; ++it) {
            int idx = it * 2048 + tid * 8;
            int r = idx / KD;
            int grow = row0 + r;
            uint4 v = (grow < N_NODES) ? *(const uint4*)&A[(size_t)grow * KD + (idx % KD)]
                                       : make_uint4(0u, 0u, 0u, 0u);
            unsigned int byte = (unsigned int)(idx * 2) ^ (unsigned int)((r & 7) << 4);
            *(uint4*)((char*)aS + byte) = v;
        }
    }
    constexpr int WITERS = (128 * KD) / (256 * 8);
#pragma unroll
    for (int it = 0; it < WITERS; ++it) {
        int idx = it * 2048 + tid * 8;
        int c = idx / KD;
        uint4 v = *(const uint4*)&Wt[idx];
        unsigned int byte = (unsigned int)(idx * 2) ^ (unsigned int)((c & 7) << 4);
        *(uint4*)((char*)wS + byte) = v;
    }
    __syncthreads();

    int w = tid >> 6, l = tid & 63;
    int wr = w >> 1, wc = w & 1;       // 2x2 wave grid
    int lr = l & 15;
    int kq = (l >> 4) * 8;
    f32x4 acc[2][4];
#pragma unroll
    for (int r = 0; r < 2; ++r)
#pragma unroll
        for (int t = 0; t < 4; ++t) acc[r][t] = (f32x4){0.f, 0.f, 0.f, 0.f};

#pragma unroll
    for (int s = 0; s < KD / 32; ++s) {
        int k0 = s * 32 + kq;
        int ar0 = 32 * wr + lr, ar1 = ar0 + 16;
        short8 af0 = *(short8*)((char*)aS + ((unsigned int)((ar0 * KD + k0) * 2) ^
                                            (unsigned int)((ar0 & 7) << 4)));
        short8 af1 = *(short8*)((char*)aS + ((unsigned int)((ar1 * KD + k0) * 2) ^
                                            (unsigned int)((ar1 & 7) << 4)));
#pragma unroll
        for (int t = 0; t < 4; ++t) {
            int col = 64 * wc + 16 * t + lr;
            short8 bf = *(short8*)((char*)wS + ((unsigned int)((col * KD + k0) * 2) ^
                                               (unsigned int)((col & 7) << 4)));
            acc[0][t] = __builtin_amdgcn_mfma_f32_16x16x32_bf16(af0, bf, acc[0][t], 0, 0, 0);
            acc[1][t] = __builtin_amdgcn_mfma_f32_16x16x32_bf16(af1, bf, acc[1][t], 0, 0, 0);
        }
    }

    // epilogue: bias (+relu) (+stats); D layout: col=lane&15, row=(lane>>4)*4+q
#pragma unroll
    for (int r = 0; r < 2; ++r) {
        int rbase = row0 + 32 * wr + 16 * r + (l >> 4) * 4;
#pragma unroll
        for (int t = 0; t < 4; ++t) {
            int col = 64 * wc + 16 * t + lr;
            float b = bias[col];
            float s1 = 0.f, s2 = 0.f;
#pragma unroll
            for (int q = 0; q < 4; ++q) {
                int grow = rbase + q;
                if (grow < N_NODES) {
                    float v = acc[r][t][q] + b;
                    if (RELU) v = fmaxf(v, 0.f);
                    if (OMODE == 0 || OMODE == 2) out[(size_t)grow * HID + col] = v;
                    if (OMODE == 1 || OMODE == 2) outbf[(size_t)grow * HID + col] = f2bf(v);
                    if (STATS) { s1 += v; s2 += v * v; }
                }
            }
            if (STATS) {
                atomicAdd(&sh1[col], s1);
                atomicAdd(&sh2[col], s2);
            }
        }
    }
    if (STATS) {
        __syncthreads();
        if (tid < HID) {
            atomicAdd(&S1[tid], sh1[tid]);
            atomicAdd(&S2[tid], sh2[tid]);
        }
    }
}

// ---------------- BN apply + relu + segment-sum into vn_up/pool (float4) ----------------
__global__ __launch_bounds__(256) void bn_kernel(const float* __restrict__ z2,
                                                 const float* __restrict__ S1,
                                                 const float* __restrict__ S2,
                                                 const float* __restrict__ gma,
                                                 const float* __restrict__ bta,
                                                 const int* __restrict__ batch,
                                                 float* __restrict__ h,
                                                 unsigned short* __restrict__ hbf,
                                                 float* __restrict__ up) {
    int tid = threadIdx.x;
    int cg = (tid & 31) * 4;
    int n0 = (blockIdx.x * 8 + (tid >> 5)) * 16;
    const float inv = 1.f / (float)N_NODES;
    float4 s1 = *(const float4*)&S1[cg];
    float4 s2 = *(const float4*)&S2[cg];
    float4 g4 = *(const float4*)&gma[cg];
    float4 b4 = *(const float4*)&bta[cg];
    float mux = s1.x * inv, muy = s1.y * inv, muz = s1.z * inv, muw = s1.w * inv;
    float gmx = g4.x * rsqrtf(s2.x * inv - mux * mux + BN_EPS);
    float gmy = g4.y * rsqrtf(s2.y * inv - muy * muy + BN_EPS);
    float gmz = g4.z * rsqrtf(s2.z * inv - muz * muz + BN_EPS);
    float gmw = g4.w * rsqrtf(s2.w * inv - muw * muw + BN_EPS);

    float4 acc = make_float4(0.f, 0.f, 0.f, 0.f);
    int gcur = -1;
    for (int i = 0; i < 16; ++i) {
        int n = n0 + i;
        if (n >= N_NODES) break;
        float4 v = *(const float4*)&z2[(size_t)n * HID + cg];
        float4 hn;
        hn.x = fmaxf(fmaf(v.x - mux, gmx, b4.x), 0.f);
        hn.y = fmaxf(fmaf(v.y - muy, gmy, b4.y), 0.f);
        hn.z = fmaxf(fmaf(v.z - muz, gmz, b4.z), 0.f);
        hn.w = fmaxf(fmaf(v.w - muw, gmw, b4.w), 0.f);
        *(float4*)&h[(size_t)n * HID + cg] = hn;
        uint2 pk;
        pk.x = (unsigned int)f2bf(hn.x) | ((unsigned int)f2bf(hn.y) << 16);
        pk.y = (unsigned int)f2bf(hn.z) | ((unsigned int)f2bf(hn.w) << 16);
        *(uint2*)&hbf[(size_t)n * HID + cg] = pk;
        int gb = batch[n];
        if (gb != gcur) {
            if (gcur >= 0) {
                atomicAdd(&up[gcur * HID + cg + 0], acc.x);
                atomicAdd(&up[gcur * HID + cg + 1], acc.y);
                atomicAdd(&up[gcur * HID + cg + 2], acc.z);
                atomicAdd(&up[gcur * HID + cg + 3], acc.w);
            }
            acc = make_float4(0.f, 0.f, 0.f, 0.f);
            gcur = gb;
        }
        acc.x += hn.x; acc.y += hn.y; acc.z += hn.z; acc.w += hn.w;
    }
    if (gcur >= 0) {
        atomicAdd(&up[gcur * HID + cg + 0], acc.x);
        atomicAdd(&up[gcur * HID + cg + 1], acc.y);
        atomicAdd(&up[gcur * HID + cg + 2], acc.z);
        atomicAdd(&up[gcur * HID + cg + 3], acc.w);
    }
}

// ---------------- virtual-node MLP: vn[g] += relu(up[g]@W1+b1)@W2+b2 ----------------
__global__ __launch_bounds__(128) void vnmlp_kernel(const float* __restrict__ up,
                                                    const float* __restrict__ W1,
                                                    const float* __restrict__ b1,
                                                    const float* __restrict__ W2,
                                                    const float* __restrict__ b2,
                                                    float* __restrict__ vn) {
    __shared__ float t[HID];
    int g = blockIdx.x, c = threadIdx.x;
    float s = b1[c];
#pragma unroll 8
    for (int k = 0; k < HID; ++k) s = fmaf(up[g * HID + k], W1[k * HID + c], s);
    t[c] = fmaxf(s, 0.f);
    __syncthreads();
    float s2 = b2[c];
#pragma unroll 8
    for (int k = 0; k < HID; ++k) s2 = fmaf(t[k], W2[k * HID + c], s2);
    vn[g * HID + c] += s2;
}

// ---------------- classifier: logits[g] ----------------
__global__ __launch_bounds__(128) void cls_kernel(const float* __restrict__ pool,
                                                  const int* __restrict__ endpos,
                                                  const float* __restrict__ W1,
                                                  const float* __restrict__ b1,
                                                  const float* __restrict__ W2,
                                                  const float* __restrict__ b2,
                                                  float* __restrict__ out) {
    __shared__ float t[HID];
    __shared__ float red[HID];
    int g = blockIdx.x, c = threadIdx.x;
    int cnt = endpos[g] - (g > 0 ? endpos[g - 1] : 0);
    float cntf = fmaxf((float)cnt, 1.f);
    t[c] = pool[g * HID + c] / cntf;
    __syncthreads();
    float s = b1[c];
#pragma unroll 8
    for (int k = 0; k < HID; ++k) s = fmaf(t[k], W1[k * HID + c], s);
    float y = fmaxf(s, 0.f);
    red[c] = y * W2[c];
    __syncthreads();
    for (int off = 64; off > 0; off >>= 1) {
        if (c < off) red[c] += red[c + off];
        __syncthreads();
    }
    if (c == 0) out[g] = red[0] + b2[0];
}

// ---------------- host-side orchestration ----------------
extern "C" void kernel_launch(void* const* d_in, const int* in_sizes, int n_in,
                              void* d_out, int out_size, void* d_ws, size_t ws_size,
                              hipStream_t stream) {
    const float* x        = (const float*)d_in[0];
    const float* edge_attr= (const float*)d_in[1];
    const int*   edge_idx = (const int*)d_in[2];
    const int*   batch    = (const int*)d_in[3];
    const float* W_in     = (const float*)d_in[4];
    const float* b_in     = (const float*)d_in[5];
    const float* W_e      = (const float*)d_in[6];
    const float* b_e      = (const float*)d_in[7];
    const float* conv_W1  = (const float*)d_in[8];
    const float* conv_b1  = (const float*)d_in[9];
    const float* conv_W2  = (const float*)d_in[10];
    const float* conv_b2  = (const float*)d_in[11];
    const float* bn_g     = (const float*)d_in[12];
    const float* bn_b     = (const float*)d_in[13];
    const float* vn_W1    = (const float*)d_in[14];
    const float* vn_b1    = (const float*)d_in[15];
    const float* vn_W2    = (const float*)d_in[16];
    const float* vn_b2    = (const float*)d_in[17];
    const float* cls_W1   = (const float*)d_in[18];
    const float* cls_b1   = (const float*)d_in[19];
    const float* cls_W2   = (const float*)d_in[20];
    const float* cls_b2   = (const float*)d_in[21];

    char* ws = (char*)d_ws;
    size_t off = 0;
    auto alloc = [&](size_t bytes) -> void* {
        void* p = ws + off;
        off = (off + bytes + 255) & ~(size_t)255;
        return p;
    };
    float* A = (float*)alloc((size_t)N_NODES * HID * 4);   // h (f32)
    float* B = (float*)alloc((size_t)N_NODES * HID * 4);   // z2 (f32)
    unsigned short* hbf = (unsigned short*)alloc((size_t)N_NODES * HID * 2);
    unsigned short* zbf = (unsigned short*)alloc((size_t)N_NODES * HID * 2);
    unsigned short* ybf = (unsigned short*)alloc((size_t)N_NODES * HID * 2);
    size_t zero_begin = off;
    int*   cnt    = (int*)alloc((size_t)N_NODES * 4);
    float* vn     = (float*)alloc((size_t)NUM_GRAPHS * HID * 4);
    float* pool   = (float*)alloc((size_t)NUM_GRAPHS * HID * 4);
    size_t zero_end = off;
    int*    endpos    = (int*)alloc((size_t)NUM_GRAPHS * 4);
    int*    row_start = (int*)alloc((size_t)(N_NODES + 1) * 4);
    int*    fillp     = (int*)alloc((size_t)N_NODES * 4);
    int4*   edges     = (int4*)alloc((size_t)N_EDGES * 16);
    float*  vn_up     = (float*)alloc((size_t)NUM_GRAPHS * HID * 4);
    float*  S1        = (float*)alloc((size_t)HID * 4);
    float*  S2        = (float*)alloc((size_t)HID * 4);
    int*    bsum      = (int*)alloc((size_t)SCAN_BLOCKS * 4);
    int*    boff      = (int*)alloc((size_t)SCAN_BLOCKS * 4);
    unsigned short* wt_in = (unsigned short*)alloc((size_t)HID * IN_DIM * 2);
    unsigned short* wt1   = (unsigned short*)alloc((size_t)NUM_LAYERS * HID * HID * 2);
    unsigned short* wt2   = (unsigned short*)alloc((size_t)NUM_LAYERS * HID * HID * 2);
    (void)ws_size; (void)in_sizes; (void)n_in; (void)out_size;

    const int* srcp = edge_idx;
    const int* dstp = edge_idx + N_EDGES;

    hipMemsetAsync(ws + zero_begin, 0, zero_end - zero_begin, stream);
    hist_kernel<<<(N_EDGES + 1023) / 1024, 256, 0, stream>>>(dstp, cnt);
    endpos_kernel<<<(N_NODES + 255) / 256, 256, 0, stream>>>(batch, endpos);
    wprep_kernel<<<(4 * HID * HID + 255) / 256, 256, 0, stream>>>(W_in, conv_W1, conv_W2,
                                                                  wt_in, wt1, wt2);
    scan1_kernel<<<SCAN_BLOCKS, 1024, 0, stream>>>(cnt, bsum);
    scan2_kernel<<<1, 64, 0, stream>>>(bsum, boff);
    scan3_kernel<<<SCAN_BLOCKS, 1024, 0, stream>>>(cnt, boff, row_start, fillp);
    fill_kernel<<<(N_EDGES + 1023) / 1024, 256, 0, stream>>>(srcp, dstp, edge_attr, fillp,
                                                             edges);

    const int gemm_grid = (N_NODES + 63) / 64;   // 782
    // h0 = x @ W_in + b_in  (f32 h + bf16 shadow)
    bgemm_kernel<0, 0, IN_DIM, 0, 2><<<gemm_grid, 256, 0, stream>>>(
        x, wt_in, b_in, A, hbf, nullptr, nullptr, nullptr, 0);

    for (int i = 0; i < NUM_LAYERS; ++i) {
        if (i > 0)
            addvn_kernel<<<(N_NODES * 32 + 255) / 256, 256, 0, stream>>>(A, hbf, vn, batch);
        aggr_kernel<<<N_NODES / 8, 256, 0, stream>>>(A, hbf, edges, row_start, W_e, b_e,
                                                     zbf, S1, S2);
        bgemm_kernel<1, 0, HID, 1, 1><<<gemm_grid, 256, 0, stream>>>(
            zbf, wt1 + (size_t)i * HID * HID, conv_b1 + (size_t)i * HID, nullptr, ybf,
            nullptr, nullptr, (i < NUM_LAYERS - 1) ? vn_up : nullptr, NUM_GRAPHS * HID);
        bgemm_kernel<0, 1, HID, 1, 0><<<gemm_grid, 256, 0, stream>>>(
            ybf, wt2 + (size_t)i * HID * HID, conv_b2 + (size_t)i * HID, B, nullptr,
            S1, S2, nullptr, 0);
        bn_kernel<<<(N_NODES + 127) / 128, 256, 0, stream>>>(B, S1, S2, bn_g + (size_t)i * HID,
                                                             bn_b + (size_t)i * HID, batch,
                                                             A, hbf,
                                                             (i < NUM_LAYERS - 1) ? vn_up : pool);
        if (i < NUM_LAYERS - 1)
            vnmlp_kernel<<<NUM_GRAPHS, 128, 0, stream>>>(vn_up, vn_W1, vn_b1, vn_W2, vn_b2, vn);
    }

    cls_kernel<<<NUM_GRAPHS, 128, 0, stream>>>(pool, endpos, cls_W1, cls_b1, cls_W2, cls_b2,
                                               (float*)d_out);
}

// Round 7
// 631.332 us; speedup vs baseline: 2.2005x; 1.0513x over previous
//
#include <hip/hip_runtime.h>

#define N_NODES 50000
#define N_EDGES 800000
#define IN_DIM 64
#define HID 128
#define NUM_LAYERS 4
#define NUM_GRAPHS 128
#define BN_EPS 1e-5f

typedef __attribute__((ext_vector_type(8))) short short8;
typedef __attribute__((ext_vector_type(4))) float f32x4;

__device__ inline unsigned short f2bf(float f) {
    unsigned int u = __float_as_uint(f);
    u += 0x7FFFu + ((u >> 16) & 1u);   // round-to-nearest-even
    return (unsigned short)(u >> 16);
}
__device__ inline float bflo(unsigned int p) { return __uint_as_float(p << 16); }
__device__ inline float bfhi(unsigned int p) { return __uint_as_float(p & 0xFFFF0000u); }

// ---------------- small utility kernels ----------------

// histogram + per-edge rank within dst bucket (rank = atomic return value)
__global__ void hist_kernel(const int* __restrict__ dst, int* __restrict__ cnt,
                            int* __restrict__ rank) {
    int base = blockIdx.x * 1024 + threadIdx.x;
#pragma unroll
    for (int u = 0; u < 4; ++u) {
        int e = base + u * 256;
        if (e < N_EDGES) rank[e] = atomicAdd(&cnt[dst[e]], 1);
    }
}

// batch is sorted: endpos[g] = #nodes with batch <= g, written only at run boundaries.
__global__ void endpos_kernel(const int* __restrict__ batch, int* __restrict__ endpos) {
    int n = blockIdx.x * 256 + threadIdx.x;
    if (n >= N_NODES) return;
    int b = batch[n];
    int b1 = (n + 1 < N_NODES) ? batch[n + 1] : NUM_GRAPHS;
    for (int g = b; g < b1; ++g) endpos[g] = n + 1;
    if (n == 0)
        for (int g = 0; g < b; ++g) endpos[g] = 0;
}

// weight prep: transpose + cvt to bf16 once per call.
__global__ void wprep_kernel(const float* __restrict__ W_in,
                             const float* __restrict__ conv_W1,
                             const float* __restrict__ conv_W2,
                             unsigned short* __restrict__ wt_in,
                             unsigned short* __restrict__ wt1,
                             unsigned short* __restrict__ wt2) {
    int i = blockIdx.x * 256 + threadIdx.x;
    if (i < 128 * IN_DIM) {
        int c = i >> 6, k = i & 63;
        wt_in[i] = f2bf(W_in[k * HID + c]);
    }
    if (i < 4 * HID * HID) {
        int o = i & (HID * HID - 1);
        int layer = i >> 14;
        int c = o >> 7, k = o & 127;
        wt1[i] = f2bf(conv_W1[layer * HID * HID + k * HID + c]);
        wt2[i] = f2bf(conv_W2[layer * HID * HID + k * HID + c]);
    }
}

// ---------------- 3-stage coalesced exclusive scan over 50000 counters ----------------
#define SCAN_BLOCKS ((N_NODES + 1023) / 1024)   // 49

__global__ __launch_bounds__(1024) void scan1_kernel(const int* __restrict__ cnt,
                                                     int* __restrict__ bsum) {
    __shared__ int ls[1024];
    int t = threadIdx.x;
    int g = blockIdx.x * 1024 + t;
    int v = (g < N_NODES) ? cnt[g] : 0;
    ls[t] = v;
    __syncthreads();
    for (int off = 512; off > 0; off >>= 1) {
        if (t < off) ls[t] += ls[t + off];
        __syncthreads();
    }
    if (t == 0) bsum[blockIdx.x] = ls[0];
}

__global__ void scan2_kernel(const int* __restrict__ bsum, int* __restrict__ boff) {
    if (threadIdx.x == 0) {
        int r = 0;
        for (int i = 0; i < SCAN_BLOCKS; ++i) {
            boff[i] = r;
            r += bsum[i];
        }
    }
}

__global__ __launch_bounds__(1024) void scan3_kernel(const int* __restrict__ cnt,
                                                     const int* __restrict__ boff,
                                                     int* __restrict__ row_start) {
    __shared__ int ls[1024];
    int t = threadIdx.x;
    int g = blockIdx.x * 1024 + t;
    int v = (g < N_NODES) ? cnt[g] : 0;
    ls[t] = v;
    __syncthreads();
    for (int off = 1; off < 1024; off <<= 1) {
        int x = (t >= off) ? ls[t - off] : 0;
        __syncthreads();
        ls[t] += x;
        __syncthreads();
    }
    int excl = ls[t] - v + boff[blockIdx.x];
    if (g < N_NODES) {
        row_start[g] = excl;
        if (g == N_NODES - 1) row_start[N_NODES] = excl + v;
    }
}

// atomic-free CSR fill: p = row_start[dst] + rank; one edge per thread.
__global__ void fill_kernel(const int* __restrict__ src, const int* __restrict__ dst,
                            const float* __restrict__ ea, const int* __restrict__ rank,
                            const int* __restrict__ row_start, int4* __restrict__ edges) {
    int e = blockIdx.x * 256 + threadIdx.x;
    if (e >= N_EDGES) return;
    float2 a = *(const float2*)&ea[2 * e];
    int p = row_start[dst[e]] + rank[e];
    edges[p] = make_int4(src[e], __float_as_int(a.x), __float_as_int(a.y), 0);
}

// h[n][cg..] += vn[batch[n]][cg..]; also refresh bf16 shadow
__global__ void addvn_kernel(float* __restrict__ h, unsigned short* __restrict__ hbf,
                             const float* __restrict__ vn, const int* __restrict__ batch) {
    int idx = blockIdx.x * 256 + threadIdx.x;   // over N_NODES*32
    int n = idx >> 5;
    if (n >= N_NODES) return;
    int cg = (idx & 31) * 4;
    float4 hv = *(const float4*)&h[(size_t)n * HID + cg];
    float4 vv = *(const float4*)&vn[(size_t)batch[n] * HID + cg];
    hv.x += vv.x; hv.y += vv.y; hv.z += vv.z; hv.w += vv.w;
    *(float4*)&h[(size_t)n * HID + cg] = hv;
    uint2 pk;
    pk.x = (unsigned int)f2bf(hv.x) | ((unsigned int)f2bf(hv.y) << 16);
    pk.y = (unsigned int)f2bf(hv.z) | ((unsigned int)f2bf(hv.w) << 16);
    *(uint2*)&hbf[(size_t)n * HID + cg] = pk;
}

// ---------------- edge aggregation (CSR gather from bf16 shadow) ----------------
// z[n] = h[n] + sum_{edges into n} relu(hbf[src] + edge_attr @ W_e + b_e); z stored bf16
__global__ __launch_bounds__(256) void aggr_kernel(const float* __restrict__ h,
                                                   const unsigned short* __restrict__ hbf,
                                                   const int4* __restrict__ edges,
                                                   const int* __restrict__ row_start,
                                                   const float* __restrict__ We,
                                                   const float* __restrict__ be,
                                                   unsigned short* __restrict__ zbf,
                                                   float* __restrict__ S1,
                                                   float* __restrict__ S2) {
    int tid = threadIdx.x;
    if (blockIdx.x == 0 && tid < HID) {   // zero BN stat accumulators for this layer
        S1[tid] = 0.f;
        S2[tid] = 0.f;
    }
    int cg = (tid & 31) * 4;              // this thread's 4-channel group
    int n = blockIdx.x * 8 + (tid >> 5);  // 8 nodes per 256-thread block (grid exact)

    float4 w0 = *(const float4*)&We[cg];
    float4 w1 = *(const float4*)&We[HID + cg];
    float4 bb = *(const float4*)&be[cg];

    float4 hn = *(const float4*)&h[(size_t)n * HID + cg];   // self term, f32
    int jb = row_start[n], je = row_start[n + 1];
    float4 acc = make_float4(0.f, 0.f, 0.f, 0.f);

    int j = jb;
    for (; j + 8 <= je; j += 8) {
        int4 q[8];
        uint2 hq[8];
#pragma unroll
        for (int u = 0; u < 8; ++u) q[u] = edges[j + u];
#pragma unroll
        for (int u = 0; u < 8; ++u) hq[u] = *(const uint2*)&hbf[(size_t)q[u].x * HID + cg];
#pragma unroll
        for (int u = 0; u < 8; ++u) {
            float ex = __int_as_float(q[u].y), ey = __int_as_float(q[u].z);
            acc.x += fmaxf(bflo(hq[u].x) + fmaf(ex, w0.x, fmaf(ey, w1.x, bb.x)), 0.f);
            acc.y += fmaxf(bfhi(hq[u].x) + fmaf(ex, w0.y, fmaf(ey, w1.y, bb.y)), 0.f);
            acc.z += fmaxf(bflo(hq[u].y) + fmaf(ex, w0.z, fmaf(ey, w1.z, bb.z)), 0.f);
            acc.w += fmaxf(bfhi(hq[u].y) + fmaf(ex, w0.w, fmaf(ey, w1.w, bb.w)), 0.f);
        }
    }
    if (j + 4 <= je) {
        int4 q[4];
        uint2 hq[4];
#pragma unroll
        for (int u = 0; u < 4; ++u) q[u] = edges[j + u];
#pragma unroll
        for (int u = 0; u < 4; ++u) hq[u] = *(const uint2*)&hbf[(size_t)q[u].x * HID + cg];
#pragma unroll
        for (int u = 0; u < 4; ++u) {
            float ex = __int_as_float(q[u].y), ey = __int_as_float(q[u].z);
            acc.x += fmaxf(bflo(hq[u].x) + fmaf(ex, w0.x, fmaf(ey, w1.x, bb.x)), 0.f);
            acc.y += fmaxf(bfhi(hq[u].x) + fmaf(ex, w0.y, fmaf(ey, w1.y, bb.y)), 0.f);
            acc.z += fmaxf(bflo(hq[u].y) + fmaf(ex, w0.z, fmaf(ey, w1.z, bb.z)), 0.f);
            acc.w += fmaxf(bfhi(hq[u].y) + fmaf(ex, w0.w, fmaf(ey, w1.w, bb.w)), 0.f);
        }
        j += 4;
    }
    for (; j < je; ++j) {
        int4 q = edges[j];
        uint2 hq = *(const uint2*)&hbf[(size_t)q.x * HID + cg];
        float ex = __int_as_float(q.y), ey = __int_as_float(q.z);
        acc.x += fmaxf(bflo(hq.x) + fmaf(ex, w0.x, fmaf(ey, w1.x, bb.x)), 0.f);
        acc.y += fmaxf(bfhi(hq.x) + fmaf(ex, w0.y, fmaf(ey, w1.y, bb.y)), 0.f);
        acc.z += fmaxf(bflo(hq.y) + fmaf(ex, w0.z, fmaf(ey, w1.z, bb.z)), 0.f);
        acc.w += fmaxf(bfhi(hq.y) + fmaf(ex, w0.w, fmaf(ey, w1.w, bb.w)), 0.f);
    }

    uint2 pk;
    pk.x = (unsigned int)f2bf(hn.x + acc.x) | ((unsigned int)f2bf(hn.y + acc.y) << 16);
    pk.y = (unsigned int)f2bf(hn.z + acc.z) | ((unsigned int)f2bf(hn.w + acc.w) << 16);
    *(uint2*)&zbf[(size_t)n * HID + cg] = pk;
}

// ---------------- bf16 MFMA GEMM: out[M,128] = A[M,KD] @ W[KD,128] + b ----------------
// 64x128 tile, 256 threads = 4 waves in 2x2 grid: wave (wr,wc) owns 32 rows x 64 cols.
// ABF: A is bf16. OMODE: 0=f32, 1=bf16, 2=both.
template <int RELU, int STATS, int KD, int ABF, int OMODE>
__global__ __launch_bounds__(256) void bgemm_kernel(const void* __restrict__ Av,
                                                    const unsigned short* __restrict__ Wt,
                                                    const float* __restrict__ bias,
                                                    float* __restrict__ out,
                                                    unsigned short* __restrict__ outbf,
                                                    float* __restrict__ S1,
                                                    float* __restrict__ S2,
                                                    float* __restrict__ zinit, int zinit_n) {
    __shared__ unsigned short aS[64 * KD];    // [row][k] bf16, byte ^= (row&7)<<4
    __shared__ unsigned short wS[128 * KD];   // [col][k] bf16, byte ^= (col&7)<<4
    __shared__ float sh1[HID], sh2[HID];
    int tid = threadIdx.x;
    if (zinit && blockIdx.x == 0)
        for (int i = tid; i < zinit_n; i += 256) zinit[i] = 0.f;
    if (STATS && tid < HID) { sh1[tid] = 0.f; sh2[tid] = 0.f; }

    int row0 = blockIdx.x * 64;

    if constexpr (!ABF) {
        const float* A = (const float*)Av;
        constexpr int AITERS = (64 * KD) / (256 * 4);
#pragma unroll
        for (int it = 0; it < AITERS; ++it) {
            int idx = it * 1024 + tid * 4;
            int r = idx / KD, k = idx % KD;
            int grow = row0 + r;
            float4 v = (grow < N_NODES) ? *(const float4*)&A[(size_t)grow * KD + k]
                                        : make_float4(0.f, 0.f, 0.f, 0.f);
            unsigned int d0 = (unsigned int)f2bf(v.x) | ((unsigned int)f2bf(v.y) << 16);
            unsigned int d1 = (unsigned int)f2bf(v.z) | ((unsigned int)f2bf(v.w) << 16);
            unsigned int byte = (unsigned int)(idx * 2) ^ (unsigned int)((r & 7) << 4);
            *(uint2*)((char*)aS + byte) = make_uint2(d0, d1);
        }
    } else {
        const unsigned short* A = (const unsigned short*)Av;
        constexpr int AITERS = (64 * KD) / (256 * 8);
#pragma unroll
        for (int it = 0; it < AITERS; ++it) {
            int idx = it * 2048 + tid * 8;
            int r = idx / KD;
            int grow = row0 + r;
            uint4 v = (grow < N_NODES) ? *(const uint4*)&A[(size_t)grow * KD + (idx % KD)]
                                       : make_uint4(0u, 0u, 0u, 0u);
            unsigned int byte = (unsigned int)(idx * 2) ^ (unsigned int)((r & 7) << 4);
            *(uint4*)((char*)aS + byte) = v;
        }
    }
    constexpr int WITERS = (128 * KD) / (256 * 8);
#pragma unroll
    for (int it = 0; it < WITERS; ++it) {
        int idx = it * 2048 + tid * 8;
        int c = idx / KD;
        uint4 v = *(const uint4*)&Wt[idx];
        unsigned int byte = (unsigned int)(idx * 2) ^ (unsigned int)((c & 7) << 4);
        *(uint4*)((char*)wS + byte) = v;
    }
    __syncthreads();

    int w = tid >> 6, l = tid & 63;
    int wr = w >> 1, wc = w & 1;       // 2x2 wave grid
    int lr = l & 15;
    int kq = (l >> 4) * 8;
    f32x4 acc[2][4];
#pragma unroll
    for (int r = 0; r < 2; ++r)
#pragma unroll
        for (int t = 0; t < 4; ++t) acc[r][t] = (f32x4){0.f, 0.f, 0.f, 0.f};

#pragma unroll
    for (int s = 0; s < KD / 32; ++s) {
        int k0 = s * 32 + kq;
        int ar0 = 32 * wr + lr, ar1 = ar0 + 16;
        short8 af0 = *(short8*)((char*)aS + ((unsigned int)((ar0 * KD + k0) * 2) ^
                                            (unsigned int)((ar0 & 7) << 4)));
        short8 af1 = *(short8*)((char*)aS + ((unsigned int)((ar1 * KD + k0) * 2) ^
                                            (unsigned int)((ar1 & 7) << 4)));
#pragma unroll
        for (int t = 0; t < 4; ++t) {
            int col = 64 * wc + 16 * t + lr;
            short8 bf = *(short8*)((char*)wS + ((unsigned int)((col * KD + k0) * 2) ^
                                               (unsigned int)((col & 7) << 4)));
            acc[0][t] = __builtin_amdgcn_mfma_f32_16x16x32_bf16(af0, bf, acc[0][t], 0, 0, 0);
            acc[1][t] = __builtin_amdgcn_mfma_f32_16x16x32_bf16(af1, bf, acc[1][t], 0, 0, 0);
        }
    }

    // epilogue: bias (+relu) (+stats); D layout: col=lane&15, row=(lane>>4)*4+q
#pragma unroll
    for (int r = 0; r < 2; ++r) {
        int rbase = row0 + 32 * wr + 16 * r + (l >> 4) * 4;
#pragma unroll
        for (int t = 0; t < 4; ++t) {
            int col = 64 * wc + 16 * t + lr;
            float b = bias[col];
            float s1 = 0.f, s2 = 0.f;
#pragma unroll
            for (int q = 0; q < 4; ++q) {
                int grow = rbase + q;
                if (grow < N_NODES) {
                    float v = acc[r][t][q] + b;
                    if (RELU) v = fmaxf(v, 0.f);
                    if (OMODE == 0 || OMODE == 2) out[(size_t)grow * HID + col] = v;
                    if (OMODE == 1 || OMODE == 2) outbf[(size_t)grow * HID + col] = f2bf(v);
                    if (STATS) { s1 += v; s2 += v * v; }
                }
            }
            if (STATS) {
                atomicAdd(&sh1[col], s1);
                atomicAdd(&sh2[col], s2);
            }
        }
    }
    if (STATS) {
        __syncthreads();
        if (tid < HID) {
            atomicAdd(&S1[tid], sh1[tid]);
            atomicAdd(&S2[tid], sh2[tid]);
        }
    }
}

// ---------------- BN apply + relu + segment-sum into vn_up/pool (float4) ----------------
__global__ __launch_bounds__(256) void bn_kernel(const float* __restrict__ z2,
                                                 const float* __restrict__ S1,
                                                 const float* __restrict__ S2,
                                                 const float* __restrict__ gma,
                                                 const float* __restrict__ bta,
                                                 const int* __restrict__ batch,
                                                 float* __restrict__ h,
                                                 unsigned short* __restrict__ hbf,
                                                 float* __restrict__ up) {
    int tid = threadIdx.x;
    int cg = (tid & 31) * 4;
    int n0 = (blockIdx.x * 8 + (tid >> 5)) * 16;
    const float inv = 1.f / (float)N_NODES;
    float4 s1 = *(const float4*)&S1[cg];
    float4 s2 = *(const float4*)&S2[cg];
    float4 g4 = *(const float4*)&gma[cg];
    float4 b4 = *(const float4*)&bta[cg];
    float mux = s1.x * inv, muy = s1.y * inv, muz = s1.z * inv, muw = s1.w * inv;
    float gmx = g4.x * rsqrtf(s2.x * inv - mux * mux + BN_EPS);
    float gmy = g4.y * rsqrtf(s2.y * inv - muy * muy + BN_EPS);
    float gmz = g4.z * rsqrtf(s2.z * inv - muz * muz + BN_EPS);
    float gmw = g4.w * rsqrtf(s2.w * inv - muw * muw + BN_EPS);

    float4 acc = make_float4(0.f, 0.f, 0.f, 0.f);
    int gcur = -1;
    for (int i = 0; i < 16; ++i) {
        int n = n0 + i;
        if (n >= N_NODES) break;
        float4 v = *(const float4*)&z2[(size_t)n * HID + cg];
        float4 hn;
        hn.x = fmaxf(fmaf(v.x - mux, gmx, b4.x), 0.f);
        hn.y = fmaxf(fmaf(v.y - muy, gmy, b4.y), 0.f);
        hn.z = fmaxf(fmaf(v.z - muz, gmz, b4.z), 0.f);
        hn.w = fmaxf(fmaf(v.w - muw, gmw, b4.w), 0.f);
        *(float4*)&h[(size_t)n * HID + cg] = hn;
        uint2 pk;
        pk.x = (unsigned int)f2bf(hn.x) | ((unsigned int)f2bf(hn.y) << 16);
        pk.y = (unsigned int)f2bf(hn.z) | ((unsigned int)f2bf(hn.w) << 16);
        *(uint2*)&hbf[(size_t)n * HID + cg] = pk;
        int gb = batch[n];
        if (gb != gcur) {
            if (gcur >= 0) {
                atomicAdd(&up[gcur * HID + cg + 0], acc.x);
                atomicAdd(&up[gcur * HID + cg + 1], acc.y);
                atomicAdd(&up[gcur * HID + cg + 2], acc.z);
                atomicAdd(&up[gcur * HID + cg + 3], acc.w);
            }
            acc = make_float4(0.f, 0.f, 0.f, 0.f);
            gcur = gb;
        }
        acc.x += hn.x; acc.y += hn.y; acc.z += hn.z; acc.w += hn.w;
    }
    if (gcur >= 0) {
        atomicAdd(&up[gcur * HID + cg + 0], acc.x);
        atomicAdd(&up[gcur * HID + cg + 1], acc.y);
        atomicAdd(&up[gcur * HID + cg + 2], acc.z);
        atomicAdd(&up[gcur * HID + cg + 3], acc.w);
    }
}

// ---------------- virtual-node MLP: vn[g] += relu(up[g]@W1+b1)@W2+b2 ----------------
__global__ __launch_bounds__(128) void vnmlp_kernel(const float* __restrict__ up,
                                                    const float* __restrict__ W1,
                                                    const float* __restrict__ b1,
                                                    const float* __restrict__ W2,
                                                    const float* __restrict__ b2,
                                                    float* __restrict__ vn) {
    __shared__ float t[HID];
    int g = blockIdx.x, c = threadIdx.x;
    float s = b1[c];
#pragma unroll 8
    for (int k = 0; k < HID; ++k) s = fmaf(up[g * HID + k], W1[k * HID + c], s);
    t[c] = fmaxf(s, 0.f);
    __syncthreads();
    float s2 = b2[c];
#pragma unroll 8
    for (int k = 0; k < HID; ++k) s2 = fmaf(t[k], W2[k * HID + c], s2);
    vn[g * HID + c] += s2;
}

// ---------------- classifier: logits[g] ----------------
__global__ __launch_bounds__(128) void cls_kernel(const float* __restrict__ pool,
                                                  const int* __restrict__ endpos,
                                                  const float* __restrict__ W1,
                                                  const float* __restrict__ b1,
                                                  const float* __restrict__ W2,
                                                  const float* __restrict__ b2,
                                                  float* __restrict__ out) {
    __shared__ float t[HID];
    __shared__ float red[HID];
    int g = blockIdx.x, c = threadIdx.x;
    int cnt = endpos[g] - (g > 0 ? endpos[g - 1] : 0);
    float cntf = fmaxf((float)cnt, 1.f);
    t[c] = pool[g * HID + c] / cntf;
    __syncthreads();
    float s = b1[c];
#pragma unroll 8
    for (int k = 0; k < HID; ++k) s = fmaf(t[k], W1[k * HID + c], s);
    float y = fmaxf(s, 0.f);
    red[c] = y * W2[c];
    __syncthreads();
    for (int off = 64; off > 0; off >>= 1) {
        if (c < off) red[c] += red[c + off];
        __syncthreads();
    }
    if (c == 0) out[g] = red[0] + b2[0];
}

// ---------------- host-side orchestration ----------------
extern "C" void kernel_launch(void* const* d_in, const int* in_sizes, int n_in,
                              void* d_out, int out_size, void* d_ws, size_t ws_size,
                              hipStream_t stream) {
    const float* x        = (const float*)d_in[0];
    const float* edge_attr= (const float*)d_in[1];
    const int*   edge_idx = (const int*)d_in[2];
    const int*   batch    = (const int*)d_in[3];
    const float* W_in     = (const float*)d_in[4];
    const float* b_in     = (const float*)d_in[5];
    const float* W_e      = (const float*)d_in[6];
    const float* b_e      = (const float*)d_in[7];
    const float* conv_W1  = (const float*)d_in[8];
    const float* conv_b1  = (const float*)d_in[9];
    const float* conv_W2  = (const float*)d_in[10];
    const float* conv_b2  = (const float*)d_in[11];
    const float* bn_g     = (const float*)d_in[12];
    const float* bn_b     = (const float*)d_in[13];
    const float* vn_W1    = (const float*)d_in[14];
    const float* vn_b1    = (const float*)d_in[15];
    const float* vn_W2    = (const float*)d_in[16];
    const float* vn_b2    = (const float*)d_in[17];
    const float* cls_W1   = (const float*)d_in[18];
    const float* cls_b1   = (const float*)d_in[19];
    const float* cls_W2   = (const float*)d_in[20];
    const float* cls_b2   = (const float*)d_in[21];

    char* ws = (char*)d_ws;
    size_t off = 0;
    auto alloc = [&](size_t bytes) -> void* {
        void* p = ws + off;
        off = (off + bytes + 255) & ~(size_t)255;
        return p;
    };
    float* A = (float*)alloc((size_t)N_NODES * HID * 4);   // h (f32)
    float* B = (float*)alloc((size_t)N_NODES * HID * 4);   // z2 (f32)
    unsigned short* hbf = (unsigned short*)alloc((size_t)N_NODES * HID * 2);
    unsigned short* zbf = (unsigned short*)alloc((size_t)N_NODES * HID * 2);
    unsigned short* ybf = (unsigned short*)alloc((size_t)N_NODES * HID * 2);
    size_t zero_begin = off;
    int*   cnt    = (int*)alloc((size_t)N_NODES * 4);
    float* vn     = (float*)alloc((size_t)NUM_GRAPHS * HID * 4);
    float* pool   = (float*)alloc((size_t)NUM_GRAPHS * HID * 4);
    size_t zero_end = off;
    int*    endpos    = (int*)alloc((size_t)NUM_GRAPHS * 4);
    int*    row_start = (int*)alloc((size_t)(N_NODES + 1) * 4);
    int*    rank      = (int*)alloc((size_t)N_EDGES * 4);
    int4*   edges     = (int4*)alloc((size_t)N_EDGES * 16);
    float*  vn_up     = (float*)alloc((size_t)NUM_GRAPHS * HID * 4);
    float*  S1        = (float*)alloc((size_t)HID * 4);
    float*  S2        = (float*)alloc((size_t)HID * 4);
    int*    bsum      = (int*)alloc((size_t)SCAN_BLOCKS * 4);
    int*    boff      = (int*)alloc((size_t)SCAN_BLOCKS * 4);
    unsigned short* wt_in = (unsigned short*)alloc((size_t)HID * IN_DIM * 2);
    unsigned short* wt1   = (unsigned short*)alloc((size_t)NUM_LAYERS * HID * HID * 2);
    unsigned short* wt2   = (unsigned short*)alloc((size_t)NUM_LAYERS * HID * HID * 2);
    (void)ws_size; (void)in_sizes; (void)n_in; (void)out_size;

    const int* srcp = edge_idx;
    const int* dstp = edge_idx + N_EDGES;

    hipMemsetAsync(ws + zero_begin, 0, zero_end - zero_begin, stream);
    hist_kernel<<<(N_EDGES + 1023) / 1024, 256, 0, stream>>>(dstp, cnt, rank);
    endpos_kernel<<<(N_NODES + 255) / 256, 256, 0, stream>>>(batch, endpos);
    wprep_kernel<<<(4 * HID * HID + 255) / 256, 256, 0, stream>>>(W_in, conv_W1, conv_W2,
                                                                  wt_in, wt1, wt2);
    scan1_kernel<<<SCAN_BLOCKS, 1024, 0, stream>>>(cnt, bsum);
    scan2_kernel<<<1, 64, 0, stream>>>(bsum, boff);
    scan3_kernel<<<SCAN_BLOCKS, 1024, 0, stream>>>(cnt, boff, row_start);
    fill_kernel<<<(N_EDGES + 255) / 256, 256, 0, stream>>>(srcp, dstp, edge_attr, rank,
                                                           row_start, edges);

    const int gemm_grid = (N_NODES + 63) / 64;   // 782
    // h0 = x @ W_in + b_in  (f32 h + bf16 shadow)
    bgemm_kernel<0, 0, IN_DIM, 0, 2><<<gemm_grid, 256, 0, stream>>>(
        x, wt_in, b_in, A, hbf, nullptr, nullptr, nullptr, 0);

    for (int i = 0; i < NUM_LAYERS; ++i) {
        if (i > 0)
            addvn_kernel<<<(N_NODES * 32 + 255) / 256, 256, 0, stream>>>(A, hbf, vn, batch);
        aggr_kernel<<<N_NODES / 8, 256, 0, stream>>>(A, hbf, edges, row_start, W_e, b_e,
                                                     zbf, S1, S2);
        bgemm_kernel<1, 0, HID, 1, 1><<<gemm_grid, 256, 0, stream>>>(
            zbf, wt1 + (size_t)i * HID * HID, conv_b1 + (size_t)i * HID, nullptr, ybf,
            nullptr, nullptr, (i < NUM_LAYERS - 1) ? vn_up : nullptr, NUM_GRAPHS * HID);
        bgemm_kernel<0, 1, HID, 1, 0><<<gemm_grid, 256, 0, stream>>>(
            ybf, wt2 + (size_t)i * HID * HID, conv_b2 + (size_t)i * HID, B, nullptr,
            S1, S2, nullptr, 0);
        bn_kernel<<<(N_NODES + 127) / 128, 256, 0, stream>>>(B, S1, S2, bn_g + (size_t)i * HID,
                                                             bn_b + (size_t)i * HID, batch,
                                                             A, hbf,
                                                             (i < NUM_LAYERS - 1) ? vn_up : pool);
        if (i < NUM_LAYERS - 1)
            vnmlp_kernel<<<NUM_GRAPHS, 128, 0, stream>>>(vn_up, vn_W1, vn_b1, vn_W2, vn_b2, vn);
    }

    cls_kernel<<<NUM_GRAPHS, 128, 0, stream>>>(pool, endpos, cls_W1, cls_b1, cls_W2, cls_b2,
                                               (float*)d_out);
}

// Round 8
// 524.985 us; speedup vs baseline: 2.6462x; 1.2026x over previous
//
#include <hip/hip_runtime.h>

#define N_NODES 50000
#define N_EDGES 800000
#define IN_DIM 64
#define HID 128
#define NUM_LAYERS 4
#define NUM_GRAPHS 128
#define BN_EPS 1e-5f

typedef __attribute__((ext_vector_type(8))) short short8;
typedef __attribute__((ext_vector_type(4))) float f32x4;

__device__ inline unsigned short f2bf(float f) {
    unsigned int u = __float_as_uint(f);
    u += 0x7FFFu + ((u >> 16) & 1u);   // round-to-nearest-even
    return (unsigned short)(u >> 16);
}
__device__ inline float bflo(unsigned int p) { return __uint_as_float(p << 16); }
__device__ inline float bfhi(unsigned int p) { return __uint_as_float(p & 0xFFFF0000u); }
__device__ inline float bfch(const uint4& v, int c) {
    unsigned int p = (&v.x)[c >> 1];
    return (c & 1) ? bfhi(p) : bflo(p);
}

// ---------------- small utility kernels ----------------

// histogram + per-edge rank within dst bucket (rank = atomic return value)
__global__ void hist_kernel(const int* __restrict__ dst, int* __restrict__ cnt,
                            int* __restrict__ rank) {
    int base = blockIdx.x * 1024 + threadIdx.x;
#pragma unroll
    for (int u = 0; u < 4; ++u) {
        int e = base + u * 256;
        if (e < N_EDGES) rank[e] = atomicAdd(&cnt[dst[e]], 1);
    }
}

// batch is sorted: endpos[g] = #nodes with batch <= g, written only at run boundaries.
__global__ void endpos_kernel(const int* __restrict__ batch, int* __restrict__ endpos) {
    int n = blockIdx.x * 256 + threadIdx.x;
    if (n >= N_NODES) return;
    int b = batch[n];
    int b1 = (n + 1 < N_NODES) ? batch[n + 1] : NUM_GRAPHS;
    for (int g = b; g < b1; ++g) endpos[g] = n + 1;
    if (n == 0)
        for (int g = 0; g < b; ++g) endpos[g] = 0;
}

// weight prep: transpose + cvt to bf16 once per call.
__global__ void wprep_kernel(const float* __restrict__ W_in,
                             const float* __restrict__ conv_W1,
                             const float* __restrict__ conv_W2,
                             unsigned short* __restrict__ wt_in,
                             unsigned short* __restrict__ wt1,
                             unsigned short* __restrict__ wt2) {
    int i = blockIdx.x * 256 + threadIdx.x;
    if (i < 128 * IN_DIM) {
        int c = i >> 6, k = i & 63;
        wt_in[i] = f2bf(W_in[k * HID + c]);
    }
    if (i < 4 * HID * HID) {
        int o = i & (HID * HID - 1);
        int layer = i >> 14;
        int c = o >> 7, k = o & 127;
        wt1[i] = f2bf(conv_W1[layer * HID * HID + k * HID + c]);
        wt2[i] = f2bf(conv_W2[layer * HID * HID + k * HID + c]);
    }
}

// ---------------- 3-stage coalesced exclusive scan over 50000 counters ----------------
#define SCAN_BLOCKS ((N_NODES + 1023) / 1024)   // 49

__global__ __launch_bounds__(1024) void scan1_kernel(const int* __restrict__ cnt,
                                                     int* __restrict__ bsum) {
    __shared__ int ls[1024];
    int t = threadIdx.x;
    int g = blockIdx.x * 1024 + t;
    int v = (g < N_NODES) ? cnt[g] : 0;
    ls[t] = v;
    __syncthreads();
    for (int off = 512; off > 0; off >>= 1) {
        if (t < off) ls[t] += ls[t + off];
        __syncthreads();
    }
    if (t == 0) bsum[blockIdx.x] = ls[0];
}

__global__ void scan2_kernel(const int* __restrict__ bsum, int* __restrict__ boff) {
    if (threadIdx.x == 0) {
        int r = 0;
        for (int i = 0; i < SCAN_BLOCKS; ++i) {
            boff[i] = r;
            r += bsum[i];
        }
    }
}

__global__ __launch_bounds__(1024) void scan3_kernel(const int* __restrict__ cnt,
                                                     const int* __restrict__ boff,
                                                     int* __restrict__ row_start) {
    __shared__ int ls[1024];
    int t = threadIdx.x;
    int g = blockIdx.x * 1024 + t;
    int v = (g < N_NODES) ? cnt[g] : 0;
    ls[t] = v;
    __syncthreads();
    for (int off = 1; off < 1024; off <<= 1) {
        int x = (t >= off) ? ls[t - off] : 0;
        __syncthreads();
        ls[t] += x;
        __syncthreads();
    }
    int excl = ls[t] - v + boff[blockIdx.x];
    if (g < N_NODES) {
        row_start[g] = excl;
        if (g == N_NODES - 1) row_start[N_NODES] = excl + v;
    }
}

// atomic-free CSR fill: p = row_start[dst] + rank. Record = {src, ea.x, ea.y, batch[src]}.
__global__ void fill_kernel(const int* __restrict__ src, const int* __restrict__ dst,
                            const float* __restrict__ ea, const int* __restrict__ rank,
                            const int* __restrict__ row_start, const int* __restrict__ batch,
                            int4* __restrict__ edges) {
    int e = blockIdx.x * 256 + threadIdx.x;
    if (e >= N_EDGES) return;
    float2 a = *(const float2*)&ea[2 * e];
    int s = src[e];
    int p = row_start[dst[e]] + rank[e];
    edges[p] = make_int4(s, __float_as_int(a.x), __float_as_int(a.y), batch[s]);
}

// ---------------- edge aggregation (CSR gather, vn fused) ----------------
// z[n] = (h[n]+vn[b(n)]) + sum_edges relu(h[src]+vn[b(src)] + ea@We + be); bf16 in/out.
// 16 threads per node (8 channels each), 16 nodes per 256-thread block.
template <int HASVN>
__global__ __launch_bounds__(256) void aggr_kernel(const unsigned short* __restrict__ hbf,
                                                   const unsigned short* __restrict__ vnb,
                                                   const int* __restrict__ batch,
                                                   const int4* __restrict__ edges,
                                                   const int* __restrict__ row_start,
                                                   const float* __restrict__ We,
                                                   const float* __restrict__ be,
                                                   unsigned short* __restrict__ zbf,
                                                   float* __restrict__ S1,
                                                   float* __restrict__ S2) {
    int tid = threadIdx.x;
    if (blockIdx.x == 0 && tid < HID) {   // zero BN stat accumulators for this layer
        S1[tid] = 0.f;
        S2[tid] = 0.f;
    }
    int cg = (tid & 15) * 8;               // 8-channel group
    int n = blockIdx.x * 16 + (tid >> 4);  // grid exact: 3125*16 = 50000

    float w0[8], w1[8], bc[8];
    {
        float4 a0 = *(const float4*)&We[cg], a1 = *(const float4*)&We[cg + 4];
        float4 b0 = *(const float4*)&We[HID + cg], b1v = *(const float4*)&We[HID + cg + 4];
        float4 c0 = *(const float4*)&be[cg], c1 = *(const float4*)&be[cg + 4];
        w0[0]=a0.x; w0[1]=a0.y; w0[2]=a0.z; w0[3]=a0.w; w0[4]=a1.x; w0[5]=a1.y; w0[6]=a1.z; w0[7]=a1.w;
        w1[0]=b0.x; w1[1]=b0.y; w1[2]=b0.z; w1[3]=b0.w; w1[4]=b1v.x; w1[5]=b1v.y; w1[6]=b1v.z; w1[7]=b1v.w;
        bc[0]=c0.x; bc[1]=c0.y; bc[2]=c0.z; bc[3]=c0.w; bc[4]=c1.x; bc[5]=c1.y; bc[6]=c1.z; bc[7]=c1.w;
    }

    // self term
    float s[8];
    {
        uint4 hs = *(const uint4*)&hbf[(size_t)n * HID + cg];
#pragma unroll
        for (int c = 0; c < 8; ++c) s[c] = bfch(hs, c);
        if (HASVN) {
            uint4 vs = *(const uint4*)&vnb[(size_t)batch[n] * HID + cg];
#pragma unroll
            for (int c = 0; c < 8; ++c) s[c] += bfch(vs, c);
        }
    }

    int jb = row_start[n], je = row_start[n + 1];
    float acc[8];
#pragma unroll
    for (int c = 0; c < 8; ++c) acc[c] = 0.f;

    int j = jb;
    for (; j + 4 <= je; j += 4) {
        int4 q[4];
        uint4 hq[4], vq[4];
#pragma unroll
        for (int u = 0; u < 4; ++u) q[u] = edges[j + u];
#pragma unroll
        for (int u = 0; u < 4; ++u) hq[u] = *(const uint4*)&hbf[(size_t)q[u].x * HID + cg];
        if (HASVN) {
#pragma unroll
            for (int u = 0; u < 4; ++u) vq[u] = *(const uint4*)&vnb[(size_t)q[u].w * HID + cg];
        }
#pragma unroll
        for (int u = 0; u < 4; ++u) {
            float ex = __int_as_float(q[u].y), ey = __int_as_float(q[u].z);
#pragma unroll
            for (int c = 0; c < 8; ++c) {
                float hv = bfch(hq[u], c);
                if (HASVN) hv += bfch(vq[u], c);
                acc[c] += fmaxf(hv + fmaf(ex, w0[c], fmaf(ey, w1[c], bc[c])), 0.f);
            }
        }
    }
    for (; j < je; ++j) {
        int4 q = edges[j];
        uint4 hq = *(const uint4*)&hbf[(size_t)q.x * HID + cg];
        uint4 vq;
        if (HASVN) vq = *(const uint4*)&vnb[(size_t)q.w * HID + cg];
        float ex = __int_as_float(q.y), ey = __int_as_float(q.z);
#pragma unroll
        for (int c = 0; c < 8; ++c) {
            float hv = bfch(hq, c);
            if (HASVN) hv += bfch(vq, c);
            acc[c] += fmaxf(hv + fmaf(ex, w0[c], fmaf(ey, w1[c], bc[c])), 0.f);
        }
    }

    unsigned int o[4];
#pragma unroll
    for (int p = 0; p < 4; ++p)
        o[p] = (unsigned int)f2bf(s[2 * p] + acc[2 * p]) |
               ((unsigned int)f2bf(s[2 * p + 1] + acc[2 * p + 1]) << 16);
    *(uint4*)&zbf[(size_t)n * HID + cg] = make_uint4(o[0], o[1], o[2], o[3]);
}

// ---------------- input GEMM (bf16 MFMA): hbf = bf16(x @ W_in + b_in) ----------------
// 64x128 tile, 4 waves in 2x2. A: f32. Output: bf16 only.
__global__ __launch_bounds__(256) void ingemm_kernel(const float* __restrict__ A,
                                                     const unsigned short* __restrict__ Wt,
                                                     const float* __restrict__ bias,
                                                     unsigned short* __restrict__ outbf) {
    constexpr int KD = IN_DIM;
    __shared__ unsigned short aS[64 * KD];
    __shared__ unsigned short wS[128 * KD];
    int tid = threadIdx.x;
    int row0 = blockIdx.x * 64;

#pragma unroll
    for (int it = 0; it < (64 * KD) / (256 * 4); ++it) {
        int idx = it * 1024 + tid * 4;
        int r = idx / KD, k = idx % KD;
        int grow = row0 + r;
        float4 v = (grow < N_NODES) ? *(const float4*)&A[(size_t)grow * KD + k]
                                    : make_float4(0.f, 0.f, 0.f, 0.f);
        unsigned int d0 = (unsigned int)f2bf(v.x) | ((unsigned int)f2bf(v.y) << 16);
        unsigned int d1 = (unsigned int)f2bf(v.z) | ((unsigned int)f2bf(v.w) << 16);
        unsigned int byte = (unsigned int)(idx * 2) ^ (unsigned int)((r & 7) << 4);
        *(uint2*)((char*)aS + byte) = make_uint2(d0, d1);
    }
#pragma unroll
    for (int it = 0; it < (128 * KD) / (256 * 8); ++it) {
        int idx = it * 2048 + tid * 8;
        int c = idx / KD;
        uint4 v = *(const uint4*)&Wt[idx];
        unsigned int byte = (unsigned int)(idx * 2) ^ (unsigned int)((c & 7) << 4);
        *(uint4*)((char*)wS + byte) = v;
    }
    __syncthreads();

    int w = tid >> 6, l = tid & 63;
    int wr = w >> 1, wc = w & 1, lr = l & 15, kq = (l >> 4) * 8;
    f32x4 acc[2][4];
#pragma unroll
    for (int r = 0; r < 2; ++r)
#pragma unroll
        for (int t = 0; t < 4; ++t) acc[r][t] = (f32x4){0.f, 0.f, 0.f, 0.f};

#pragma unroll
    for (int sstep = 0; sstep < KD / 32; ++sstep) {
        int k0 = sstep * 32 + kq;
        int ar0 = 32 * wr + lr, ar1 = ar0 + 16;
        short8 af0 = *(short8*)((char*)aS + ((unsigned int)((ar0 * KD + k0) * 2) ^
                                            (unsigned int)((ar0 & 7) << 4)));
        short8 af1 = *(short8*)((char*)aS + ((unsigned int)((ar1 * KD + k0) * 2) ^
                                            (unsigned int)((ar1 & 7) << 4)));
#pragma unroll
        for (int t = 0; t < 4; ++t) {
            int col = 64 * wc + 16 * t + lr;
            short8 bf = *(short8*)((char*)wS + ((unsigned int)((col * KD + k0) * 2) ^
                                               (unsigned int)((col & 7) << 4)));
            acc[0][t] = __builtin_amdgcn_mfma_f32_16x16x32_bf16(af0, bf, acc[0][t], 0, 0, 0);
            acc[1][t] = __builtin_amdgcn_mfma_f32_16x16x32_bf16(af1, bf, acc[1][t], 0, 0, 0);
        }
    }
#pragma unroll
    for (int r = 0; r < 2; ++r) {
        int rbase = row0 + 32 * wr + 16 * r + (l >> 4) * 4;
#pragma unroll
        for (int t = 0; t < 4; ++t) {
            int col = 64 * wc + 16 * t + lr;
            float b = bias[col];
#pragma unroll
            for (int q = 0; q < 4; ++q) {
                int grow = rbase + q;
                if (grow < N_NODES) outbf[(size_t)grow * HID + col] = f2bf(acc[r][t][q] + b);
            }
        }
    }
}

// ---------------- fused conv MLP: z2 = relu(z@W1+b1)@W2+b2, + BN stats ----------------
// One 64-row block does both GEMMs; y lives in LDS (reuses z tile), W2 reloads into W1's LDS.
__global__ __launch_bounds__(256) void conv_kernel(const unsigned short* __restrict__ zbf,
                                                   const unsigned short* __restrict__ Wt1,
                                                   const float* __restrict__ b1,
                                                   const unsigned short* __restrict__ Wt2,
                                                   const float* __restrict__ b2,
                                                   float* __restrict__ B,
                                                   float* __restrict__ S1,
                                                   float* __restrict__ S2,
                                                   float* __restrict__ zinit, int zinit_n) {
    constexpr int KD = HID;
    __shared__ unsigned short aS[64 * KD];    // z tile, then y tile
    __shared__ unsigned short wS[128 * KD];   // W1, then W2
    __shared__ float sh1[HID], sh2[HID];
    int tid = threadIdx.x;
    if (zinit && blockIdx.x == 0)
        for (int i = tid; i < zinit_n; i += 256) zinit[i] = 0.f;
    if (tid < HID) { sh1[tid] = 0.f; sh2[tid] = 0.f; }

    int row0 = blockIdx.x * 64;

#pragma unroll
    for (int it = 0; it < 4; ++it) {          // 64*128/(256*8)
        int idx = it * 2048 + tid * 8;
        int r = idx >> 7;
        int grow = row0 + r;
        uint4 v = (grow < N_NODES) ? *(const uint4*)&zbf[(size_t)grow * HID + (idx & 127)]
                                   : make_uint4(0u, 0u, 0u, 0u);
        unsigned int byte = (unsigned int)(idx * 2) ^ (unsigned int)((r & 7) << 4);
        *(uint4*)((char*)aS + byte) = v;
    }
#pragma unroll
    for (int it = 0; it < 8; ++it) {          // 128*128/(256*8)
        int idx = it * 2048 + tid * 8;
        int c = idx >> 7;
        uint4 v = *(const uint4*)&Wt1[idx];
        unsigned int byte = (unsigned int)(idx * 2) ^ (unsigned int)((c & 7) << 4);
        *(uint4*)((char*)wS + byte) = v;
    }
    __syncthreads();

    int w = tid >> 6, l = tid & 63;
    int wr = w >> 1, wc = w & 1, lr = l & 15, kq = (l >> 4) * 8;
    int ar0 = 32 * wr + lr, ar1 = ar0 + 16;

    f32x4 acc[2][4];
#pragma unroll
    for (int r = 0; r < 2; ++r)
#pragma unroll
        for (int t = 0; t < 4; ++t) acc[r][t] = (f32x4){0.f, 0.f, 0.f, 0.f};

#pragma unroll
    for (int sstep = 0; sstep < 4; ++sstep) {
        int k0 = sstep * 32 + kq;
        short8 af0 = *(short8*)((char*)aS + ((unsigned int)((ar0 * KD + k0) * 2) ^
                                            (unsigned int)((ar0 & 7) << 4)));
        short8 af1 = *(short8*)((char*)aS + ((unsigned int)((ar1 * KD + k0) * 2) ^
                                            (unsigned int)((ar1 & 7) << 4)));
#pragma unroll
        for (int t = 0; t < 4; ++t) {
            int col = 64 * wc + 16 * t + lr;
            short8 bf = *(short8*)((char*)wS + ((unsigned int)((col * KD + k0) * 2) ^
                                               (unsigned int)((col & 7) << 4)));
            acc[0][t] = __builtin_amdgcn_mfma_f32_16x16x32_bf16(af0, bf, acc[0][t], 0, 0, 0);
            acc[1][t] = __builtin_amdgcn_mfma_f32_16x16x32_bf16(af1, bf, acc[1][t], 0, 0, 0);
        }
    }
    __syncthreads();   // everyone done reading aS (z) and wS (W1)

    // y = relu(acc + b1) -> aS (bf16, swizzled); stage W2 -> wS
#pragma unroll
    for (int r = 0; r < 2; ++r) {
        int lrow0 = 32 * wr + 16 * r + (l >> 4) * 4;
#pragma unroll
        for (int t = 0; t < 4; ++t) {
            int col = 64 * wc + 16 * t + lr;
            float b = b1[col];
#pragma unroll
            for (int q = 0; q < 4; ++q) {
                int lrow = lrow0 + q;
                float v = fmaxf(acc[r][t][q] + b, 0.f);
                unsigned int byte = (unsigned int)((lrow * KD + col) * 2) ^
                                    (unsigned int)((lrow & 7) << 4);
                *(unsigned short*)((char*)aS + byte) = f2bf(v);
            }
        }
    }
#pragma unroll
    for (int it = 0; it < 8; ++it) {
        int idx = it * 2048 + tid * 8;
        int c = idx >> 7;
        uint4 v = *(const uint4*)&Wt2[idx];
        unsigned int byte = (unsigned int)(idx * 2) ^ (unsigned int)((c & 7) << 4);
        *(uint4*)((char*)wS + byte) = v;
    }
    __syncthreads();

    f32x4 acc2[2][4];
#pragma unroll
    for (int r = 0; r < 2; ++r)
#pragma unroll
        for (int t = 0; t < 4; ++t) acc2[r][t] = (f32x4){0.f, 0.f, 0.f, 0.f};

#pragma unroll
    for (int sstep = 0; sstep < 4; ++sstep) {
        int k0 = sstep * 32 + kq;
        short8 af0 = *(short8*)((char*)aS + ((unsigned int)((ar0 * KD + k0) * 2) ^
                                            (unsigned int)((ar0 & 7) << 4)));
        short8 af1 = *(short8*)((char*)aS + ((unsigned int)((ar1 * KD + k0) * 2) ^
                                            (unsigned int)((ar1 & 7) << 4)));
#pragma unroll
        for (int t = 0; t < 4; ++t) {
            int col = 64 * wc + 16 * t + lr;
            short8 bf = *(short8*)((char*)wS + ((unsigned int)((col * KD + k0) * 2) ^
                                               (unsigned int)((col & 7) << 4)));
            acc2[0][t] = __builtin_amdgcn_mfma_f32_16x16x32_bf16(af0, bf, acc2[0][t], 0, 0, 0);
            acc2[1][t] = __builtin_amdgcn_mfma_f32_16x16x32_bf16(af1, bf, acc2[1][t], 0, 0, 0);
        }
    }

    // epilogue: z2 = acc2 + b2 -> B (f32) + BN stats
#pragma unroll
    for (int r = 0; r < 2; ++r) {
        int rbase = row0 + 32 * wr + 16 * r + (l >> 4) * 4;
#pragma unroll
        for (int t = 0; t < 4; ++t) {
            int col = 64 * wc + 16 * t + lr;
            float b = b2[col];
            float s1 = 0.f, s2 = 0.f;
#pragma unroll
            for (int q = 0; q < 4; ++q) {
                int grow = rbase + q;
                if (grow < N_NODES) {
                    float v = acc2[r][t][q] + b;
                    B[(size_t)grow * HID + col] = v;
                    s1 += v;
                    s2 += v * v;
                }
            }
            atomicAdd(&sh1[col], s1);
            atomicAdd(&sh2[col], s2);
        }
    }
    __syncthreads();
    if (tid < HID) {
        atomicAdd(&S1[tid], sh1[tid]);
        atomicAdd(&S2[tid], sh2[tid]);
    }
}

// ---------------- BN apply + relu -> hbf (bf16) + segment-sum into vn_up/pool ----------------
__global__ __launch_bounds__(256) void bn_kernel(const float* __restrict__ z2,
                                                 const float* __restrict__ S1,
                                                 const float* __restrict__ S2,
                                                 const float* __restrict__ gma,
                                                 const float* __restrict__ bta,
                                                 const int* __restrict__ batch,
                                                 unsigned short* __restrict__ hbf,
                                                 float* __restrict__ up) {
    int tid = threadIdx.x;
    int cg = (tid & 31) * 4;
    int n0 = (blockIdx.x * 8 + (tid >> 5)) * 16;
    const float inv = 1.f / (float)N_NODES;
    float4 s1 = *(const float4*)&S1[cg];
    float4 s2 = *(const float4*)&S2[cg];
    float4 g4 = *(const float4*)&gma[cg];
    float4 b4 = *(const float4*)&bta[cg];
    float mux = s1.x * inv, muy = s1.y * inv, muz = s1.z * inv, muw = s1.w * inv;
    float gmx = g4.x * rsqrtf(s2.x * inv - mux * mux + BN_EPS);
    float gmy = g4.y * rsqrtf(s2.y * inv - muy * muy + BN_EPS);
    float gmz = g4.z * rsqrtf(s2.z * inv - muz * muz + BN_EPS);
    float gmw = g4.w * rsqrtf(s2.w * inv - muw * muw + BN_EPS);

    float4 acc = make_float4(0.f, 0.f, 0.f, 0.f);
    int gcur = -1;
    for (int i = 0; i < 16; ++i) {
        int n = n0 + i;
        if (n >= N_NODES) break;
        float4 v = *(const float4*)&z2[(size_t)n * HID + cg];
        float4 hn;
        hn.x = fmaxf(fmaf(v.x - mux, gmx, b4.x), 0.f);
        hn.y = fmaxf(fmaf(v.y - muy, gmy, b4.y), 0.f);
        hn.z = fmaxf(fmaf(v.z - muz, gmz, b4.z), 0.f);
        hn.w = fmaxf(fmaf(v.w - muw, gmw, b4.w), 0.f);
        uint2 pk;
        pk.x = (unsigned int)f2bf(hn.x) | ((unsigned int)f2bf(hn.y) << 16);
        pk.y = (unsigned int)f2bf(hn.z) | ((unsigned int)f2bf(hn.w) << 16);
        *(uint2*)&hbf[(size_t)n * HID + cg] = pk;
        int gb = batch[n];
        if (gb != gcur) {
            if (gcur >= 0) {
                atomicAdd(&up[gcur * HID + cg + 0], acc.x);
                atomicAdd(&up[gcur * HID + cg + 1], acc.y);
                atomicAdd(&up[gcur * HID + cg + 2], acc.z);
                atomicAdd(&up[gcur * HID + cg + 3], acc.w);
            }
            acc = make_float4(0.f, 0.f, 0.f, 0.f);
            gcur = gb;
        }
        acc.x += hn.x; acc.y += hn.y; acc.z += hn.z; acc.w += hn.w;
    }
    if (gcur >= 0) {
        atomicAdd(&up[gcur * HID + cg + 0], acc.x);
        atomicAdd(&up[gcur * HID + cg + 1], acc.y);
        atomicAdd(&up[gcur * HID + cg + 2], acc.z);
        atomicAdd(&up[gcur * HID + cg + 3], acc.w);
    }
}

// ---------------- virtual-node MLP: vn += relu(up@W1+b1)@W2+b2; also bf16 copy ----------------
__global__ __launch_bounds__(128) void vnmlp_kernel(const float* __restrict__ up,
                                                    const float* __restrict__ W1,
                                                    const float* __restrict__ b1,
                                                    const float* __restrict__ W2,
                                                    const float* __restrict__ b2,
                                                    float* __restrict__ vn,
                                                    unsigned short* __restrict__ vnb) {
    __shared__ float t[HID];
    int g = blockIdx.x, c = threadIdx.x;
    float s = b1[c];
#pragma unroll 8
    for (int k = 0; k < HID; ++k) s = fmaf(up[g * HID + k], W1[k * HID + c], s);
    t[c] = fmaxf(s, 0.f);
    __syncthreads();
    float s2 = b2[c];
#pragma unroll 8
    for (int k = 0; k < HID; ++k) s2 = fmaf(t[k], W2[k * HID + c], s2);
    float nv = vn[g * HID + c] + s2;
    vn[g * HID + c] = nv;
    vnb[g * HID + c] = f2bf(nv);
}

// ---------------- classifier: logits[g] ----------------
__global__ __launch_bounds__(128) void cls_kernel(const float* __restrict__ pool,
                                                  const int* __restrict__ endpos,
                                                  const float* __restrict__ W1,
                                                  const float* __restrict__ b1,
                                                  const float* __restrict__ W2,
                                                  const float* __restrict__ b2,
                                                  float* __restrict__ out) {
    __shared__ float t[HID];
    __shared__ float red[HID];
    int g = blockIdx.x, c = threadIdx.x;
    int cnt = endpos[g] - (g > 0 ? endpos[g - 1] : 0);
    float cntf = fmaxf((float)cnt, 1.f);
    t[c] = pool[g * HID + c] / cntf;
    __syncthreads();
    float s = b1[c];
#pragma unroll 8
    for (int k = 0; k < HID; ++k) s = fmaf(t[k], W1[k * HID + c], s);
    float y = fmaxf(s, 0.f);
    red[c] = y * W2[c];
    __syncthreads();
    for (int off = 64; off > 0; off >>= 1) {
        if (c < off) red[c] += red[c + off];
        __syncthreads();
    }
    if (c == 0) out[g] = red[0] + b2[0];
}

// ---------------- host-side orchestration ----------------
extern "C" void kernel_launch(void* const* d_in, const int* in_sizes, int n_in,
                              void* d_out, int out_size, void* d_ws, size_t ws_size,
                              hipStream_t stream) {
    const float* x        = (const float*)d_in[0];
    const float* edge_attr= (const float*)d_in[1];
    const int*   edge_idx = (const int*)d_in[2];
    const int*   batch    = (const int*)d_in[3];
    const float* W_in     = (const float*)d_in[4];
    const float* b_in     = (const float*)d_in[5];
    const float* W_e      = (const float*)d_in[6];
    const float* b_e      = (const float*)d_in[7];
    const float* conv_W1  = (const float*)d_in[8];
    const float* conv_b1  = (const float*)d_in[9];
    const float* conv_W2  = (const float*)d_in[10];
    const float* conv_b2  = (const float*)d_in[11];
    const float* bn_g     = (const float*)d_in[12];
    const float* bn_b     = (const float*)d_in[13];
    const float* vn_W1    = (const float*)d_in[14];
    const float* vn_b1    = (const float*)d_in[15];
    const float* vn_W2    = (const float*)d_in[16];
    const float* vn_b2    = (const float*)d_in[17];
    const float* cls_W1   = (const float*)d_in[18];
    const float* cls_b1   = (const float*)d_in[19];
    const float* cls_W2   = (const float*)d_in[20];
    const float* cls_b2   = (const float*)d_in[21];

    char* ws = (char*)d_ws;
    size_t off = 0;
    auto alloc = [&](size_t bytes) -> void* {
        void* p = ws + off;
        off = (off + bytes + 255) & ~(size_t)255;
        return p;
    };
    float* B = (float*)alloc((size_t)N_NODES * HID * 4);   // z2 (f32)
    unsigned short* hbf = (unsigned short*)alloc((size_t)N_NODES * HID * 2);
    unsigned short* zbf = (unsigned short*)alloc((size_t)N_NODES * HID * 2);
    size_t zero_begin = off;
    int*   cnt    = (int*)alloc((size_t)N_NODES * 4);
    float* vn     = (float*)alloc((size_t)NUM_GRAPHS * HID * 4);
    unsigned short* vnb = (unsigned short*)alloc((size_t)NUM_GRAPHS * HID * 2);
    float* pool   = (float*)alloc((size_t)NUM_GRAPHS * HID * 4);
    size_t zero_end = off;
    int*    endpos    = (int*)alloc((size_t)NUM_GRAPHS * 4);
    int*    row_start = (int*)alloc((size_t)(N_NODES + 1) * 4);
    int*    rank      = (int*)alloc((size_t)N_EDGES * 4);
    int4*   edges     = (int4*)alloc((size_t)N_EDGES * 16);
    float*  vn_up     = (float*)alloc((size_t)NUM_GRAPHS * HID * 4);
    float*  S1        = (float*)alloc((size_t)HID * 4);
    float*  S2        = (float*)alloc((size_t)HID * 4);
    int*    bsum      = (int*)alloc((size_t)SCAN_BLOCKS * 4);
    int*    boff      = (int*)alloc((size_t)SCAN_BLOCKS * 4);
    unsigned short* wt_in = (unsigned short*)alloc((size_t)HID * IN_DIM * 2);
    unsigned short* wt1   = (unsigned short*)alloc((size_t)NUM_LAYERS * HID * HID * 2);
    unsigned short* wt2   = (unsigned short*)alloc((size_t)NUM_LAYERS * HID * HID * 2);
    (void)ws_size; (void)in_sizes; (void)n_in; (void)out_size;

    const int* srcp = edge_idx;
    const int* dstp = edge_idx + N_EDGES;

    hipMemsetAsync(ws + zero_begin, 0, zero_end - zero_begin, stream);
    hist_kernel<<<(N_EDGES + 1023) / 1024, 256, 0, stream>>>(dstp, cnt, rank);
    endpos_kernel<<<(N_NODES + 255) / 256, 256, 0, stream>>>(batch, endpos);
    wprep_kernel<<<(4 * HID * HID + 255) / 256, 256, 0, stream>>>(W_in, conv_W1, conv_W2,
                                                                  wt_in, wt1, wt2);
    scan1_kernel<<<SCAN_BLOCKS, 1024, 0, stream>>>(cnt, bsum);
    scan2_kernel<<<1, 64, 0, stream>>>(bsum, boff);
    scan3_kernel<<<SCAN_BLOCKS, 1024, 0, stream>>>(cnt, boff, row_start);
    fill_kernel<<<(N_EDGES + 255) / 256, 256, 0, stream>>>(srcp, dstp, edge_attr, rank,
                                                           row_start, batch, edges);

    const int gemm_grid = (N_NODES + 63) / 64;   // 782
    ingemm_kernel<<<gemm_grid, 256, 0, stream>>>(x, wt_in, b_in, hbf);

    for (int i = 0; i < NUM_LAYERS; ++i) {
        if (i == 0)
            aggr_kernel<0><<<N_NODES / 16, 256, 0, stream>>>(hbf, vnb, batch, edges, row_start,
                                                             W_e, b_e, zbf, S1, S2);
        else
            aggr_kernel<1><<<N_NODES / 16, 256, 0, stream>>>(hbf, vnb, batch, edges, row_start,
                                                             W_e, b_e, zbf, S1, S2);
        conv_kernel<<<gemm_grid, 256, 0, stream>>>(
            zbf, wt1 + (size_t)i * HID * HID, conv_b1 + (size_t)i * HID,
            wt2 + (size_t)i * HID * HID, conv_b2 + (size_t)i * HID,
            B, S1, S2, (i < NUM_LAYERS - 1) ? vn_up : nullptr, NUM_GRAPHS * HID);
        bn_kernel<<<(N_NODES + 127) / 128, 256, 0, stream>>>(B, S1, S2, bn_g + (size_t)i * HID,
                                                             bn_b + (size_t)i * HID, batch, hbf,
                                                             (i < NUM_LAYERS - 1) ? vn_up : pool);
        if (i < NUM_LAYERS - 1)
            vnmlp_kernel<<<NUM_GRAPHS, 128, 0, stream>>>(vn_up, vn_W1, vn_b1, vn_W2, vn_b2,
                                                         vn, vnb);
    }

    cls_kernel<<<NUM_GRAPHS, 128, 0, stream>>>(pool, endpos, cls_W1, cls_b1, cls_W2, cls_b2,
                                               (float*)d_out);
}

// Round 9
// 523.687 us; speedup vs baseline: 2.6528x; 1.0025x over previous
//
#include <hip/hip_runtime.h>

#define N_NODES 50000
#define N_EDGES 800000
#define IN_DIM 64
#define HID 128
#define NUM_LAYERS 4
#define NUM_GRAPHS 128
#define BN_EPS 1e-5f

typedef __attribute__((ext_vector_type(8))) short short8;
typedef __attribute__((ext_vector_type(4))) float f32x4;

__device__ inline unsigned short f2bf(float f) {
    unsigned int u = __float_as_uint(f);
    u += 0x7FFFu + ((u >> 16) & 1u);   // round-to-nearest-even
    return (unsigned short)(u >> 16);
}
__device__ inline float bflo(unsigned int p) { return __uint_as_float(p << 16); }
__device__ inline float bfhi(unsigned int p) { return __uint_as_float(p & 0xFFFF0000u); }
__device__ inline float bfch(const uint4& v, int c) {
    unsigned int p = (&v.x)[c >> 1];
    return (c & 1) ? bfhi(p) : bflo(p);
}

// ---------------- small utility kernels ----------------

// histogram + per-edge rank within dst bucket (rank = atomic return value)
__global__ void hist_kernel(const int* __restrict__ dst, int* __restrict__ cnt,
                            int* __restrict__ rank) {
    int base = blockIdx.x * 1024 + threadIdx.x;
#pragma unroll
    for (int u = 0; u < 4; ++u) {
        int e = base + u * 256;
        if (e < N_EDGES) rank[e] = atomicAdd(&cnt[dst[e]], 1);
    }
}

// batch is sorted: endpos[g] = #nodes with batch <= g, written only at run boundaries.
__global__ void endpos_kernel(const int* __restrict__ batch, int* __restrict__ endpos) {
    int n = blockIdx.x * 256 + threadIdx.x;
    if (n >= N_NODES) return;
    int b = batch[n];
    int b1 = (n + 1 < N_NODES) ? batch[n + 1] : NUM_GRAPHS;
    for (int g = b; g < b1; ++g) endpos[g] = n + 1;
    if (n == 0)
        for (int g = 0; g < b; ++g) endpos[g] = 0;
}

// weight prep: transpose + cvt to bf16 once per call.
__global__ void wprep_kernel(const float* __restrict__ W_in,
                             const float* __restrict__ conv_W1,
                             const float* __restrict__ conv_W2,
                             unsigned short* __restrict__ wt_in,
                             unsigned short* __restrict__ wt1,
                             unsigned short* __restrict__ wt2) {
    int i = blockIdx.x * 256 + threadIdx.x;
    if (i < 128 * IN_DIM) {
        int c = i >> 6, k = i & 63;
        wt_in[i] = f2bf(W_in[k * HID + c]);
    }
    if (i < 4 * HID * HID) {
        int o = i & (HID * HID - 1);
        int layer = i >> 14;
        int c = o >> 7, k = o & 127;
        wt1[i] = f2bf(conv_W1[layer * HID * HID + k * HID + c]);
        wt2[i] = f2bf(conv_W2[layer * HID * HID + k * HID + c]);
    }
}

// ---------------- 3-stage coalesced exclusive scan over 50000 counters ----------------
#define SCAN_BLOCKS ((N_NODES + 1023) / 1024)   // 49

__global__ __launch_bounds__(1024) void scan1_kernel(const int* __restrict__ cnt,
                                                     int* __restrict__ bsum) {
    __shared__ int ls[1024];
    int t = threadIdx.x;
    int g = blockIdx.x * 1024 + t;
    int v = (g < N_NODES) ? cnt[g] : 0;
    ls[t] = v;
    __syncthreads();
    for (int off = 512; off > 0; off >>= 1) {
        if (t < off) ls[t] += ls[t + off];
        __syncthreads();
    }
    if (t == 0) bsum[blockIdx.x] = ls[0];
}

__global__ void scan2_kernel(const int* __restrict__ bsum, int* __restrict__ boff) {
    if (threadIdx.x == 0) {
        int r = 0;
        for (int i = 0; i < SCAN_BLOCKS; ++i) {
            boff[i] = r;
            r += bsum[i];
        }
    }
}

__global__ __launch_bounds__(1024) void scan3_kernel(const int* __restrict__ cnt,
                                                     const int* __restrict__ boff,
                                                     int* __restrict__ row_start) {
    __shared__ int ls[1024];
    int t = threadIdx.x;
    int g = blockIdx.x * 1024 + t;
    int v = (g < N_NODES) ? cnt[g] : 0;
    ls[t] = v;
    __syncthreads();
    for (int off = 1; off < 1024; off <<= 1) {
        int x = (t >= off) ? ls[t - off] : 0;
        __syncthreads();
        ls[t] += x;
        __syncthreads();
    }
    int excl = ls[t] - v + boff[blockIdx.x];
    if (g < N_NODES) {
        row_start[g] = excl;
        if (g == N_NODES - 1) row_start[N_NODES] = excl + v;
    }
}

// atomic-free CSR fill: p = row_start[dst] + rank. Record = {src, ea.x, ea.y, 0}.
__global__ void fill_kernel(const int* __restrict__ src, const int* __restrict__ dst,
                            const float* __restrict__ ea, const int* __restrict__ rank,
                            const int* __restrict__ row_start, int4* __restrict__ edges) {
    int e = blockIdx.x * 256 + threadIdx.x;
    if (e >= N_EDGES) return;
    float2 a = *(const float2*)&ea[2 * e];
    int p = row_start[dst[e]] + rank[e];
    edges[p] = make_int4(src[e], __float_as_int(a.x), __float_as_int(a.y), 0);
}

// gbf[n] = bf16(hbf[n] + vnb[batch[n]])  -- pre-combined gather table for aggr
__global__ void hvadd_kernel(const unsigned short* __restrict__ hbf,
                             const unsigned short* __restrict__ vnb,
                             const int* __restrict__ batch,
                             unsigned short* __restrict__ gbf) {
    int idx = blockIdx.x * 256 + threadIdx.x;   // over N_NODES*16
    int n = idx >> 4;
    if (n >= N_NODES) return;
    int cg = (idx & 15) * 8;
    uint4 h = *(const uint4*)&hbf[(size_t)n * HID + cg];
    uint4 v = *(const uint4*)&vnb[(size_t)batch[n] * HID + cg];
    unsigned int o[4];
#pragma unroll
    for (int p = 0; p < 4; ++p) {
        float lo = bflo((&h.x)[p]) + bflo((&v.x)[p]);
        float hi = bfhi((&h.x)[p]) + bfhi((&v.x)[p]);
        o[p] = (unsigned int)f2bf(lo) | ((unsigned int)f2bf(hi) << 16);
    }
    *(uint4*)&gbf[(size_t)n * HID + cg] = make_uint4(o[0], o[1], o[2], o[3]);
}

// ---------------- edge aggregation (CSR gather from pre-combined bf16 table) ----------------
// z[n] = g[n] + sum_edges relu(g[src] + ea@We + be); bf16 in/out.
// 16 threads per node (8 channels each), 16 nodes per 256-thread block.
__global__ __launch_bounds__(256) void aggr_kernel(const unsigned short* __restrict__ gbf,
                                                   const int4* __restrict__ edges,
                                                   const int* __restrict__ row_start,
                                                   const float* __restrict__ We,
                                                   const float* __restrict__ be,
                                                   unsigned short* __restrict__ zbf,
                                                   float* __restrict__ S1,
                                                   float* __restrict__ S2) {
    int tid = threadIdx.x;
    if (blockIdx.x == 0 && tid < HID) {   // zero BN stat accumulators for this layer
        S1[tid] = 0.f;
        S2[tid] = 0.f;
    }
    int cg = (tid & 15) * 8;               // 8-channel group
    int n = blockIdx.x * 16 + (tid >> 4);  // grid exact: 3125*16 = 50000

    float w0[8], w1[8], bc[8];
    {
        float4 a0 = *(const float4*)&We[cg], a1 = *(const float4*)&We[cg + 4];
        float4 b0 = *(const float4*)&We[HID + cg], b1v = *(const float4*)&We[HID + cg + 4];
        float4 c0 = *(const float4*)&be[cg], c1 = *(const float4*)&be[cg + 4];
        w0[0]=a0.x; w0[1]=a0.y; w0[2]=a0.z; w0[3]=a0.w; w0[4]=a1.x; w0[5]=a1.y; w0[6]=a1.z; w0[7]=a1.w;
        w1[0]=b0.x; w1[1]=b0.y; w1[2]=b0.z; w1[3]=b0.w; w1[4]=b1v.x; w1[5]=b1v.y; w1[6]=b1v.z; w1[7]=b1v.w;
        bc[0]=c0.x; bc[1]=c0.y; bc[2]=c0.z; bc[3]=c0.w; bc[4]=c1.x; bc[5]=c1.y; bc[6]=c1.z; bc[7]=c1.w;
    }

    uint4 hs = *(const uint4*)&gbf[(size_t)n * HID + cg];   // self term (issued early)
    int jb = row_start[n], je = row_start[n + 1];
    float acc[8];
#pragma unroll
    for (int c = 0; c < 8; ++c) acc[c] = 0.f;

    int j = jb;
    for (; j + 8 <= je; j += 8) {
        int4 q[8];
        uint4 hq[8];
#pragma unroll
        for (int u = 0; u < 8; ++u) q[u] = edges[j + u];
#pragma unroll
        for (int u = 0; u < 8; ++u) hq[u] = *(const uint4*)&gbf[(size_t)q[u].x * HID + cg];
#pragma unroll
        for (int u = 0; u < 8; ++u) {
            float ex = __int_as_float(q[u].y), ey = __int_as_float(q[u].z);
#pragma unroll
            for (int c = 0; c < 8; ++c)
                acc[c] += fmaxf(bfch(hq[u], c) + fmaf(ex, w0[c], fmaf(ey, w1[c], bc[c])), 0.f);
        }
    }
    if (j + 4 <= je) {
        int4 q[4];
        uint4 hq[4];
#pragma unroll
        for (int u = 0; u < 4; ++u) q[u] = edges[j + u];
#pragma unroll
        for (int u = 0; u < 4; ++u) hq[u] = *(const uint4*)&gbf[(size_t)q[u].x * HID + cg];
#pragma unroll
        for (int u = 0; u < 4; ++u) {
            float ex = __int_as_float(q[u].y), ey = __int_as_float(q[u].z);
#pragma unroll
            for (int c = 0; c < 8; ++c)
                acc[c] += fmaxf(bfch(hq[u], c) + fmaf(ex, w0[c], fmaf(ey, w1[c], bc[c])), 0.f);
        }
        j += 4;
    }
    for (; j < je; ++j) {
        int4 q = edges[j];
        uint4 hq = *(const uint4*)&gbf[(size_t)q.x * HID + cg];
        float ex = __int_as_float(q.y), ey = __int_as_float(q.z);
#pragma unroll
        for (int c = 0; c < 8; ++c)
            acc[c] += fmaxf(bfch(hq, c) + fmaf(ex, w0[c], fmaf(ey, w1[c], bc[c])), 0.f);
    }

    unsigned int o[4];
#pragma unroll
    for (int p = 0; p < 4; ++p)
        o[p] = (unsigned int)f2bf(bflo((&hs.x)[p]) + acc[2 * p]) |
               ((unsigned int)f2bf(bfhi((&hs.x)[p]) + acc[2 * p + 1]) << 16);
    *(uint4*)&zbf[(size_t)n * HID + cg] = make_uint4(o[0], o[1], o[2], o[3]);
}

// ---------------- input GEMM (bf16 MFMA): hbf = bf16(x @ W_in + b_in) ----------------
__global__ __launch_bounds__(256) void ingemm_kernel(const float* __restrict__ A,
                                                     const unsigned short* __restrict__ Wt,
                                                     const float* __restrict__ bias,
                                                     unsigned short* __restrict__ outbf) {
    constexpr int KD = IN_DIM;
    __shared__ unsigned short aS[64 * KD];
    __shared__ unsigned short wS[128 * KD];
    int tid = threadIdx.x;
    int row0 = blockIdx.x * 64;

#pragma unroll
    for (int it = 0; it < (64 * KD) / (256 * 4); ++it) {
        int idx = it * 1024 + tid * 4;
        int r = idx / KD, k = idx % KD;
        int grow = row0 + r;
        float4 v = (grow < N_NODES) ? *(const float4*)&A[(size_t)grow * KD + k]
                                    : make_float4(0.f, 0.f, 0.f, 0.f);
        unsigned int d0 = (unsigned int)f2bf(v.x) | ((unsigned int)f2bf(v.y) << 16);
        unsigned int d1 = (unsigned int)f2bf(v.z) | ((unsigned int)f2bf(v.w) << 16);
        unsigned int byte = (unsigned int)(idx * 2) ^ (unsigned int)((r & 7) << 4);
        *(uint2*)((char*)aS + byte) = make_uint2(d0, d1);
    }
#pragma unroll
    for (int it = 0; it < (128 * KD) / (256 * 8); ++it) {
        int idx = it * 2048 + tid * 8;
        int c = idx / KD;
        uint4 v = *(const uint4*)&Wt[idx];
        unsigned int byte = (unsigned int)(idx * 2) ^ (unsigned int)((c & 7) << 4);
        *(uint4*)((char*)wS + byte) = v;
    }
    __syncthreads();

    int w = tid >> 6, l = tid & 63;
    int wr = w >> 1, wc = w & 1, lr = l & 15, kq = (l >> 4) * 8;
    f32x4 acc[2][4];
#pragma unroll
    for (int r = 0; r < 2; ++r)
#pragma unroll
        for (int t = 0; t < 4; ++t) acc[r][t] = (f32x4){0.f, 0.f, 0.f, 0.f};

#pragma unroll
    for (int sstep = 0; sstep < KD / 32; ++sstep) {
        int k0 = sstep * 32 + kq;
        int ar0 = 32 * wr + lr, ar1 = ar0 + 16;
        short8 af0 = *(short8*)((char*)aS + ((unsigned int)((ar0 * KD + k0) * 2) ^
                                            (unsigned int)((ar0 & 7) << 4)));
        short8 af1 = *(short8*)((char*)aS + ((unsigned int)((ar1 * KD + k0) * 2) ^
                                            (unsigned int)((ar1 & 7) << 4)));
#pragma unroll
        for (int t = 0; t < 4; ++t) {
            int col = 64 * wc + 16 * t + lr;
            short8 bf = *(short8*)((char*)wS + ((unsigned int)((col * KD + k0) * 2) ^
                                               (unsigned int)((col & 7) << 4)));
            acc[0][t] = __builtin_amdgcn_mfma_f32_16x16x32_bf16(af0, bf, acc[0][t], 0, 0, 0);
            acc[1][t] = __builtin_amdgcn_mfma_f32_16x16x32_bf16(af1, bf, acc[1][t], 0, 0, 0);
        }
    }
#pragma unroll
    for (int r = 0; r < 2; ++r) {
        int rbase = row0 + 32 * wr + 16 * r + (l >> 4) * 4;
#pragma unroll
        for (int t = 0; t < 4; ++t) {
            int col = 64 * wc + 16 * t + lr;
            float b = bias[col];
#pragma unroll
            for (int q = 0; q < 4; ++q) {
                int grow = rbase + q;
                if (grow < N_NODES) outbf[(size_t)grow * HID + col] = f2bf(acc[r][t][q] + b);
            }
        }
    }
}

// ---------------- fused conv MLP: z2 = relu(z@W1+b1)@W2+b2, + BN stats ----------------
// One 64-row block does both GEMMs; y lives in LDS; W2 prefetched into regs during GEMM1.
__global__ __launch_bounds__(256) void conv_kernel(const unsigned short* __restrict__ zbf,
                                                   const unsigned short* __restrict__ Wt1,
                                                   const float* __restrict__ b1,
                                                   const unsigned short* __restrict__ Wt2,
                                                   const float* __restrict__ b2,
                                                   float* __restrict__ B,
                                                   float* __restrict__ S1,
                                                   float* __restrict__ S2,
                                                   float* __restrict__ zinit, int zinit_n) {
    constexpr int KD = HID;
    __shared__ unsigned short aS[64 * KD];    // z tile, then y tile
    __shared__ unsigned short wS[128 * KD];   // W1, then W2
    __shared__ float sh1[HID], sh2[HID];
    int tid = threadIdx.x;
    if (zinit && blockIdx.x == 0)
        for (int i = tid; i < zinit_n; i += 256) zinit[i] = 0.f;
    if (tid < HID) { sh1[tid] = 0.f; sh2[tid] = 0.f; }

    int row0 = blockIdx.x * 64;

#pragma unroll
    for (int it = 0; it < 4; ++it) {          // 64*128/(256*8)
        int idx = it * 2048 + tid * 8;
        int r = idx >> 7;
        int grow = row0 + r;
        uint4 v = (grow < N_NODES) ? *(const uint4*)&zbf[(size_t)grow * HID + (idx & 127)]
                                   : make_uint4(0u, 0u, 0u, 0u);
        unsigned int byte = (unsigned int)(idx * 2) ^ (unsigned int)((r & 7) << 4);
        *(uint4*)((char*)aS + byte) = v;
    }
#pragma unroll
    for (int it = 0; it < 8; ++it) {          // 128*128/(256*8)
        int idx = it * 2048 + tid * 8;
        int c = idx >> 7;
        uint4 v = *(const uint4*)&Wt1[idx];
        unsigned int byte = (unsigned int)(idx * 2) ^ (unsigned int)((c & 7) << 4);
        *(uint4*)((char*)wS + byte) = v;
    }
    // T14: issue W2 loads now; they stay in flight across GEMM1.
    uint4 w2r[8];
#pragma unroll
    for (int it = 0; it < 8; ++it) w2r[it] = *(const uint4*)&Wt2[it * 2048 + tid * 8];
    __syncthreads();

    int w = tid >> 6, l = tid & 63;
    int wr = w >> 1, wc = w & 1, lr = l & 15, kq = (l >> 4) * 8;
    int ar0 = 32 * wr + lr, ar1 = ar0 + 16;

    f32x4 acc[2][4];
#pragma unroll
    for (int r = 0; r < 2; ++r)
#pragma unroll
        for (int t = 0; t < 4; ++t) acc[r][t] = (f32x4){0.f, 0.f, 0.f, 0.f};

#pragma unroll
    for (int sstep = 0; sstep < 4; ++sstep) {
        int k0 = sstep * 32 + kq;
        short8 af0 = *(short8*)((char*)aS + ((unsigned int)((ar0 * KD + k0) * 2) ^
                                            (unsigned int)((ar0 & 7) << 4)));
        short8 af1 = *(short8*)((char*)aS + ((unsigned int)((ar1 * KD + k0) * 2) ^
                                            (unsigned int)((ar1 & 7) << 4)));
#pragma unroll
        for (int t = 0; t < 4; ++t) {
            int col = 64 * wc + 16 * t + lr;
            short8 bf = *(short8*)((char*)wS + ((unsigned int)((col * KD + k0) * 2) ^
                                               (unsigned int)((col & 7) << 4)));
            acc[0][t] = __builtin_amdgcn_mfma_f32_16x16x32_bf16(af0, bf, acc[0][t], 0, 0, 0);
            acc[1][t] = __builtin_amdgcn_mfma_f32_16x16x32_bf16(af1, bf, acc[1][t], 0, 0, 0);
        }
    }
    __syncthreads();   // everyone done reading aS (z) and wS (W1)

    // y = relu(acc + b1) -> aS (bf16, swizzled); W2 regs -> wS
#pragma unroll
    for (int r = 0; r < 2; ++r) {
        int lrow0 = 32 * wr + 16 * r + (l >> 4) * 4;
#pragma unroll
        for (int t = 0; t < 4; ++t) {
            int col = 64 * wc + 16 * t + lr;
            float b = b1[col];
#pragma unroll
            for (int q = 0; q < 4; ++q) {
                int lrow = lrow0 + q;
                float v = fmaxf(acc[r][t][q] + b, 0.f);
                unsigned int byte = (unsigned int)((lrow * KD + col) * 2) ^
                                    (unsigned int)((lrow & 7) << 4);
                *(unsigned short*)((char*)aS + byte) = f2bf(v);
            }
        }
    }
#pragma unroll
    for (int it = 0; it < 8; ++it) {
        int idx = it * 2048 + tid * 8;
        int c = idx >> 7;
        unsigned int byte = (unsigned int)(idx * 2) ^ (unsigned int)((c & 7) << 4);
        *(uint4*)((char*)wS + byte) = w2r[it];
    }
    __syncthreads();

    f32x4 acc2[2][4];
#pragma unroll
    for (int r = 0; r < 2; ++r)
#pragma unroll
        for (int t = 0; t < 4; ++t) acc2[r][t] = (f32x4){0.f, 0.f, 0.f, 0.f};

#pragma unroll
    for (int sstep = 0; sstep < 4; ++sstep) {
        int k0 = sstep * 32 + kq;
        short8 af0 = *(short8*)((char*)aS + ((unsigned int)((ar0 * KD + k0) * 2) ^
                                            (unsigned int)((ar0 & 7) << 4)));
        short8 af1 = *(short8*)((char*)aS + ((unsigned int)((ar1 * KD + k0) * 2) ^
                                            (unsigned int)((ar1 & 7) << 4)));
#pragma unroll
        for (int t = 0; t < 4; ++t) {
            int col = 64 * wc + 16 * t + lr;
            short8 bf = *(short8*)((char*)wS + ((unsigned int)((col * KD + k0) * 2) ^
                                               (unsigned int)((col & 7) << 4)));
            acc2[0][t] = __builtin_amdgcn_mfma_f32_16x16x32_bf16(af0, bf, acc2[0][t], 0, 0, 0);
            acc2[1][t] = __builtin_amdgcn_mfma_f32_16x16x32_bf16(af1, bf, acc2[1][t], 0, 0, 0);
        }
    }

    // epilogue: z2 = acc2 + b2 -> B (f32) + BN stats
#pragma unroll
    for (int r = 0; r < 2; ++r) {
        int rbase = row0 + 32 * wr + 16 * r + (l >> 4) * 4;
#pragma unroll
        for (int t = 0; t < 4; ++t) {
            int col = 64 * wc + 16 * t + lr;
            float b = b2[col];
            float s1 = 0.f, s2 = 0.f;
#pragma unroll
            for (int q = 0; q < 4; ++q) {
                int grow = rbase + q;
                if (grow < N_NODES) {
                    float v = acc2[r][t][q] + b;
                    B[(size_t)grow * HID + col] = v;
                    s1 += v;
                    s2 += v * v;
                }
            }
            atomicAdd(&sh1[col], s1);
            atomicAdd(&sh2[col], s2);
        }
    }
    __syncthreads();
    if (tid < HID) {
        atomicAdd(&S1[tid], sh1[tid]);
        atomicAdd(&S2[tid], sh2[tid]);
    }
}

// ---------------- BN apply + relu -> hbf (bf16) + segment-sum into vn_up/pool ----------------
__global__ __launch_bounds__(256) void bn_kernel(const float* __restrict__ z2,
                                                 const float* __restrict__ S1,
                                                 const float* __restrict__ S2,
                                                 const float* __restrict__ gma,
                                                 const float* __restrict__ bta,
                                                 const int* __restrict__ batch,
                                                 unsigned short* __restrict__ hbf,
                                                 float* __restrict__ up) {
    int tid = threadIdx.x;
    int cg = (tid & 31) * 4;
    int n0 = (blockIdx.x * 8 + (tid >> 5)) * 16;
    const float inv = 1.f / (float)N_NODES;
    float4 s1 = *(const float4*)&S1[cg];
    float4 s2 = *(const float4*)&S2[cg];
    float4 g4 = *(const float4*)&gma[cg];
    float4 b4 = *(const float4*)&bta[cg];
    float mux = s1.x * inv, muy = s1.y * inv, muz = s1.z * inv, muw = s1.w * inv;
    float gmx = g4.x * rsqrtf(s2.x * inv - mux * mux + BN_EPS);
    float gmy = g4.y * rsqrtf(s2.y * inv - muy * muy + BN_EPS);
    float gmz = g4.z * rsqrtf(s2.z * inv - muz * muz + BN_EPS);
    float gmw = g4.w * rsqrtf(s2.w * inv - muw * muw + BN_EPS);

    float4 acc = make_float4(0.f, 0.f, 0.f, 0.f);
    int gcur = -1;
    for (int i = 0; i < 16; ++i) {
        int n = n0 + i;
        if (n >= N_NODES) break;
        float4 v = *(const float4*)&z2[(size_t)n * HID + cg];
        float4 hn;
        hn.x = fmaxf(fmaf(v.x - mux, gmx, b4.x), 0.f);
        hn.y = fmaxf(fmaf(v.y - muy, gmy, b4.y), 0.f);
        hn.z = fmaxf(fmaf(v.z - muz, gmz, b4.z), 0.f);
        hn.w = fmaxf(fmaf(v.w - muw, gmw, b4.w), 0.f);
        uint2 pk;
        pk.x = (unsigned int)f2bf(hn.x) | ((unsigned int)f2bf(hn.y) << 16);
        pk.y = (unsigned int)f2bf(hn.z) | ((unsigned int)f2bf(hn.w) << 16);
        *(uint2*)&hbf[(size_t)n * HID + cg] = pk;
        int gb = batch[n];
        if (gb != gcur) {
            if (gcur >= 0) {
                atomicAdd(&up[gcur * HID + cg + 0], acc.x);
                atomicAdd(&up[gcur * HID + cg + 1], acc.y);
                atomicAdd(&up[gcur * HID + cg + 2], acc.z);
                atomicAdd(&up[gcur * HID + cg + 3], acc.w);
            }
            acc = make_float4(0.f, 0.f, 0.f, 0.f);
            gcur = gb;
        }
        acc.x += hn.x; acc.y += hn.y; acc.z += hn.z; acc.w += hn.w;
    }
    if (gcur >= 0) {
        atomicAdd(&up[gcur * HID + cg + 0], acc.x);
        atomicAdd(&up[gcur * HID + cg + 1], acc.y);
        atomicAdd(&up[gcur * HID + cg + 2], acc.z);
        atomicAdd(&up[gcur * HID + cg + 3], acc.w);
    }
}

// ---------------- virtual-node MLP: vn += relu(up@W1+b1)@W2+b2; also bf16 copy ----------------
__global__ __launch_bounds__(128) void vnmlp_kernel(const float* __restrict__ up,
                                                    const float* __restrict__ W1,
                                                    const float* __restrict__ b1,
                                                    const float* __restrict__ W2,
                                                    const float* __restrict__ b2,
                                                    float* __restrict__ vn,
                                                    unsigned short* __restrict__ vnb) {
    __shared__ float t[HID];
    int g = blockIdx.x, c = threadIdx.x;
    float s = b1[c];
#pragma unroll 8
    for (int k = 0; k < HID; ++k) s = fmaf(up[g * HID + k], W1[k * HID + c], s);
    t[c] = fmaxf(s, 0.f);
    __syncthreads();
    float s2 = b2[c];
#pragma unroll 8
    for (int k = 0; k < HID; ++k) s2 = fmaf(t[k], W2[k * HID + c], s2);
    float nv = vn[g * HID + c] + s2;
    vn[g * HID + c] = nv;
    vnb[g * HID + c] = f2bf(nv);
}

// ---------------- classifier: logits[g] ----------------
__global__ __launch_bounds__(128) void cls_kernel(const float* __restrict__ pool,
                                                  const int* __restrict__ endpos,
                                                  const float* __restrict__ W1,
                                                  const float* __restrict__ b1,
                                                  const float* __restrict__ W2,
                                                  const float* __restrict__ b2,
                                                  float* __restrict__ out) {
    __shared__ float t[HID];
    __shared__ float red[HID];
    int g = blockIdx.x, c = threadIdx.x;
    int cnt = endpos[g] - (g > 0 ? endpos[g - 1] : 0);
    float cntf = fmaxf((float)cnt, 1.f);
    t[c] = pool[g * HID + c] / cntf;
    __syncthreads();
    float s = b1[c];
#pragma unroll 8
    for (int k = 0; k < HID; ++k) s = fmaf(t[k], W1[k * HID + c], s);
    float y = fmaxf(s, 0.f);
    red[c] = y * W2[c];
    __syncthreads();
    for (int off = 64; off > 0; off >>= 1) {
        if (c < off) red[c] += red[c + off];
        __syncthreads();
    }
    if (c == 0) out[g] = red[0] + b2[0];
}

// ---------------- host-side orchestration ----------------
extern "C" void kernel_launch(void* const* d_in, const int* in_sizes, int n_in,
                              void* d_out, int out_size, void* d_ws, size_t ws_size,
                              hipStream_t stream) {
    const float* x        = (const float*)d_in[0];
    const float* edge_attr= (const float*)d_in[1];
    const int*   edge_idx = (const int*)d_in[2];
    const int*   batch    = (const int*)d_in[3];
    const float* W_in     = (const float*)d_in[4];
    const float* b_in     = (const float*)d_in[5];
    const float* W_e      = (const float*)d_in[6];
    const float* b_e      = (const float*)d_in[7];
    const float* conv_W1  = (const float*)d_in[8];
    const float* conv_b1  = (const float*)d_in[9];
    const float* conv_W2  = (const float*)d_in[10];
    const float* conv_b2  = (const float*)d_in[11];
    const float* bn_g     = (const float*)d_in[12];
    const float* bn_b     = (const float*)d_in[13];
    const float* vn_W1    = (const float*)d_in[14];
    const float* vn_b1    = (const float*)d_in[15];
    const float* vn_W2    = (const float*)d_in[16];
    const float* vn_b2    = (const float*)d_in[17];
    const float* cls_W1   = (const float*)d_in[18];
    const float* cls_b1   = (const float*)d_in[19];
    const float* cls_W2   = (const float*)d_in[20];
    const float* cls_b2   = (const float*)d_in[21];

    char* ws = (char*)d_ws;
    size_t off = 0;
    auto alloc = [&](size_t bytes) -> void* {
        void* p = ws + off;
        off = (off + bytes + 255) & ~(size_t)255;
        return p;
    };
    float* B = (float*)alloc((size_t)N_NODES * HID * 4);   // z2 (f32)
    unsigned short* hbf = (unsigned short*)alloc((size_t)N_NODES * HID * 2);
    unsigned short* gbf = (unsigned short*)alloc((size_t)N_NODES * HID * 2);
    unsigned short* zbf = (unsigned short*)alloc((size_t)N_NODES * HID * 2);
    size_t zero_begin = off;
    int*   cnt    = (int*)alloc((size_t)N_NODES * 4);
    float* vn     = (float*)alloc((size_t)NUM_GRAPHS * HID * 4);
    unsigned short* vnb = (unsigned short*)alloc((size_t)NUM_GRAPHS * HID * 2);
    float* pool   = (float*)alloc((size_t)NUM_GRAPHS * HID * 4);
    size_t zero_end = off;
    int*    endpos    = (int*)alloc((size_t)NUM_GRAPHS * 4);
    int*    row_start = (int*)alloc((size_t)(N_NODES + 1) * 4);
    int*    rank      = (int*)alloc((size_t)N_EDGES * 4);
    int4*   edges     = (int4*)alloc((size_t)N_EDGES * 16);
    float*  vn_up     = (float*)alloc((size_t)NUM_GRAPHS * HID * 4);
    float*  S1        = (float*)alloc((size_t)HID * 4);
    float*  S2        = (float*)alloc((size_t)HID * 4);
    int*    bsum      = (int*)alloc((size_t)SCAN_BLOCKS * 4);
    int*    boff      = (int*)alloc((size_t)SCAN_BLOCKS * 4);
    unsigned short* wt_in = (unsigned short*)alloc((size_t)HID * IN_DIM * 2);
    unsigned short* wt1   = (unsigned short*)alloc((size_t)NUM_LAYERS * HID * HID * 2);
    unsigned short* wt2   = (unsigned short*)alloc((size_t)NUM_LAYERS * HID * HID * 2);
    (void)ws_size; (void)in_sizes; (void)n_in; (void)out_size;

    const int* srcp = edge_idx;
    const int* dstp = edge_idx + N_EDGES;

    hipMemsetAsync(ws + zero_begin, 0, zero_end - zero_begin, stream);
    hist_kernel<<<(N_EDGES + 1023) / 1024, 256, 0, stream>>>(dstp, cnt, rank);
    endpos_kernel<<<(N_NODES + 255) / 256, 256, 0, stream>>>(batch, endpos);
    wprep_kernel<<<(4 * HID * HID + 255) / 256, 256, 0, stream>>>(W_in, conv_W1, conv_W2,
                                                                  wt_in, wt1, wt2);
    scan1_kernel<<<SCAN_BLOCKS, 1024, 0, stream>>>(cnt, bsum);
    scan2_kernel<<<1, 64, 0, stream>>>(bsum, boff);
    scan3_kernel<<<SCAN_BLOCKS, 1024, 0, stream>>>(cnt, boff, row_start);
    fill_kernel<<<(N_EDGES + 255) / 256, 256, 0, stream>>>(srcp, dstp, edge_attr, rank,
                                                           row_start, edges);

    const int gemm_grid = (N_NODES + 63) / 64;   // 782
    ingemm_kernel<<<gemm_grid, 256, 0, stream>>>(x, wt_in, b_in, hbf);

    for (int i = 0; i < NUM_LAYERS; ++i) {
        const unsigned short* src_tab = hbf;
        if (i > 0) {
            hvadd_kernel<<<(N_NODES * 16 + 255) / 256, 256, 0, stream>>>(hbf, vnb, batch, gbf);
            src_tab = gbf;
        }
        aggr_kernel<<<N_NODES / 16, 256, 0, stream>>>(src_tab, edges, row_start,
                                                      W_e, b_e, zbf, S1, S2);
        conv_kernel<<<gemm_grid, 256, 0, stream>>>(
            zbf, wt1 + (size_t)i * HID * HID, conv_b1 + (size_t)i * HID,
            wt2 + (size_t)i * HID * HID, conv_b2 + (size_t)i * HID,
            B, S1, S2, (i < NUM_LAYERS - 1) ? vn_up : nullptr, NUM_GRAPHS * HID);
        bn_kernel<<<(N_NODES + 127) / 128, 256, 0, stream>>>(B, S1, S2, bn_g + (size_t)i * HID,
                                                             bn_b + (size_t)i * HID, batch, hbf,
                                                             (i < NUM_LAYERS - 1) ? vn_up : pool);
        if (i < NUM_LAYERS - 1)
            vnmlp_kernel<<<NUM_GRAPHS, 128, 0, stream>>>(vn_up, vn_W1, vn_b1, vn_W2, vn_b2,
                                                         vn, vnb);
    }

    cls_kernel<<<NUM_GRAPHS, 128, 0, stream>>>(pool, endpos, cls_W1, cls_b1, cls_W2, cls_b2,
                                               (float*)d_out);
}

// Round 10
// 492.540 us; speedup vs baseline: 2.8205x; 1.0632x over previous
//
#include <hip/hip_runtime.h>

#define N_NODES 50000
#define N_EDGES 800000
#define IN_DIM 64
#define HID 128
#define NUM_LAYERS 4
#define NUM_GRAPHS 128
#define BN_EPS 1e-5f

typedef __attribute__((ext_vector_type(8))) short short8;
typedef __attribute__((ext_vector_type(4))) float f32x4;

__device__ inline unsigned short f2bf(float f) {
    unsigned int u = __float_as_uint(f);
    u += 0x7FFFu + ((u >> 16) & 1u);   // round-to-nearest-even
    return (unsigned short)(u >> 16);
}
__device__ inline float bflo(unsigned int p) { return __uint_as_float(p << 16); }
__device__ inline float bfhi(unsigned int p) { return __uint_as_float(p & 0xFFFF0000u); }
__device__ inline float bfch(const uint4& v, int c) {
    unsigned int p = (&v.x)[c >> 1];
    return (c & 1) ? bfhi(p) : bflo(p);
}

// ---------------- small utility kernels ----------------

// histogram + per-edge rank within dst bucket (rank = atomic return value)
__global__ void hist_kernel(const int* __restrict__ dst, int* __restrict__ cnt,
                            int* __restrict__ rank) {
    int base = blockIdx.x * 1024 + threadIdx.x;
#pragma unroll
    for (int u = 0; u < 4; ++u) {
        int e = base + u * 256;
        if (e < N_EDGES) rank[e] = atomicAdd(&cnt[dst[e]], 1);
    }
}

// batch is sorted: endpos[g] = #nodes with batch <= g, written only at run boundaries.
__global__ void endpos_kernel(const int* __restrict__ batch, int* __restrict__ endpos) {
    int n = blockIdx.x * 256 + threadIdx.x;
    if (n >= N_NODES) return;
    int b = batch[n];
    int b1 = (n + 1 < N_NODES) ? batch[n + 1] : NUM_GRAPHS;
    for (int g = b; g < b1; ++g) endpos[g] = n + 1;
    if (n == 0)
        for (int g = 0; g < b; ++g) endpos[g] = 0;
}

// weight prep: transpose + cvt to bf16 once per call.
__global__ void wprep_kernel(const float* __restrict__ W_in,
                             const float* __restrict__ conv_W1,
                             const float* __restrict__ conv_W2,
                             unsigned short* __restrict__ wt_in,
                             unsigned short* __restrict__ wt1,
                             unsigned short* __restrict__ wt2) {
    int i = blockIdx.x * 256 + threadIdx.x;
    if (i < 128 * IN_DIM) {
        int c = i >> 6, k = i & 63;
        wt_in[i] = f2bf(W_in[k * HID + c]);
    }
    if (i < 4 * HID * HID) {
        int o = i & (HID * HID - 1);
        int layer = i >> 14;
        int c = o >> 7, k = o & 127;
        wt1[i] = f2bf(conv_W1[layer * HID * HID + k * HID + c]);
        wt2[i] = f2bf(conv_W2[layer * HID * HID + k * HID + c]);
    }
}

// ---------------- 3-stage coalesced exclusive scan over 50000 counters ----------------
#define SCAN_BLOCKS ((N_NODES + 1023) / 1024)   // 49

__global__ __launch_bounds__(1024) void scan1_kernel(const int* __restrict__ cnt,
                                                     int* __restrict__ bsum) {
    __shared__ int ls[1024];
    int t = threadIdx.x;
    int g = blockIdx.x * 1024 + t;
    int v = (g < N_NODES) ? cnt[g] : 0;
    ls[t] = v;
    __syncthreads();
    for (int off = 512; off > 0; off >>= 1) {
        if (t < off) ls[t] += ls[t + off];
        __syncthreads();
    }
    if (t == 0) bsum[blockIdx.x] = ls[0];
}

__global__ void scan2_kernel(const int* __restrict__ bsum, int* __restrict__ boff) {
    if (threadIdx.x == 0) {
        int r = 0;
        for (int i = 0; i < SCAN_BLOCKS; ++i) {
            boff[i] = r;
            r += bsum[i];
        }
    }
}

__global__ __launch_bounds__(1024) void scan3_kernel(const int* __restrict__ cnt,
                                                     const int* __restrict__ boff,
                                                     int* __restrict__ row_start) {
    __shared__ int ls[1024];
    int t = threadIdx.x;
    int g = blockIdx.x * 1024 + t;
    int v = (g < N_NODES) ? cnt[g] : 0;
    ls[t] = v;
    __syncthreads();
    for (int off = 1; off < 1024; off <<= 1) {
        int x = (t >= off) ? ls[t - off] : 0;
        __syncthreads();
        ls[t] += x;
        __syncthreads();
    }
    int excl = ls[t] - v + boff[blockIdx.x];
    if (g < N_NODES) {
        row_start[g] = excl;
        if (g == N_NODES - 1) row_start[N_NODES] = excl + v;
    }
}

// atomic-free CSR fill: p = row_start[dst] + rank. Record = {src, ea.x, ea.y, 0}.
__global__ void fill_kernel(const int* __restrict__ src, const int* __restrict__ dst,
                            const float* __restrict__ ea, const int* __restrict__ rank,
                            const int* __restrict__ row_start, int4* __restrict__ edges) {
    int e = blockIdx.x * 256 + threadIdx.x;
    if (e >= N_EDGES) return;
    float2 a = *(const float2*)&ea[2 * e];
    int p = row_start[dst[e]] + rank[e];
    edges[p] = make_int4(src[e], __float_as_int(a.x), __float_as_int(a.y), 0);
}

// gbf[n] = bf16(hbf[n] + vnb[batch[n]])  -- pre-combined gather table for aggr
__global__ void hvadd_kernel(const unsigned short* __restrict__ hbf,
                             const unsigned short* __restrict__ vnb,
                             const int* __restrict__ batch,
                             unsigned short* __restrict__ gbf) {
    int idx = blockIdx.x * 256 + threadIdx.x;   // over N_NODES*16
    int n = idx >> 4;
    if (n >= N_NODES) return;
    int cg = (idx & 15) * 8;
    uint4 h = *(const uint4*)&hbf[(size_t)n * HID + cg];
    uint4 v = *(const uint4*)&vnb[(size_t)batch[n] * HID + cg];
    unsigned int o[4];
#pragma unroll
    for (int p = 0; p < 4; ++p) {
        float lo = bflo((&h.x)[p]) + bflo((&v.x)[p]);
        float hi = bfhi((&h.x)[p]) + bfhi((&v.x)[p]);
        o[p] = (unsigned int)f2bf(lo) | ((unsigned int)f2bf(hi) << 16);
    }
    *(uint4*)&gbf[(size_t)n * HID + cg] = make_uint4(o[0], o[1], o[2], o[3]);
}

// ---------------- edge aggregation (CSR gather from pre-combined bf16 table) ----------------
// z[n] = g[n] + sum_edges relu(g[src] + ea@We + be); bf16 in/out.
// 16 threads per node (8 channels each), 16 nodes per 256-thread block.
__global__ __launch_bounds__(256) void aggr_kernel(const unsigned short* __restrict__ gbf,
                                                   const int4* __restrict__ edges,
                                                   const int* __restrict__ row_start,
                                                   const float* __restrict__ We,
                                                   const float* __restrict__ be,
                                                   unsigned short* __restrict__ zbf,
                                                   float* __restrict__ S1,
                                                   float* __restrict__ S2) {
    int tid = threadIdx.x;
    if (blockIdx.x == 0 && tid < HID) {   // zero BN stat accumulators for this layer
        S1[tid] = 0.f;
        S2[tid] = 0.f;
    }
    int cg = (tid & 15) * 8;               // 8-channel group
    int n = blockIdx.x * 16 + (tid >> 4);  // grid exact: 3125*16 = 50000

    float w0[8], w1[8], bc[8];
    {
        float4 a0 = *(const float4*)&We[cg], a1 = *(const float4*)&We[cg + 4];
        float4 b0 = *(const float4*)&We[HID + cg], b1v = *(const float4*)&We[HID + cg + 4];
        float4 c0 = *(const float4*)&be[cg], c1 = *(const float4*)&be[cg + 4];
        w0[0]=a0.x; w0[1]=a0.y; w0[2]=a0.z; w0[3]=a0.w; w0[4]=a1.x; w0[5]=a1.y; w0[6]=a1.z; w0[7]=a1.w;
        w1[0]=b0.x; w1[1]=b0.y; w1[2]=b0.z; w1[3]=b0.w; w1[4]=b1v.x; w1[5]=b1v.y; w1[6]=b1v.z; w1[7]=b1v.w;
        bc[0]=c0.x; bc[1]=c0.y; bc[2]=c0.z; bc[3]=c0.w; bc[4]=c1.x; bc[5]=c1.y; bc[6]=c1.z; bc[7]=c1.w;
    }

    uint4 hs = *(const uint4*)&gbf[(size_t)n * HID + cg];   // self term (issued early)
    int jb = row_start[n], je = row_start[n + 1];
    float acc[8];
#pragma unroll
    for (int c = 0; c < 8; ++c) acc[c] = 0.f;

    int j = jb;
    for (; j + 8 <= je; j += 8) {
        int4 q[8];
        uint4 hq[8];
#pragma unroll
        for (int u = 0; u < 8; ++u) q[u] = edges[j + u];
#pragma unroll
        for (int u = 0; u < 8; ++u) hq[u] = *(const uint4*)&gbf[(size_t)q[u].x * HID + cg];
#pragma unroll
        for (int u = 0; u < 8; ++u) {
            float ex = __int_as_float(q[u].y), ey = __int_as_float(q[u].z);
#pragma unroll
            for (int c = 0; c < 8; ++c)
                acc[c] += fmaxf(bfch(hq[u], c) + fmaf(ex, w0[c], fmaf(ey, w1[c], bc[c])), 0.f);
        }
    }
    if (j + 4 <= je) {
        int4 q[4];
        uint4 hq[4];
#pragma unroll
        for (int u = 0; u < 4; ++u) q[u] = edges[j + u];
#pragma unroll
        for (int u = 0; u < 4; ++u) hq[u] = *(const uint4*)&gbf[(size_t)q[u].x * HID + cg];
#pragma unroll
        for (int u = 0; u < 4; ++u) {
            float ex = __int_as_float(q[u].y), ey = __int_as_float(q[u].z);
#pragma unroll
            for (int c = 0; c < 8; ++c)
                acc[c] += fmaxf(bfch(hq[u], c) + fmaf(ex, w0[c], fmaf(ey, w1[c], bc[c])), 0.f);
        }
        j += 4;
    }
    for (; j < je; ++j) {
        int4 q = edges[j];
        uint4 hq = *(const uint4*)&gbf[(size_t)q.x * HID + cg];
        float ex = __int_as_float(q.y), ey = __int_as_float(q.z);
#pragma unroll
        for (int c = 0; c < 8; ++c)
            acc[c] += fmaxf(bfch(hq, c) + fmaf(ex, w0[c], fmaf(ey, w1[c], bc[c])), 0.f);
    }

    unsigned int o[4];
#pragma unroll
    for (int p = 0; p < 4; ++p)
        o[p] = (unsigned int)f2bf(bflo((&hs.x)[p]) + acc[2 * p]) |
               ((unsigned int)f2bf(bfhi((&hs.x)[p]) + acc[2 * p + 1]) << 16);
    *(uint4*)&zbf[(size_t)n * HID + cg] = make_uint4(o[0], o[1], o[2], o[3]);
}

// ---------------- input GEMM (bf16 MFMA): hbf = bf16(x @ W_in + b_in) ----------------
__global__ __launch_bounds__(256) void ingemm_kernel(const float* __restrict__ A,
                                                     const unsigned short* __restrict__ Wt,
                                                     const float* __restrict__ bias,
                                                     unsigned short* __restrict__ outbf) {
    constexpr int KD = IN_DIM;
    __shared__ unsigned short aS[64 * KD];
    __shared__ unsigned short wS[128 * KD];
    int tid = threadIdx.x;
    int row0 = blockIdx.x * 64;

#pragma unroll
    for (int it = 0; it < (64 * KD) / (256 * 4); ++it) {
        int idx = it * 1024 + tid * 4;
        int r = idx / KD, k = idx % KD;
        int grow = row0 + r;
        float4 v = (grow < N_NODES) ? *(const float4*)&A[(size_t)grow * KD + k]
                                    : make_float4(0.f, 0.f, 0.f, 0.f);
        unsigned int d0 = (unsigned int)f2bf(v.x) | ((unsigned int)f2bf(v.y) << 16);
        unsigned int d1 = (unsigned int)f2bf(v.z) | ((unsigned int)f2bf(v.w) << 16);
        unsigned int byte = (unsigned int)(idx * 2) ^ (unsigned int)((r & 7) << 4);
        *(uint2*)((char*)aS + byte) = make_uint2(d0, d1);
    }
#pragma unroll
    for (int it = 0; it < (128 * KD) / (256 * 8); ++it) {
        int idx = it * 2048 + tid * 8;
        int c = idx / KD;
        uint4 v = *(const uint4*)&Wt[idx];
        unsigned int byte = (unsigned int)(idx * 2) ^ (unsigned int)((c & 7) << 4);
        *(uint4*)((char*)wS + byte) = v;
    }
    __syncthreads();

    int w = tid >> 6, l = tid & 63;
    int wr = w >> 1, wc = w & 1, lr = l & 15, kq = (l >> 4) * 8;
    f32x4 acc[2][4];
#pragma unroll
    for (int r = 0; r < 2; ++r)
#pragma unroll
        for (int t = 0; t < 4; ++t) acc[r][t] = (f32x4){0.f, 0.f, 0.f, 0.f};

#pragma unroll
    for (int sstep = 0; sstep < KD / 32; ++sstep) {
        int k0 = sstep * 32 + kq;
        int ar0 = 32 * wr + lr, ar1 = ar0 + 16;
        short8 af0 = *(short8*)((char*)aS + ((unsigned int)((ar0 * KD + k0) * 2) ^
                                            (unsigned int)((ar0 & 7) << 4)));
        short8 af1 = *(short8*)((char*)aS + ((unsigned int)((ar1 * KD + k0) * 2) ^
                                            (unsigned int)((ar1 & 7) << 4)));
#pragma unroll
        for (int t = 0; t < 4; ++t) {
            int col = 64 * wc + 16 * t + lr;
            short8 bf = *(short8*)((char*)wS + ((unsigned int)((col * KD + k0) * 2) ^
                                               (unsigned int)((col & 7) << 4)));
            acc[0][t] = __builtin_amdgcn_mfma_f32_16x16x32_bf16(af0, bf, acc[0][t], 0, 0, 0);
            acc[1][t] = __builtin_amdgcn_mfma_f32_16x16x32_bf16(af1, bf, acc[1][t], 0, 0, 0);
        }
    }
#pragma unroll
    for (int r = 0; r < 2; ++r) {
        int rbase = row0 + 32 * wr + 16 * r + (l >> 4) * 4;
#pragma unroll
        for (int t = 0; t < 4; ++t) {
            int col = 64 * wc + 16 * t + lr;
            float b = bias[col];
#pragma unroll
            for (int q = 0; q < 4; ++q) {
                int grow = rbase + q;
                if (grow < N_NODES) outbf[(size_t)grow * HID + col] = f2bf(acc[r][t][q] + b);
            }
        }
    }
}

// ---------------- fused conv MLP: z2 = relu(z@W1+b1)@W2+b2, + BN stats ----------------
// 128x128 tile, 512 threads = 8 waves (2x4). y lives in LDS (reuses z tile);
// W2 reloaded from L2 after GEMM1 (reg-prefetch reverted: vmcnt drain at barrier negated it).
__global__ __launch_bounds__(512) void conv_kernel(const unsigned short* __restrict__ zbf,
                                                   const unsigned short* __restrict__ Wt1,
                                                   const float* __restrict__ b1,
                                                   const unsigned short* __restrict__ Wt2,
                                                   const float* __restrict__ b2,
                                                   float* __restrict__ B,
                                                   float* __restrict__ S1,
                                                   float* __restrict__ S2,
                                                   float* __restrict__ zinit, int zinit_n) {
    constexpr int KD = HID;
    __shared__ unsigned short aS[128 * KD];   // z tile, then y tile (32 KB)
    __shared__ unsigned short wS[128 * KD];   // W1, then W2 (32 KB)
    __shared__ float sh1[HID], sh2[HID];
    int tid = threadIdx.x;
    if (zinit && blockIdx.x == 0)
        for (int i = tid; i < zinit_n; i += 512) zinit[i] = 0.f;
    if (tid < HID) { sh1[tid] = 0.f; sh2[tid] = 0.f; }

    int row0 = blockIdx.x * 128;

#pragma unroll
    for (int it = 0; it < 4; ++it) {          // 128*128/(512*8)
        int idx = it * 4096 + tid * 8;
        int r = idx >> 7;
        int grow = row0 + r;
        uint4 v = (grow < N_NODES) ? *(const uint4*)&zbf[(size_t)grow * HID + (idx & 127)]
                                   : make_uint4(0u, 0u, 0u, 0u);
        unsigned int byte = (unsigned int)(idx * 2) ^ (unsigned int)((r & 7) << 4);
        *(uint4*)((char*)aS + byte) = v;
    }
#pragma unroll
    for (int it = 0; it < 4; ++it) {
        int idx = it * 4096 + tid * 8;
        int c = idx >> 7;
        uint4 v = *(const uint4*)&Wt1[idx];
        unsigned int byte = (unsigned int)(idx * 2) ^ (unsigned int)((c & 7) << 4);
        *(uint4*)((char*)wS + byte) = v;
    }
    __syncthreads();

    int w = tid >> 6, l = tid & 63;
    int wr = w >> 2, wc = w & 3;       // 2x4 wave grid: 64 rows x 32 cols per wave
    int lr = l & 15, kq = (l >> 4) * 8;

    f32x4 acc[4][2];
#pragma unroll
    for (int rt = 0; rt < 4; ++rt)
#pragma unroll
        for (int ct = 0; ct < 2; ++ct) acc[rt][ct] = (f32x4){0.f, 0.f, 0.f, 0.f};

#pragma unroll
    for (int sstep = 0; sstep < 4; ++sstep) {
        int k0 = sstep * 32 + kq;
        short8 af[4];
#pragma unroll
        for (int rt = 0; rt < 4; ++rt) {
            int ar = 64 * wr + 16 * rt + lr;
            af[rt] = *(short8*)((char*)aS + ((unsigned int)((ar * KD + k0) * 2) ^
                                            (unsigned int)((ar & 7) << 4)));
        }
#pragma unroll
        for (int ct = 0; ct < 2; ++ct) {
            int col = 32 * wc + 16 * ct + lr;
            short8 bf = *(short8*)((char*)wS + ((unsigned int)((col * KD + k0) * 2) ^
                                               (unsigned int)((col & 7) << 4)));
#pragma unroll
            for (int rt = 0; rt < 4; ++rt)
                acc[rt][ct] = __builtin_amdgcn_mfma_f32_16x16x32_bf16(af[rt], bf, acc[rt][ct], 0, 0, 0);
        }
    }
    __syncthreads();   // everyone done reading aS (z) and wS (W1)

    // y = relu(acc + b1) -> aS (bf16, swizzled); stage W2 -> wS
#pragma unroll
    for (int rt = 0; rt < 4; ++rt) {
        int lrow0 = 64 * wr + 16 * rt + (l >> 4) * 4;
#pragma unroll
        for (int ct = 0; ct < 2; ++ct) {
            int col = 32 * wc + 16 * ct + lr;
            float b = b1[col];
#pragma unroll
            for (int q = 0; q < 4; ++q) {
                int lrow = lrow0 + q;
                float v = fmaxf(acc[rt][ct][q] + b, 0.f);
                unsigned int byte = (unsigned int)((lrow * KD + col) * 2) ^
                                    (unsigned int)((lrow & 7) << 4);
                *(unsigned short*)((char*)aS + byte) = f2bf(v);
            }
        }
    }
#pragma unroll
    for (int it = 0; it < 4; ++it) {
        int idx = it * 4096 + tid * 8;
        int c = idx >> 7;
        uint4 v = *(const uint4*)&Wt2[idx];
        unsigned int byte = (unsigned int)(idx * 2) ^ (unsigned int)((c & 7) << 4);
        *(uint4*)((char*)wS + byte) = v;
    }
    __syncthreads();

    f32x4 acc2[4][2];
#pragma unroll
    for (int rt = 0; rt < 4; ++rt)
#pragma unroll
        for (int ct = 0; ct < 2; ++ct) acc2[rt][ct] = (f32x4){0.f, 0.f, 0.f, 0.f};

#pragma unroll
    for (int sstep = 0; sstep < 4; ++sstep) {
        int k0 = sstep * 32 + kq;
        short8 af[4];
#pragma unroll
        for (int rt = 0; rt < 4; ++rt) {
            int ar = 64 * wr + 16 * rt + lr;
            af[rt] = *(short8*)((char*)aS + ((unsigned int)((ar * KD + k0) * 2) ^
                                            (unsigned int)((ar & 7) << 4)));
        }
#pragma unroll
        for (int ct = 0; ct < 2; ++ct) {
            int col = 32 * wc + 16 * ct + lr;
            short8 bf = *(short8*)((char*)wS + ((unsigned int)((col * KD + k0) * 2) ^
                                               (unsigned int)((col & 7) << 4)));
#pragma unroll
            for (int rt = 0; rt < 4; ++rt)
                acc2[rt][ct] = __builtin_amdgcn_mfma_f32_16x16x32_bf16(af[rt], bf, acc2[rt][ct], 0, 0, 0);
        }
    }

    // epilogue: z2 = acc2 + b2 -> B (f32) + BN stats
#pragma unroll
    for (int rt = 0; rt < 4; ++rt) {
        int rbase = row0 + 64 * wr + 16 * rt + (l >> 4) * 4;
#pragma unroll
        for (int ct = 0; ct < 2; ++ct) {
            int col = 32 * wc + 16 * ct + lr;
            float b = b2[col];
            float s1 = 0.f, s2 = 0.f;
#pragma unroll
            for (int q = 0; q < 4; ++q) {
                int grow = rbase + q;
                if (grow < N_NODES) {
                    float v = acc2[rt][ct][q] + b;
                    B[(size_t)grow * HID + col] = v;
                    s1 += v;
                    s2 += v * v;
                }
            }
            atomicAdd(&sh1[col], s1);
            atomicAdd(&sh2[col], s2);
        }
    }
    __syncthreads();
    if (tid < HID) {
        atomicAdd(&S1[tid], sh1[tid]);
        atomicAdd(&S2[tid], sh2[tid]);
    }
}

// ---------------- BN apply + relu -> hbf (bf16) + segment-sum into vn_up/pool ----------------
__global__ __launch_bounds__(256) void bn_kernel(const float* __restrict__ z2,
                                                 const float* __restrict__ S1,
                                                 const float* __restrict__ S2,
                                                 const float* __restrict__ gma,
                                                 const float* __restrict__ bta,
                                                 const int* __restrict__ batch,
                                                 unsigned short* __restrict__ hbf,
                                                 float* __restrict__ up) {
    int tid = threadIdx.x;
    int cg = (tid & 31) * 4;
    int n0 = (blockIdx.x * 8 + (tid >> 5)) * 16;
    const float inv = 1.f / (float)N_NODES;
    float4 s1 = *(const float4*)&S1[cg];
    float4 s2 = *(const float4*)&S2[cg];
    float4 g4 = *(const float4*)&gma[cg];
    float4 b4 = *(const float4*)&bta[cg];
    float mux = s1.x * inv, muy = s1.y * inv, muz = s1.z * inv, muw = s1.w * inv;
    float gmx = g4.x * rsqrtf(s2.x * inv - mux * mux + BN_EPS);
    float gmy = g4.y * rsqrtf(s2.y * inv - muy * muy + BN_EPS);
    float gmz = g4.z * rsqrtf(s2.z * inv - muz * muz + BN_EPS);
    float gmw = g4.w * rsqrtf(s2.w * inv - muw * muw + BN_EPS);

    float4 acc = make_float4(0.f, 0.f, 0.f, 0.f);
    int gcur = -1;
    for (int i = 0; i < 16; ++i) {
        int n = n0 + i;
        if (n >= N_NODES) break;
        float4 v = *(const float4*)&z2[(size_t)n * HID + cg];
        float4 hn;
        hn.x = fmaxf(fmaf(v.x - mux, gmx, b4.x), 0.f);
        hn.y = fmaxf(fmaf(v.y - muy, gmy, b4.y), 0.f);
        hn.z = fmaxf(fmaf(v.z - muz, gmz, b4.z), 0.f);
        hn.w = fmaxf(fmaf(v.w - muw, gmw, b4.w), 0.f);
        uint2 pk;
        pk.x = (unsigned int)f2bf(hn.x) | ((unsigned int)f2bf(hn.y) << 16);
        pk.y = (unsigned int)f2bf(hn.z) | ((unsigned int)f2bf(hn.w) << 16);
        *(uint2*)&hbf[(size_t)n * HID + cg] = pk;
        int gb = batch[n];
        if (gb != gcur) {
            if (gcur >= 0) {
                atomicAdd(&up[gcur * HID + cg + 0], acc.x);
                atomicAdd(&up[gcur * HID + cg + 1], acc.y);
                atomicAdd(&up[gcur * HID + cg + 2], acc.z);
                atomicAdd(&up[gcur * HID + cg + 3], acc.w);
            }
            acc = make_float4(0.f, 0.f, 0.f, 0.f);
            gcur = gb;
        }
        acc.x += hn.x; acc.y += hn.y; acc.z += hn.z; acc.w += hn.w;
    }
    if (gcur >= 0) {
        atomicAdd(&up[gcur * HID + cg + 0], acc.x);
        atomicAdd(&up[gcur * HID + cg + 1], acc.y);
        atomicAdd(&up[gcur * HID + cg + 2], acc.z);
        atomicAdd(&up[gcur * HID + cg + 3], acc.w);
    }
}

// ---------------- virtual-node MLP: vn += relu(up@W1+b1)@W2+b2; also bf16 copy ----------------
__global__ __launch_bounds__(128) void vnmlp_kernel(const float* __restrict__ up,
                                                    const float* __restrict__ W1,
                                                    const float* __restrict__ b1,
                                                    const float* __restrict__ W2,
                                                    const float* __restrict__ b2,
                                                    float* __restrict__ vn,
                                                    unsigned short* __restrict__ vnb) {
    __shared__ float t[HID];
    int g = blockIdx.x, c = threadIdx.x;
    float s = b1[c];
#pragma unroll 8
    for (int k = 0; k < HID; ++k) s = fmaf(up[g * HID + k], W1[k * HID + c], s);
    t[c] = fmaxf(s, 0.f);
    __syncthreads();
    float s2 = b2[c];
#pragma unroll 8
    for (int k = 0; k < HID; ++k) s2 = fmaf(t[k], W2[k * HID + c], s2);
    float nv = vn[g * HID + c] + s2;
    vn[g * HID + c] = nv;
    vnb[g * HID + c] = f2bf(nv);
}

// ---------------- classifier: logits[g] ----------------
__global__ __launch_bounds__(128) void cls_kernel(const float* __restrict__ pool,
                                                  const int* __restrict__ endpos,
                                                  const float* __restrict__ W1,
                                                  const float* __restrict__ b1,
                                                  const float* __restrict__ W2,
                                                  const float* __restrict__ b2,
                                                  float* __restrict__ out) {
    __shared__ float t[HID];
    __shared__ float red[HID];
    int g = blockIdx.x, c = threadIdx.x;
    int cnt = endpos[g] - (g > 0 ? endpos[g - 1] : 0);
    float cntf = fmaxf((float)cnt, 1.f);
    t[c] = pool[g * HID + c] / cntf;
    __syncthreads();
    float s = b1[c];
#pragma unroll 8
    for (int k = 0; k < HID; ++k) s = fmaf(t[k], W1[k * HID + c], s);
    float y = fmaxf(s, 0.f);
    red[c] = y * W2[c];
    __syncthreads();
    for (int off = 64; off > 0; off >>= 1) {
        if (c < off) red[c] += red[c + off];
        __syncthreads();
    }
    if (c == 0) out[g] = red[0] + b2[0];
}

// ---------------- host-side orchestration ----------------
extern "C" void kernel_launch(void* const* d_in, const int* in_sizes, int n_in,
                              void* d_out, int out_size, void* d_ws, size_t ws_size,
                              hipStream_t stream) {
    const float* x        = (const float*)d_in[0];
    const float* edge_attr= (const float*)d_in[1];
    const int*   edge_idx = (const int*)d_in[2];
    const int*   batch    = (const int*)d_in[3];
    const float* W_in     = (const float*)d_in[4];
    const float* b_in     = (const float*)d_in[5];
    const float* W_e      = (const float*)d_in[6];
    const float* b_e      = (const float*)d_in[7];
    const float* conv_W1  = (const float*)d_in[8];
    const float* conv_b1  = (const float*)d_in[9];
    const float* conv_W2  = (const float*)d_in[10];
    const float* conv_b2  = (const float*)d_in[11];
    const float* bn_g     = (const float*)d_in[12];
    const float* bn_b     = (const float*)d_in[13];
    const float* vn_W1    = (const float*)d_in[14];
    const float* vn_b1    = (const float*)d_in[15];
    const float* vn_W2    = (const float*)d_in[16];
    const float* vn_b2    = (const float*)d_in[17];
    const float* cls_W1   = (const float*)d_in[18];
    const float* cls_b1   = (const float*)d_in[19];
    const float* cls_W2   = (const float*)d_in[20];
    const float* cls_b2   = (const float*)d_in[21];

    char* ws = (char*)d_ws;
    size_t off = 0;
    auto alloc = [&](size_t bytes) -> void* {
        void* p = ws + off;
        off = (off + bytes + 255) & ~(size_t)255;
        return p;
    };
    float* B = (float*)alloc((size_t)N_NODES * HID * 4);   // z2 (f32)
    unsigned short* hbf = (unsigned short*)alloc((size_t)N_NODES * HID * 2);
    unsigned short* gbf = (unsigned short*)alloc((size_t)N_NODES * HID * 2);
    unsigned short* zbf = (unsigned short*)alloc((size_t)N_NODES * HID * 2);
    size_t zero_begin = off;
    int*   cnt    = (int*)alloc((size_t)N_NODES * 4);
    float* vn     = (float*)alloc((size_t)NUM_GRAPHS * HID * 4);
    unsigned short* vnb = (unsigned short*)alloc((size_t)NUM_GRAPHS * HID * 2);
    float* pool   = (float*)alloc((size_t)NUM_GRAPHS * HID * 4);
    size_t zero_end = off;
    int*    endpos    = (int*)alloc((size_t)NUM_GRAPHS * 4);
    int*    row_start = (int*)alloc((size_t)(N_NODES + 1) * 4);
    int*    rank      = (int*)alloc((size_t)N_EDGES * 4);
    int4*   edges     = (int4*)alloc((size_t)N_EDGES * 16);
    float*  vn_up     = (float*)alloc((size_t)NUM_GRAPHS * HID * 4);
    float*  S1        = (float*)alloc((size_t)HID * 4);
    float*  S2        = (float*)alloc((size_t)HID * 4);
    int*    bsum      = (int*)alloc((size_t)SCAN_BLOCKS * 4);
    int*    boff      = (int*)alloc((size_t)SCAN_BLOCKS * 4);
    unsigned short* wt_in = (unsigned short*)alloc((size_t)HID * IN_DIM * 2);
    unsigned short* wt1   = (unsigned short*)alloc((size_t)NUM_LAYERS * HID * HID * 2);
    unsigned short* wt2   = (unsigned short*)alloc((size_t)NUM_LAYERS * HID * HID * 2);
    (void)ws_size; (void)in_sizes; (void)n_in; (void)out_size;

    const int* srcp = edge_idx;
    const int* dstp = edge_idx + N_EDGES;

    hipMemsetAsync(ws + zero_begin, 0, zero_end - zero_begin, stream);
    hist_kernel<<<(N_EDGES + 1023) / 1024, 256, 0, stream>>>(dstp, cnt, rank);
    endpos_kernel<<<(N_NODES + 255) / 256, 256, 0, stream>>>(batch, endpos);
    wprep_kernel<<<(4 * HID * HID + 255) / 256, 256, 0, stream>>>(W_in, conv_W1, conv_W2,
                                                                  wt_in, wt1, wt2);
    scan1_kernel<<<SCAN_BLOCKS, 1024, 0, stream>>>(cnt, bsum);
    scan2_kernel<<<1, 64, 0, stream>>>(bsum, boff);
    scan3_kernel<<<SCAN_BLOCKS, 1024, 0, stream>>>(cnt, boff, row_start);
    fill_kernel<<<(N_EDGES + 255) / 256, 256, 0, stream>>>(srcp, dstp, edge_attr, rank,
                                                           row_start, edges);

    ingemm_kernel<<<(N_NODES + 63) / 64, 256, 0, stream>>>(x, wt_in, b_in, hbf);

    const int conv_grid = (N_NODES + 127) / 128;   // 391
    for (int i = 0; i < NUM_LAYERS; ++i) {
        const unsigned short* src_tab = hbf;
        if (i > 0) {
            hvadd_kernel<<<(N_NODES * 16 + 255) / 256, 256, 0, stream>>>(hbf, vnb, batch, gbf);
            src_tab = gbf;
        }
        aggr_kernel<<<N_NODES / 16, 256, 0, stream>>>(src_tab, edges, row_start,
                                                      W_e, b_e, zbf, S1, S2);
        conv_kernel<<<conv_grid, 512, 0, stream>>>(
            zbf, wt1 + (size_t)i * HID * HID, conv_b1 + (size_t)i * HID,
            wt2 + (size_t)i * HID * HID, conv_b2 + (size_t)i * HID,
            B, S1, S2, (i < NUM_LAYERS - 1) ? vn_up : nullptr, NUM_GRAPHS * HID);
        bn_kernel<<<(N_NODES + 127) / 128, 256, 0, stream>>>(B, S1, S2, bn_g + (size_t)i * HID,
                                                             bn_b + (size_t)i * HID, batch, hbf,
                                                             (i < NUM_LAYERS - 1) ? vn_up : pool);
        if (i < NUM_LAYERS - 1)
            vnmlp_kernel<<<NUM_GRAPHS, 128, 0, stream>>>(vn_up, vn_W1, vn_b1, vn_W2, vn_b2,
                                                         vn, vnb);
    }

    cls_kernel<<<NUM_GRAPHS, 128, 0, stream>>>(pool, endpos, cls_W1, cls_b1, cls_W2, cls_b2,
                                               (float*)d_out);
}

// Round 11
// 431.456 us; speedup vs baseline: 3.2199x; 1.1416x over previous
//
#include <hip/hip_runtime.h>

#define N_NODES 50000
#define N_EDGES 800000
#define IN_DIM 64
#define HID 128
#define NUM_LAYERS 4
#define NUM_GRAPHS 128
#define BN_EPS 1e-5f

typedef __attribute__((ext_vector_type(8))) short short8;
typedef __attribute__((ext_vector_type(4))) float f32x4;

__device__ inline unsigned short f2bf(float f) {
    unsigned int u = __float_as_uint(f);
    u += 0x7FFFu + ((u >> 16) & 1u);   // round-to-nearest-even
    return (unsigned short)(u >> 16);
}
__device__ inline float bflo(unsigned int p) { return __uint_as_float(p << 16); }
__device__ inline float bfhi(unsigned int p) { return __uint_as_float(p & 0xFFFF0000u); }
__device__ inline float bfch(const uint4& v, int c) {
    unsigned int p = (&v.x)[c >> 1];
    return (c & 1) ? bfhi(p) : bflo(p);
}

// ---------------- small utility kernels ----------------

// histogram + per-edge rank within dst bucket (rank = atomic return value)
__global__ void hist_kernel(const int* __restrict__ dst, int* __restrict__ cnt,
                            int* __restrict__ rank) {
    int base = blockIdx.x * 1024 + threadIdx.x;
#pragma unroll
    for (int u = 0; u < 4; ++u) {
        int e = base + u * 256;
        if (e < N_EDGES) rank[e] = atomicAdd(&cnt[dst[e]], 1);
    }
}

// batch is sorted: endpos[g] = #nodes with batch <= g, written only at run boundaries.
__global__ void endpos_kernel(const int* __restrict__ batch, int* __restrict__ endpos) {
    int n = blockIdx.x * 256 + threadIdx.x;
    if (n >= N_NODES) return;
    int b = batch[n];
    int b1 = (n + 1 < N_NODES) ? batch[n + 1] : NUM_GRAPHS;
    for (int g = b; g < b1; ++g) endpos[g] = n + 1;
    if (n == 0)
        for (int g = 0; g < b; ++g) endpos[g] = 0;
}

// weight prep: transpose + cvt to bf16 once per call.
__global__ void wprep_kernel(const float* __restrict__ W_in,
                             const float* __restrict__ conv_W1,
                             const float* __restrict__ conv_W2,
                             unsigned short* __restrict__ wt_in,
                             unsigned short* __restrict__ wt1,
                             unsigned short* __restrict__ wt2) {
    int i = blockIdx.x * 256 + threadIdx.x;
    if (i < 128 * IN_DIM) {
        int c = i >> 6, k = i & 63;
        wt_in[i] = f2bf(W_in[k * HID + c]);
    }
    if (i < 4 * HID * HID) {
        int o = i & (HID * HID - 1);
        int layer = i >> 14;
        int c = o >> 7, k = o & 127;
        wt1[i] = f2bf(conv_W1[layer * HID * HID + k * HID + c]);
        wt2[i] = f2bf(conv_W2[layer * HID * HID + k * HID + c]);
    }
}

// ---------------- 3-stage coalesced exclusive scan over 50000 counters ----------------
#define SCAN_BLOCKS ((N_NODES + 1023) / 1024)   // 49

__global__ __launch_bounds__(1024) void scan1_kernel(const int* __restrict__ cnt,
                                                     int* __restrict__ bsum) {
    __shared__ int ls[1024];
    int t = threadIdx.x;
    int g = blockIdx.x * 1024 + t;
    int v = (g < N_NODES) ? cnt[g] : 0;
    ls[t] = v;
    __syncthreads();
    for (int off = 512; off > 0; off >>= 1) {
        if (t < off) ls[t] += ls[t + off];
        __syncthreads();
    }
    if (t == 0) bsum[blockIdx.x] = ls[0];
}

__global__ void scan2_kernel(const int* __restrict__ bsum, int* __restrict__ boff) {
    if (threadIdx.x == 0) {
        int r = 0;
        for (int i = 0; i < SCAN_BLOCKS; ++i) {
            boff[i] = r;
            r += bsum[i];
        }
    }
}

__global__ __launch_bounds__(1024) void scan3_kernel(const int* __restrict__ cnt,
                                                     const int* __restrict__ boff,
                                                     int* __restrict__ row_start) {
    __shared__ int ls[1024];
    int t = threadIdx.x;
    int g = blockIdx.x * 1024 + t;
    int v = (g < N_NODES) ? cnt[g] : 0;
    ls[t] = v;
    __syncthreads();
    for (int off = 1; off < 1024; off <<= 1) {
        int x = (t >= off) ? ls[t - off] : 0;
        __syncthreads();
        ls[t] += x;
        __syncthreads();
    }
    int excl = ls[t] - v + boff[blockIdx.x];
    if (g < N_NODES) {
        row_start[g] = excl;
        if (g == N_NODES - 1) row_start[N_NODES] = excl + v;
    }
}

// atomic-free CSR fill: p = row_start[dst] + rank. Record = {src, ea.x, ea.y, 0}.
__global__ void fill_kernel(const int* __restrict__ src, const int* __restrict__ dst,
                            const float* __restrict__ ea, const int* __restrict__ rank,
                            const int* __restrict__ row_start, int4* __restrict__ edges) {
    int e = blockIdx.x * 256 + threadIdx.x;
    if (e >= N_EDGES) return;
    float2 a = *(const float2*)&ea[2 * e];
    int p = row_start[dst[e]] + rank[e];
    edges[p] = make_int4(src[e], __float_as_int(a.x), __float_as_int(a.y), 0);
}

// gbf[n] = bf16(hbf[n] + vnb[batch[n]])  -- pre-combined gather table for aggr
__global__ void hvadd_kernel(const unsigned short* __restrict__ hbf,
                             const unsigned short* __restrict__ vnb,
                             const int* __restrict__ batch,
                             unsigned short* __restrict__ gbf) {
    int idx = blockIdx.x * 256 + threadIdx.x;   // over N_NODES*16
    int n = idx >> 4;
    if (n >= N_NODES) return;
    int cg = (idx & 15) * 8;
    uint4 h = *(const uint4*)&hbf[(size_t)n * HID + cg];
    uint4 v = *(const uint4*)&vnb[(size_t)batch[n] * HID + cg];
    unsigned int o[4];
#pragma unroll
    for (int p = 0; p < 4; ++p) {
        float lo = bflo((&h.x)[p]) + bflo((&v.x)[p]);
        float hi = bfhi((&h.x)[p]) + bfhi((&v.x)[p]);
        o[p] = (unsigned int)f2bf(lo) | ((unsigned int)f2bf(hi) << 16);
    }
    *(uint4*)&gbf[(size_t)n * HID + cg] = make_uint4(o[0], o[1], o[2], o[3]);
}

// ---------------- edge aggregation (CSR gather from pre-combined bf16 table) ----------------
// z[n] = g[n] + sum_edges relu(g[src] + ea@We + be); bf16 in/out.
// 16 threads per node (8 channels each), 16 nodes per 256-thread block.
__global__ __launch_bounds__(256) void aggr_kernel(const unsigned short* __restrict__ gbf,
                                                   const int4* __restrict__ edges,
                                                   const int* __restrict__ row_start,
                                                   const float* __restrict__ We,
                                                   const float* __restrict__ be,
                                                   unsigned short* __restrict__ zbf,
                                                   float* __restrict__ S1,
                                                   float* __restrict__ S2) {
    int tid = threadIdx.x;
    if (blockIdx.x == 0 && tid < HID) {   // zero BN stat accumulators for this layer
        S1[tid] = 0.f;
        S2[tid] = 0.f;
    }
    int cg = (tid & 15) * 8;               // 8-channel group
    int n = blockIdx.x * 16 + (tid >> 4);  // grid exact: 3125*16 = 50000

    float w0[8], w1[8], bc[8];
    {
        float4 a0 = *(const float4*)&We[cg], a1 = *(const float4*)&We[cg + 4];
        float4 b0 = *(const float4*)&We[HID + cg], b1v = *(const float4*)&We[HID + cg + 4];
        float4 c0 = *(const float4*)&be[cg], c1 = *(const float4*)&be[cg + 4];
        w0[0]=a0.x; w0[1]=a0.y; w0[2]=a0.z; w0[3]=a0.w; w0[4]=a1.x; w0[5]=a1.y; w0[6]=a1.z; w0[7]=a1.w;
        w1[0]=b0.x; w1[1]=b0.y; w1[2]=b0.z; w1[3]=b0.w; w1[4]=b1v.x; w1[5]=b1v.y; w1[6]=b1v.z; w1[7]=b1v.w;
        bc[0]=c0.x; bc[1]=c0.y; bc[2]=c0.z; bc[3]=c0.w; bc[4]=c1.x; bc[5]=c1.y; bc[6]=c1.z; bc[7]=c1.w;
    }

    uint4 hs = *(const uint4*)&gbf[(size_t)n * HID + cg];   // self term (issued early)
    int jb = row_start[n], je = row_start[n + 1];
    float acc[8];
#pragma unroll
    for (int c = 0; c < 8; ++c) acc[c] = 0.f;

    int j = jb;
    for (; j + 8 <= je; j += 8) {
        int4 q[8];
        uint4 hq[8];
#pragma unroll
        for (int u = 0; u < 8; ++u) q[u] = edges[j + u];
#pragma unroll
        for (int u = 0; u < 8; ++u) hq[u] = *(const uint4*)&gbf[(size_t)q[u].x * HID + cg];
#pragma unroll
        for (int u = 0; u < 8; ++u) {
            float ex = __int_as_float(q[u].y), ey = __int_as_float(q[u].z);
#pragma unroll
            for (int c = 0; c < 8; ++c)
                acc[c] += fmaxf(bfch(hq[u], c) + fmaf(ex, w0[c], fmaf(ey, w1[c], bc[c])), 0.f);
        }
    }
    if (j + 4 <= je) {
        int4 q[4];
        uint4 hq[4];
#pragma unroll
        for (int u = 0; u < 4; ++u) q[u] = edges[j + u];
#pragma unroll
        for (int u = 0; u < 4; ++u) hq[u] = *(const uint4*)&gbf[(size_t)q[u].x * HID + cg];
#pragma unroll
        for (int u = 0; u < 4; ++u) {
            float ex = __int_as_float(q[u].y), ey = __int_as_float(q[u].z);
#pragma unroll
            for (int c = 0; c < 8; ++c)
                acc[c] += fmaxf(bfch(hq[u], c) + fmaf(ex, w0[c], fmaf(ey, w1[c], bc[c])), 0.f);
        }
        j += 4;
    }
    for (; j < je; ++j) {
        int4 q = edges[j];
        uint4 hq = *(const uint4*)&gbf[(size_t)q.x * HID + cg];
        float ex = __int_as_float(q.y), ey = __int_as_float(q.z);
#pragma unroll
        for (int c = 0; c < 8; ++c)
            acc[c] += fmaxf(bfch(hq, c) + fmaf(ex, w0[c], fmaf(ey, w1[c], bc[c])), 0.f);
    }

    unsigned int o[4];
#pragma unroll
    for (int p = 0; p < 4; ++p)
        o[p] = (unsigned int)f2bf(bflo((&hs.x)[p]) + acc[2 * p]) |
               ((unsigned int)f2bf(bfhi((&hs.x)[p]) + acc[2 * p + 1]) << 16);
    *(uint4*)&zbf[(size_t)n * HID + cg] = make_uint4(o[0], o[1], o[2], o[3]);
}

// ---------------- input GEMM (bf16 MFMA): hbf = bf16(x @ W_in + b_in) ----------------
__global__ __launch_bounds__(256) void ingemm_kernel(const float* __restrict__ A,
                                                     const unsigned short* __restrict__ Wt,
                                                     const float* __restrict__ bias,
                                                     unsigned short* __restrict__ outbf) {
    constexpr int KD = IN_DIM;
    __shared__ unsigned short aS[64 * KD];
    __shared__ unsigned short wS[128 * KD];
    int tid = threadIdx.x;
    int row0 = blockIdx.x * 64;

#pragma unroll
    for (int it = 0; it < (64 * KD) / (256 * 4); ++it) {
        int idx = it * 1024 + tid * 4;
        int r = idx / KD, k = idx % KD;
        int grow = row0 + r;
        float4 v = (grow < N_NODES) ? *(const float4*)&A[(size_t)grow * KD + k]
                                    : make_float4(0.f, 0.f, 0.f, 0.f);
        unsigned int d0 = (unsigned int)f2bf(v.x) | ((unsigned int)f2bf(v.y) << 16);
        unsigned int d1 = (unsigned int)f2bf(v.z) | ((unsigned int)f2bf(v.w) << 16);
        unsigned int byte = (unsigned int)(idx * 2) ^ (unsigned int)((r & 7) << 4);
        *(uint2*)((char*)aS + byte) = make_uint2(d0, d1);
    }
#pragma unroll
    for (int it = 0; it < (128 * KD) / (256 * 8); ++it) {
        int idx = it * 2048 + tid * 8;
        int c = idx / KD;
        uint4 v = *(const uint4*)&Wt[idx];
        unsigned int byte = (unsigned int)(idx * 2) ^ (unsigned int)((c & 7) << 4);
        *(uint4*)((char*)wS + byte) = v;
    }
    __syncthreads();

    int w = tid >> 6, l = tid & 63;
    int wr = w >> 1, wc = w & 1, lr = l & 15, kq = (l >> 4) * 8;
    f32x4 acc[2][4];
#pragma unroll
    for (int r = 0; r < 2; ++r)
#pragma unroll
        for (int t = 0; t < 4; ++t) acc[r][t] = (f32x4){0.f, 0.f, 0.f, 0.f};

#pragma unroll
    for (int sstep = 0; sstep < KD / 32; ++sstep) {
        int k0 = sstep * 32 + kq;
        int ar0 = 32 * wr + lr, ar1 = ar0 + 16;
        short8 af0 = *(short8*)((char*)aS + ((unsigned int)((ar0 * KD + k0) * 2) ^
                                            (unsigned int)((ar0 & 7) << 4)));
        short8 af1 = *(short8*)((char*)aS + ((unsigned int)((ar1 * KD + k0) * 2) ^
                                            (unsigned int)((ar1 & 7) << 4)));
#pragma unroll
        for (int t = 0; t < 4; ++t) {
            int col = 64 * wc + 16 * t + lr;
            short8 bf = *(short8*)((char*)wS + ((unsigned int)((col * KD + k0) * 2) ^
                                               (unsigned int)((col & 7) << 4)));
            acc[0][t] = __builtin_amdgcn_mfma_f32_16x16x32_bf16(af0, bf, acc[0][t], 0, 0, 0);
            acc[1][t] = __builtin_amdgcn_mfma_f32_16x16x32_bf16(af1, bf, acc[1][t], 0, 0, 0);
        }
    }
#pragma unroll
    for (int r = 0; r < 2; ++r) {
        int rbase = row0 + 32 * wr + 16 * r + (l >> 4) * 4;
#pragma unroll
        for (int t = 0; t < 4; ++t) {
            int col = 64 * wc + 16 * t + lr;
            float b = bias[col];
#pragma unroll
            for (int q = 0; q < 4; ++q) {
                int grow = rbase + q;
                if (grow < N_NODES) outbf[(size_t)grow * HID + col] = f2bf(acc[r][t][q] + b);
            }
        }
    }
}

// ---------------- fused conv MLP: z2 = relu(z@W1+b1)@W2+b2, + BN stats ----------------
// 128x128 tile, 512 threads = 8 waves (2x4). y lives in LDS (reuses z tile).
// BN stats shuffle-reduced across the 4 same-column lanes before LDS atomics.
__global__ __launch_bounds__(512) void conv_kernel(const unsigned short* __restrict__ zbf,
                                                   const unsigned short* __restrict__ Wt1,
                                                   const float* __restrict__ b1,
                                                   const unsigned short* __restrict__ Wt2,
                                                   const float* __restrict__ b2,
                                                   unsigned short* __restrict__ z2bf,
                                                   float* __restrict__ S1,
                                                   float* __restrict__ S2,
                                                   float* __restrict__ zinit, int zinit_n) {
    constexpr int KD = HID;
    __shared__ unsigned short aS[128 * KD];   // z tile, then y tile (32 KB)
    __shared__ unsigned short wS[128 * KD];   // W1, then W2 (32 KB)
    __shared__ float sh1[HID], sh2[HID];
    int tid = threadIdx.x;
    if (zinit && blockIdx.x == 0)
        for (int i = tid; i < zinit_n; i += 512) zinit[i] = 0.f;
    if (tid < HID) { sh1[tid] = 0.f; sh2[tid] = 0.f; }

    int row0 = blockIdx.x * 128;

#pragma unroll
    for (int it = 0; it < 4; ++it) {          // 128*128/(512*8)
        int idx = it * 4096 + tid * 8;
        int r = idx >> 7;
        int grow = row0 + r;
        uint4 v = (grow < N_NODES) ? *(const uint4*)&zbf[(size_t)grow * HID + (idx & 127)]
                                   : make_uint4(0u, 0u, 0u, 0u);
        unsigned int byte = (unsigned int)(idx * 2) ^ (unsigned int)((r & 7) << 4);
        *(uint4*)((char*)aS + byte) = v;
    }
#pragma unroll
    for (int it = 0; it < 4; ++it) {
        int idx = it * 4096 + tid * 8;
        int c = idx >> 7;
        uint4 v = *(const uint4*)&Wt1[idx];
        unsigned int byte = (unsigned int)(idx * 2) ^ (unsigned int)((c & 7) << 4);
        *(uint4*)((char*)wS + byte) = v;
    }
    __syncthreads();

    int w = tid >> 6, l = tid & 63;
    int wr = w >> 2, wc = w & 3;       // 2x4 wave grid: 64 rows x 32 cols per wave
    int lr = l & 15, kq = (l >> 4) * 8;

    f32x4 acc[4][2];
#pragma unroll
    for (int rt = 0; rt < 4; ++rt)
#pragma unroll
        for (int ct = 0; ct < 2; ++ct) acc[rt][ct] = (f32x4){0.f, 0.f, 0.f, 0.f};

#pragma unroll
    for (int sstep = 0; sstep < 4; ++sstep) {
        int k0 = sstep * 32 + kq;
        short8 af[4];
#pragma unroll
        for (int rt = 0; rt < 4; ++rt) {
            int ar = 64 * wr + 16 * rt + lr;
            af[rt] = *(short8*)((char*)aS + ((unsigned int)((ar * KD + k0) * 2) ^
                                            (unsigned int)((ar & 7) << 4)));
        }
#pragma unroll
        for (int ct = 0; ct < 2; ++ct) {
            int col = 32 * wc + 16 * ct + lr;
            short8 bf = *(short8*)((char*)wS + ((unsigned int)((col * KD + k0) * 2) ^
                                               (unsigned int)((col & 7) << 4)));
#pragma unroll
            for (int rt = 0; rt < 4; ++rt)
                acc[rt][ct] = __builtin_amdgcn_mfma_f32_16x16x32_bf16(af[rt], bf, acc[rt][ct], 0, 0, 0);
        }
    }
    __syncthreads();   // everyone done reading aS (z) and wS (W1)

    // y = relu(acc + b1) -> aS (bf16, swizzled); stage W2 -> wS
#pragma unroll
    for (int rt = 0; rt < 4; ++rt) {
        int lrow0 = 64 * wr + 16 * rt + (l >> 4) * 4;
#pragma unroll
        for (int ct = 0; ct < 2; ++ct) {
            int col = 32 * wc + 16 * ct + lr;
            float b = b1[col];
#pragma unroll
            for (int q = 0; q < 4; ++q) {
                int lrow = lrow0 + q;
                float v = fmaxf(acc[rt][ct][q] + b, 0.f);
                unsigned int byte = (unsigned int)((lrow * KD + col) * 2) ^
                                    (unsigned int)((lrow & 7) << 4);
                *(unsigned short*)((char*)aS + byte) = f2bf(v);
            }
        }
    }
#pragma unroll
    for (int it = 0; it < 4; ++it) {
        int idx = it * 4096 + tid * 8;
        int c = idx >> 7;
        uint4 v = *(const uint4*)&Wt2[idx];
        unsigned int byte = (unsigned int)(idx * 2) ^ (unsigned int)((c & 7) << 4);
        *(uint4*)((char*)wS + byte) = v;
    }
    __syncthreads();

    f32x4 acc2[4][2];
#pragma unroll
    for (int rt = 0; rt < 4; ++rt)
#pragma unroll
        for (int ct = 0; ct < 2; ++ct) acc2[rt][ct] = (f32x4){0.f, 0.f, 0.f, 0.f};

#pragma unroll
    for (int sstep = 0; sstep < 4; ++sstep) {
        int k0 = sstep * 32 + kq;
        short8 af[4];
#pragma unroll
        for (int rt = 0; rt < 4; ++rt) {
            int ar = 64 * wr + 16 * rt + lr;
            af[rt] = *(short8*)((char*)aS + ((unsigned int)((ar * KD + k0) * 2) ^
                                            (unsigned int)((ar & 7) << 4)));
        }
#pragma unroll
        for (int ct = 0; ct < 2; ++ct) {
            int col = 32 * wc + 16 * ct + lr;
            short8 bf = *(short8*)((char*)wS + ((unsigned int)((col * KD + k0) * 2) ^
                                               (unsigned int)((col & 7) << 4)));
#pragma unroll
            for (int rt = 0; rt < 4; ++rt)
                acc2[rt][ct] = __builtin_amdgcn_mfma_f32_16x16x32_bf16(af[rt], bf, acc2[rt][ct], 0, 0, 0);
        }
    }

    // epilogue: z2 = acc2 + b2 -> z2bf (bf16) + BN stats (register acc + shuffle reduce)
    float s1v[2] = {0.f, 0.f}, s2v[2] = {0.f, 0.f};
#pragma unroll
    for (int rt = 0; rt < 4; ++rt) {
        int rbase = row0 + 64 * wr + 16 * rt + (l >> 4) * 4;
#pragma unroll
        for (int ct = 0; ct < 2; ++ct) {
            int col = 32 * wc + 16 * ct + lr;
            float b = b2[col];
#pragma unroll
            for (int q = 0; q < 4; ++q) {
                int grow = rbase + q;
                if (grow < N_NODES) {
                    float v = acc2[rt][ct][q] + b;
                    z2bf[(size_t)grow * HID + col] = f2bf(v);
                    s1v[ct] += v;
                    s2v[ct] += v * v;
                }
            }
        }
    }
#pragma unroll
    for (int ct = 0; ct < 2; ++ct) {
        float a = s1v[ct], bsum2 = s2v[ct];
        a += __shfl_xor(a, 16); a += __shfl_xor(a, 32);
        bsum2 += __shfl_xor(bsum2, 16); bsum2 += __shfl_xor(bsum2, 32);
        if ((l >> 4) == 0) {
            int col = 32 * wc + 16 * ct + lr;
            atomicAdd(&sh1[col], a);
            atomicAdd(&sh2[col], bsum2);
        }
    }
    __syncthreads();
    if (tid < HID) {
        atomicAdd(&S1[tid], sh1[tid]);
        atomicAdd(&S2[tid], sh2[tid]);
    }
}

// ---------------- BN apply + relu -> hbf (bf16) + segment-sum into vn_up/pool ----------------
__global__ __launch_bounds__(256) void bn_kernel(const unsigned short* __restrict__ z2bf,
                                                 const float* __restrict__ S1,
                                                 const float* __restrict__ S2,
                                                 const float* __restrict__ gma,
                                                 const float* __restrict__ bta,
                                                 const int* __restrict__ batch,
                                                 unsigned short* __restrict__ hbf,
                                                 float* __restrict__ up) {
    int tid = threadIdx.x;
    int cg = (tid & 31) * 4;
    int n0 = (blockIdx.x * 8 + (tid >> 5)) * 16;
    const float inv = 1.f / (float)N_NODES;
    float4 s1 = *(const float4*)&S1[cg];
    float4 s2 = *(const float4*)&S2[cg];
    float4 g4 = *(const float4*)&gma[cg];
    float4 b4 = *(const float4*)&bta[cg];
    float mux = s1.x * inv, muy = s1.y * inv, muz = s1.z * inv, muw = s1.w * inv;
    float gmx = g4.x * rsqrtf(s2.x * inv - mux * mux + BN_EPS);
    float gmy = g4.y * rsqrtf(s2.y * inv - muy * muy + BN_EPS);
    float gmz = g4.z * rsqrtf(s2.z * inv - muz * muz + BN_EPS);
    float gmw = g4.w * rsqrtf(s2.w * inv - muw * muw + BN_EPS);

    float4 acc = make_float4(0.f, 0.f, 0.f, 0.f);
    int gcur = -1;
    for (int i = 0; i < 16; ++i) {
        int n = n0 + i;
        if (n >= N_NODES) break;
        uint2 zv = *(const uint2*)&z2bf[(size_t)n * HID + cg];
        float4 hn;
        hn.x = fmaxf(fmaf(bflo(zv.x) - mux, gmx, b4.x), 0.f);
        hn.y = fmaxf(fmaf(bfhi(zv.x) - muy, gmy, b4.y), 0.f);
        hn.z = fmaxf(fmaf(bflo(zv.y) - muz, gmz, b4.z), 0.f);
        hn.w = fmaxf(fmaf(bfhi(zv.y) - muw, gmw, b4.w), 0.f);
        uint2 pk;
        pk.x = (unsigned int)f2bf(hn.x) | ((unsigned int)f2bf(hn.y) << 16);
        pk.y = (unsigned int)f2bf(hn.z) | ((unsigned int)f2bf(hn.w) << 16);
        *(uint2*)&hbf[(size_t)n * HID + cg] = pk;
        int gb = batch[n];
        if (gb != gcur) {
            if (gcur >= 0) {
                atomicAdd(&up[gcur * HID + cg + 0], acc.x);
                atomicAdd(&up[gcur * HID + cg + 1], acc.y);
                atomicAdd(&up[gcur * HID + cg + 2], acc.z);
                atomicAdd(&up[gcur * HID + cg + 3], acc.w);
            }
            acc = make_float4(0.f, 0.f, 0.f, 0.f);
            gcur = gb;
        }
        acc.x += hn.x; acc.y += hn.y; acc.z += hn.z; acc.w += hn.w;
    }
    if (gcur >= 0) {
        atomicAdd(&up[gcur * HID + cg + 0], acc.x);
        atomicAdd(&up[gcur * HID + cg + 1], acc.y);
        atomicAdd(&up[gcur * HID + cg + 2], acc.z);
        atomicAdd(&up[gcur * HID + cg + 3], acc.w);
    }
}

// ---------------- virtual-node MLP: vn += relu(up@W1+b1)@W2+b2; also bf16 copy ----------------
__global__ __launch_bounds__(128) void vnmlp_kernel(const float* __restrict__ up,
                                                    const float* __restrict__ W1,
                                                    const float* __restrict__ b1,
                                                    const float* __restrict__ W2,
                                                    const float* __restrict__ b2,
                                                    float* __restrict__ vn,
                                                    unsigned short* __restrict__ vnb) {
    __shared__ float t[HID];
    int g = blockIdx.x, c = threadIdx.x;
    float s = b1[c];
#pragma unroll 8
    for (int k = 0; k < HID; ++k) s = fmaf(up[g * HID + k], W1[k * HID + c], s);
    t[c] = fmaxf(s, 0.f);
    __syncthreads();
    float s2 = b2[c];
#pragma unroll 8
    for (int k = 0; k < HID; ++k) s2 = fmaf(t[k], W2[k * HID + c], s2);
    float nv = vn[g * HID + c] + s2;
    vn[g * HID + c] = nv;
    vnb[g * HID + c] = f2bf(nv);
}

// ---------------- classifier: logits[g] ----------------
__global__ __launch_bounds__(128) void cls_kernel(const float* __restrict__ pool,
                                                  const int* __restrict__ endpos,
                                                  const float* __restrict__ W1,
                                                  const float* __restrict__ b1,
                                                  const float* __restrict__ W2,
                                                  const float* __restrict__ b2,
                                                  float* __restrict__ out) {
    __shared__ float t[HID];
    __shared__ float red[HID];
    int g = blockIdx.x, c = threadIdx.x;
    int cnt = endpos[g] - (g > 0 ? endpos[g - 1] : 0);
    float cntf = fmaxf((float)cnt, 1.f);
    t[c] = pool[g * HID + c] / cntf;
    __syncthreads();
    float s = b1[c];
#pragma unroll 8
    for (int k = 0; k < HID; ++k) s = fmaf(t[k], W1[k * HID + c], s);
    float y = fmaxf(s, 0.f);
    red[c] = y * W2[c];
    __syncthreads();
    for (int off = 64; off > 0; off >>= 1) {
        if (c < off) red[c] += red[c + off];
        __syncthreads();
    }
    if (c == 0) out[g] = red[0] + b2[0];
}

// ---------------- host-side orchestration ----------------
extern "C" void kernel_launch(void* const* d_in, const int* in_sizes, int n_in,
                              void* d_out, int out_size, void* d_ws, size_t ws_size,
                              hipStream_t stream) {
    const float* x        = (const float*)d_in[0];
    const float* edge_attr= (const float*)d_in[1];
    const int*   edge_idx = (const int*)d_in[2];
    const int*   batch    = (const int*)d_in[3];
    const float* W_in     = (const float*)d_in[4];
    const float* b_in     = (const float*)d_in[5];
    const float* W_e      = (const float*)d_in[6];
    const float* b_e      = (const float*)d_in[7];
    const float* conv_W1  = (const float*)d_in[8];
    const float* conv_b1  = (const float*)d_in[9];
    const float* conv_W2  = (const float*)d_in[10];
    const float* conv_b2  = (const float*)d_in[11];
    const float* bn_g     = (const float*)d_in[12];
    const float* bn_b     = (const float*)d_in[13];
    const float* vn_W1    = (const float*)d_in[14];
    const float* vn_b1    = (const float*)d_in[15];
    const float* vn_W2    = (const float*)d_in[16];
    const float* vn_b2    = (const float*)d_in[17];
    const float* cls_W1   = (const float*)d_in[18];
    const float* cls_b1   = (const float*)d_in[19];
    const float* cls_W2   = (const float*)d_in[20];
    const float* cls_b2   = (const float*)d_in[21];

    char* ws = (char*)d_ws;
    size_t off = 0;
    auto alloc = [&](size_t bytes) -> void* {
        void* p = ws + off;
        off = (off + bytes + 255) & ~(size_t)255;
        return p;
    };
    unsigned short* z2bf = (unsigned short*)alloc((size_t)N_NODES * HID * 2);
    unsigned short* hbf = (unsigned short*)alloc((size_t)N_NODES * HID * 2);
    unsigned short* gbf = (unsigned short*)alloc((size_t)N_NODES * HID * 2);
    unsigned short* zbf = (unsigned short*)alloc((size_t)N_NODES * HID * 2);
    size_t zero_begin = off;
    int*   cnt    = (int*)alloc((size_t)N_NODES * 4);
    float* vn     = (float*)alloc((size_t)NUM_GRAPHS * HID * 4);
    unsigned short* vnb = (unsigned short*)alloc((size_t)NUM_GRAPHS * HID * 2);
    float* pool   = (float*)alloc((size_t)NUM_GRAPHS * HID * 4);
    size_t zero_end = off;
    int*    endpos    = (int*)alloc((size_t)NUM_GRAPHS * 4);
    int*    row_start = (int*)alloc((size_t)(N_NODES + 1) * 4);
    int*    rank      = (int*)alloc((size_t)N_EDGES * 4);
    int4*   edges     = (int4*)alloc((size_t)N_EDGES * 16);
    float*  vn_up     = (float*)alloc((size_t)NUM_GRAPHS * HID * 4);
    float*  S1        = (float*)alloc((size_t)HID * 4);
    float*  S2        = (float*)alloc((size_t)HID * 4);
    int*    bsum      = (int*)alloc((size_t)SCAN_BLOCKS * 4);
    int*    boff      = (int*)alloc((size_t)SCAN_BLOCKS * 4);
    unsigned short* wt_in = (unsigned short*)alloc((size_t)HID * IN_DIM * 2);
    unsigned short* wt1   = (unsigned short*)alloc((size_t)NUM_LAYERS * HID * HID * 2);
    unsigned short* wt2   = (unsigned short*)alloc((size_t)NUM_LAYERS * HID * HID * 2);
    (void)ws_size; (void)in_sizes; (void)n_in; (void)out_size;

    const int* srcp = edge_idx;
    const int* dstp = edge_idx + N_EDGES;

    hipMemsetAsync(ws + zero_begin, 0, zero_end - zero_begin, stream);
    hist_kernel<<<(N_EDGES + 1023) / 1024, 256, 0, stream>>>(dstp, cnt, rank);
    endpos_kernel<<<(N_NODES + 255) / 256, 256, 0, stream>>>(batch, endpos);
    wprep_kernel<<<(4 * HID * HID + 255) / 256, 256, 0, stream>>>(W_in, conv_W1, conv_W2,
                                                                  wt_in, wt1, wt2);
    scan1_kernel<<<SCAN_BLOCKS, 1024, 0, stream>>>(cnt, bsum);
    scan2_kernel<<<1, 64, 0, stream>>>(bsum, boff);
    scan3_kernel<<<SCAN_BLOCKS, 1024, 0, stream>>>(cnt, boff, row_start);
    fill_kernel<<<(N_EDGES + 255) / 256, 256, 0, stream>>>(srcp, dstp, edge_attr, rank,
                                                           row_start, edges);

    ingemm_kernel<<<(N_NODES + 63) / 64, 256, 0, stream>>>(x, wt_in, b_in, hbf);

    const int conv_grid = (N_NODES + 127) / 128;   // 391
    for (int i = 0; i < NUM_LAYERS; ++i) {
        const unsigned short* src_tab = hbf;
        if (i > 0) {
            hvadd_kernel<<<(N_NODES * 16 + 255) / 256, 256, 0, stream>>>(hbf, vnb, batch, gbf);
            src_tab = gbf;
        }
        aggr_kernel<<<N_NODES / 16, 256, 0, stream>>>(src_tab, edges, row_start,
                                                      W_e, b_e, zbf, S1, S2);
        conv_kernel<<<conv_grid, 512, 0, stream>>>(
            zbf, wt1 + (size_t)i * HID * HID, conv_b1 + (size_t)i * HID,
            wt2 + (size_t)i * HID * HID, conv_b2 + (size_t)i * HID,
            z2bf, S1, S2, (i < NUM_LAYERS - 1) ? vn_up : nullptr, NUM_GRAPHS * HID);
        bn_kernel<<<(N_NODES + 127) / 128, 256, 0, stream>>>(z2bf, S1, S2, bn_g + (size_t)i * HID,
                                                             bn_b + (size_t)i * HID, batch, hbf,
                                                             (i < NUM_LAYERS - 1) ? vn_up : pool);
        if (i < NUM_LAYERS - 1)
            vnmlp_kernel<<<NUM_GRAPHS, 128, 0, stream>>>(vn_up, vn_W1, vn_b1, vn_W2, vn_b2,
                                                         vn, vnb);
    }

    cls_kernel<<<NUM_GRAPHS, 128, 0, stream>>>(pool, endpos, cls_W1, cls_b1, cls_W2, cls_b2,
                                               (float*)d_out);
}